// Round 8
// baseline (3243.108 us; speedup 1.0000x reference)
//
#include <hip/hip_runtime.h>

#define NCAND 50000
#define NB    512
#define DIN   820
#define KP_IN 832
#define DM    512
#define DBK   1024
#define NFEAT 50
#define NCAT  20
#define NFREQ 16
#define DEMB  16
#define CTX   96
#define NCMAX 9216
#define TOTMAX (NCMAX + CTX)

typedef __attribute__((ext_vector_type(8))) short short8;
typedef __attribute__((ext_vector_type(4))) float f32x4;

static __device__ __forceinline__ unsigned short f2bf(float f) {
    union { float f; unsigned int i; } u; u.f = f;
    unsigned int r = u.i + 0x7FFFu + ((u.i >> 16) & 1u);
    return (unsigned short)(r >> 16);
}
static __device__ __forceinline__ float bf2f(unsigned short s) {
    union { unsigned int i; float f; } u; u.i = ((unsigned int)s) << 16;
    return u.f;
}
// order-preserving float->uint key (ascending)
static __device__ __forceinline__ unsigned int f2key(float f) {
    union { float f; unsigned int i; } u; u.f = f;
    return (u.i & 0x80000000u) ? ~u.i : (u.i | 0x80000000u);
}
static __device__ __forceinline__ float key2f(unsigned int k) {
    union { unsigned int i; float f; } u;
    u.i = (k & 0x80000000u) ? (k ^ 0x80000000u) : ~k;
    return u.f;
}

#define GLDS16(g, l) __builtin_amdgcn_global_load_lds( \
    (const __attribute__((address_space(1))) void*)(g), \
    (__attribute__((address_space(3))) void*)(l), 16, 0, 0)

#define BG_RELU  1
#define BG_SCORE 2

// LDS chunk swizzle: physical chunk c_p at row r holds logical chunk (c_p - (r>>1))&3.
// Staging (GLDS16, lane covers row base+(lane>>2), phys chunk lane&3):
//   scol = (((lane&3) - ((lane>>3)&3)) & 3) * 8      [valid: base row multiple of 16]
// Read (logical chunk q at row wr+i*16+fr, wr mult of 32):
//   pcs  = ((q + (fr>>1)) & 3) * 8

// ---------------------------------------------------------------- weight prep
__global__ __launch_bounds__(256) void wprep_kernel(
    const float* __restrict__ W, int K, int N, int Kp,
    unsigned short* __restrict__ Wh, unsigned short* __restrict__ Wl)
{
    int idx = blockIdx.x * 256 + threadIdx.x;
    if (idx >= N * Kp) return;
    int n = idx / Kp, k = idx % Kp;
    float v = (k < K) ? W[(size_t)k * N + n] : 0.f;
    unsigned short h = f2bf(v);
    Wh[idx] = h;
    if (Wl) Wl[idx] = f2bf(v - bf2f(h));
}

// ---------------------------------------------------------------- PLR encode (bf16 hi/lo out)
__global__ __launch_bounds__(256) void plr_bf16_kernel(
    const float* __restrict__ xn_, const float* __restrict__ xc_, int nrows,
    const float* __restrict__ freq, const float* __restrict__ plr_w,
    const float* __restrict__ plr_b,
    unsigned short* __restrict__ oh, unsigned short* __restrict__ ol)
{
    __shared__ float sW[32 * 16];
    __shared__ float sB[16];
    __shared__ float sF[NFEAT * NFREQ];
    int tid = threadIdx.x;
    for (int i = tid; i < 512; i += 256) sW[i] = plr_w[i];
    if (tid < 16) sB[tid] = plr_b[tid];
    for (int i = tid; i < NFEAT * NFREQ; i += 256) sF[i] = freq[i];
    __syncthreads();
    int wave = tid >> 6, lane = tid & 63;
    int row = blockIdx.x * 4 + wave;
    if (row >= nrows) return;
    const float* xn = xn_ + (size_t)row * NFEAT;
    const float* xc = xc_ + (size_t)row * NCAT;
    unsigned short* ph = oh + (size_t)row * KP_IN;
    unsigned short* pl = ol + (size_t)row * KP_IN;
    if (lane < NFEAT) {
        float x = xn[lane];
        float cs[NFREQ], sn[NFREQ];
        #pragma unroll
        for (int j = 0; j < NFREQ; j++) {
            float p = 6.28318530717958647692f * sF[lane * NFREQ + j] * x;
            sn[j] = __sinf(p);
            cs[j] = __cosf(p);
        }
        #pragma unroll
        for (int d = 0; d < DEMB; d++) {
            float acc = sB[d];
            #pragma unroll
            for (int j = 0; j < NFREQ; j++)
                acc = fmaf(cs[j], sW[j * DEMB + d], fmaf(sn[j], sW[(NFREQ + j) * DEMB + d], acc));
            float v = fmaxf(acc, 0.f);
            unsigned short h = f2bf(v);
            ph[lane * DEMB + d] = h;
            pl[lane * DEMB + d] = f2bf(v - bf2f(h));
        }
    }
    if (lane < NCAT) {
        float v = xc[lane];
        unsigned short h = f2bf(v);
        ph[800 + lane] = h;
        pl[800 + lane] = f2bf(v - bf2f(h));
    }
    if (lane >= NCAT && lane < 32) {
        ph[800 + lane] = 0;
        pl[800 + lane] = 0;
    }
}

// ------------------------------- bf16 MFMA GEMM (plain 1-term), 128 tile, 512 threads
__global__ __launch_bounds__(512) void bgemm_kernel(
    const unsigned short* __restrict__ A, const unsigned short* __restrict__ Bt,
    int M, int N, int Kp,
    float* __restrict__ Cf, unsigned short* __restrict__ Cb,
    const float* __restrict__ bias, int flags)
{
    __shared__ unsigned short As[128 * 32];
    __shared__ unsigned short Bs[128 * 32];
    int tid = threadIdx.x;
    int w = tid >> 6, lane = tid & 63;
    int m0 = blockIdx.y * 128, n0 = blockIdx.x * 128;
    int wr = (w >> 1) * 32, wc = (w & 1) * 64;

    f32x4 acc[2][4];
    #pragma unroll
    for (int i = 0; i < 2; i++)
        #pragma unroll
        for (int j = 0; j < 4; j++) acc[i][j] = (f32x4){0.f, 0.f, 0.f, 0.f};

    int arr = w & 1;
    int qrt = (w >> 1) * 32;
    int scol = (((lane & 3) - ((lane >> 3) & 3)) & 3) * 8;
    const unsigned short* gsrc = arr ? Bt : A;
    int glim = arr ? (N - 1) : (M - 1);
    int gb   = arr ? n0 : m0;
    unsigned short* ldst = arr ? Bs : As;
    const unsigned short* gp0 = gsrc + (size_t)min(gb + qrt + (lane >> 2),      glim) * Kp + scol;
    const unsigned short* gp1 = gsrc + (size_t)min(gb + qrt + 16 + (lane >> 2), glim) * Kp + scol;
    unsigned short* lp0 = ldst + qrt * 32;
    unsigned short* lp1 = ldst + (qrt + 16) * 32;

    int fr = lane & 15, q = lane >> 4;
    int pcs = ((q + (fr >> 1)) & 3) * 8;

    for (int k0 = 0; k0 < Kp; k0 += 32) {
        __syncthreads();
        GLDS16(gp0 + k0, lp0);
        GLDS16(gp1 + k0, lp1);
        __syncthreads();
        short8 a[2], b[4];
        #pragma unroll
        for (int i = 0; i < 2; i++)
            a[i] = *(const short8*)&As[(wr + i * 16 + fr) * 32 + pcs];
        #pragma unroll
        for (int j = 0; j < 4; j++)
            b[j] = *(const short8*)&Bs[(wc + j * 16 + fr) * 32 + pcs];
        #pragma unroll
        for (int i = 0; i < 2; i++)
            #pragma unroll
            for (int j = 0; j < 4; j++)
                acc[i][j] = __builtin_amdgcn_mfma_f32_16x16x32_bf16(a[i], b[j], acc[i][j], 0, 0, 0);
    }

    int col = lane & 15, rq = (lane >> 4) * 4;
    #pragma unroll
    for (int i = 0; i < 2; i++)
        #pragma unroll
        for (int j = 0; j < 4; j++) {
            int n_g = n0 + wc + j * 16 + col;
            #pragma unroll
            for (int r = 0; r < 4; r++) {
                int m_g = m0 + wr + i * 16 + rq + r;
                if (m_g < M && n_g < N) {
                    float v = acc[i][j][r];
                    if (bias) v += bias[n_g];
                    if (flags & BG_RELU) v = fmaxf(v, 0.f);
                    if (Cf) Cf[(size_t)m_g * N + n_g] = v;
                    if (Cb) Cb[(size_t)m_g * N + n_g] = f2bf(v);
                }
            }
        }
}

// ------------------------- bf16 MFMA GEMM, 3-term split, 128 tile, 512 threads
__global__ __launch_bounds__(512) void bgemm3_kernel(
    const unsigned short* __restrict__ Ah, const unsigned short* __restrict__ Al,
    const unsigned short* __restrict__ Bh, const unsigned short* __restrict__ Bl,
    int M, int N, int Kp,
    float* __restrict__ Cf, unsigned short* __restrict__ Cbh, unsigned short* __restrict__ Cbl,
    const float* __restrict__ bias, const float* __restrict__ resf,
    const float* __restrict__ cnorm, int flags)
{
    __shared__ unsigned short Ash[128 * 32];
    __shared__ unsigned short Asl[128 * 32];
    __shared__ unsigned short Bsh[128 * 32];
    __shared__ unsigned short Bsl[128 * 32];
    int tid = threadIdx.x;
    int w = tid >> 6, lane = tid & 63;
    int m0 = blockIdx.y * 128, n0 = blockIdx.x * 128;
    int wr = (w >> 1) * 32, wc = (w & 1) * 64;

    f32x4 acc[2][4];
    #pragma unroll
    for (int i = 0; i < 2; i++)
        #pragma unroll
        for (int j = 0; j < 4; j++) acc[i][j] = (f32x4){0.f, 0.f, 0.f, 0.f};

    int arr = w & 3;
    int half = (w >> 2) * 64;
    int scol = (((lane & 3) - ((lane >> 3) & 3)) & 3) * 8;
    const unsigned short* gsrc = (arr == 0) ? Ah : (arr == 1) ? Al : (arr == 2) ? Bh : Bl;
    int glim = (arr < 2) ? (M - 1) : (N - 1);
    int gb   = (arr < 2) ? m0 : n0;
    unsigned short* ldst = (arr == 0) ? Ash : (arr == 1) ? Asl : (arr == 2) ? Bsh : Bsl;
    const unsigned short* gp[4];
    unsigned short* lp[4];
    #pragma unroll
    for (int t = 0; t < 4; t++) {
        int r = half + t * 16;
        gp[t] = gsrc + (size_t)min(gb + r + (lane >> 2), glim) * Kp + scol;
        lp[t] = ldst + r * 32;
    }

    int fr = lane & 15, q = lane >> 4;
    int pcs = ((q + (fr >> 1)) & 3) * 8;

    for (int k0 = 0; k0 < Kp; k0 += 32) {
        __syncthreads();
        GLDS16(gp[0] + k0, lp[0]);
        GLDS16(gp[1] + k0, lp[1]);
        GLDS16(gp[2] + k0, lp[2]);
        GLDS16(gp[3] + k0, lp[3]);
        __syncthreads();
        short8 a[2], b[4];
        #pragma unroll
        for (int i = 0; i < 2; i++)
            a[i] = *(const short8*)&Ash[(wr + i * 16 + fr) * 32 + pcs];
        #pragma unroll
        for (int j = 0; j < 4; j++)
            b[j] = *(const short8*)&Bsh[(wc + j * 16 + fr) * 32 + pcs];
        #pragma unroll
        for (int i = 0; i < 2; i++)
            #pragma unroll
            for (int j = 0; j < 4; j++)
                acc[i][j] = __builtin_amdgcn_mfma_f32_16x16x32_bf16(a[i], b[j], acc[i][j], 0, 0, 0);
        short8 al2[2];
        #pragma unroll
        for (int i = 0; i < 2; i++)
            al2[i] = *(const short8*)&Asl[(wr + i * 16 + fr) * 32 + pcs];
        #pragma unroll
        for (int i = 0; i < 2; i++)
            #pragma unroll
            for (int j = 0; j < 4; j++)
                acc[i][j] = __builtin_amdgcn_mfma_f32_16x16x32_bf16(al2[i], b[j], acc[i][j], 0, 0, 0);
        short8 bl2[4];
        #pragma unroll
        for (int j = 0; j < 4; j++)
            bl2[j] = *(const short8*)&Bsl[(wc + j * 16 + fr) * 32 + pcs];
        #pragma unroll
        for (int i = 0; i < 2; i++)
            #pragma unroll
            for (int j = 0; j < 4; j++)
                acc[i][j] = __builtin_amdgcn_mfma_f32_16x16x32_bf16(a[i], bl2[j], acc[i][j], 0, 0, 0);
    }

    int col = lane & 15, rq = (lane >> 4) * 4;
    #pragma unroll
    for (int i = 0; i < 2; i++)
        #pragma unroll
        for (int j = 0; j < 4; j++) {
            int n_g = n0 + wc + j * 16 + col;
            #pragma unroll
            for (int r = 0; r < 4; r++) {
                int m_g = m0 + wr + i * 16 + rq + r;
                if (m_g < M && n_g < N) {
                    float v = acc[i][j][r];
                    if (bias) v += bias[n_g];
                    if (resf) v += resf[(size_t)m_g * N + n_g];
                    if (flags & BG_RELU) v = fmaxf(v, 0.f);
                    if (flags & BG_SCORE) v = 2.f * v - cnorm[n_g];
                    if (Cf) Cf[(size_t)m_g * N + n_g] = v;
                    if (Cbh) {
                        unsigned short h = f2bf(v);
                        Cbh[(size_t)m_g * N + n_g] = h;
                        if (Cbl) Cbl[(size_t)m_g * N + n_g] = f2bf(v - bf2f(h));
                    }
                }
            }
        }
}

// ------------------------- small-M GEMM: 64x64 tile, 1- or 3-term (Al null => 1-term)
__global__ __launch_bounds__(256) void bgemm3s_kernel(
    const unsigned short* __restrict__ Ah, const unsigned short* __restrict__ Al,
    const unsigned short* __restrict__ Bh, const unsigned short* __restrict__ Bl,
    int M, int N, int Kp,
    float* __restrict__ Cf, unsigned short* __restrict__ Cbh, unsigned short* __restrict__ Cbl,
    const float* __restrict__ bias, const float* __restrict__ resf, int flags)
{
    __shared__ unsigned short Ash[64 * 32];
    __shared__ unsigned short Asl[64 * 32];
    __shared__ unsigned short Bsh[64 * 32];
    __shared__ unsigned short Bsl[64 * 32];
    int tid = threadIdx.x;
    int w = tid >> 6, lane = tid & 63;
    int m0 = blockIdx.y * 64, n0 = blockIdx.x * 64;
    int wr = (w >> 1) * 32, wc = (w & 1) * 32;
    int three = (Al != nullptr);

    f32x4 acc[2][2];
    #pragma unroll
    for (int i = 0; i < 2; i++)
        #pragma unroll
        for (int j = 0; j < 2; j++) acc[i][j] = (f32x4){0.f, 0.f, 0.f, 0.f};

    int srow = w * 16 + (lane >> 2);
    int scol = (((lane & 3) - ((lane >> 3) & 3)) & 3) * 8;
    size_t ra = (size_t)min(m0 + srow, M - 1) * Kp + scol;
    size_t rb = (size_t)min(n0 + srow, N - 1) * Kp + scol;
    unsigned short* lah = &Ash[(w * 16) * 32];
    unsigned short* lal = &Asl[(w * 16) * 32];
    unsigned short* lbh = &Bsh[(w * 16) * 32];
    unsigned short* lbl = &Bsl[(w * 16) * 32];

    int fr = lane & 15, q = lane >> 4;
    int pcs = ((q + (fr >> 1)) & 3) * 8;

    for (int k0 = 0; k0 < Kp; k0 += 32) {
        __syncthreads();
        GLDS16(Ah + ra + k0, lah);
        GLDS16(Bh + rb + k0, lbh);
        if (three) {
            GLDS16(Al + ra + k0, lal);
            GLDS16(Bl + rb + k0, lbl);
        }
        __syncthreads();
        short8 a[2], b[2];
        #pragma unroll
        for (int i = 0; i < 2; i++)
            a[i] = *(const short8*)&Ash[(wr + i * 16 + fr) * 32 + pcs];
        #pragma unroll
        for (int j = 0; j < 2; j++)
            b[j] = *(const short8*)&Bsh[(wc + j * 16 + fr) * 32 + pcs];
        #pragma unroll
        for (int i = 0; i < 2; i++)
            #pragma unroll
            for (int j = 0; j < 2; j++)
                acc[i][j] = __builtin_amdgcn_mfma_f32_16x16x32_bf16(a[i], b[j], acc[i][j], 0, 0, 0);
        if (three) {
            short8 al2[2], bl2[2];
            #pragma unroll
            for (int i = 0; i < 2; i++)
                al2[i] = *(const short8*)&Asl[(wr + i * 16 + fr) * 32 + pcs];
            #pragma unroll
            for (int j = 0; j < 2; j++)
                bl2[j] = *(const short8*)&Bsl[(wc + j * 16 + fr) * 32 + pcs];
            #pragma unroll
            for (int i = 0; i < 2; i++)
                #pragma unroll
                for (int j = 0; j < 2; j++) {
                    acc[i][j] = __builtin_amdgcn_mfma_f32_16x16x32_bf16(al2[i], b[j], acc[i][j], 0, 0, 0);
                    acc[i][j] = __builtin_amdgcn_mfma_f32_16x16x32_bf16(a[i], bl2[j], acc[i][j], 0, 0, 0);
                }
        }
    }

    int col = lane & 15, rq = (lane >> 4) * 4;
    #pragma unroll
    for (int i = 0; i < 2; i++)
        #pragma unroll
        for (int j = 0; j < 2; j++) {
            int n_g = n0 + wc + j * 16 + col;
            #pragma unroll
            for (int r = 0; r < 4; r++) {
                int m_g = m0 + wr + i * 16 + rq + r;
                if (m_g < M && n_g < N) {
                    float v = acc[i][j][r];
                    if (bias) v += bias[n_g];
                    if (resf) v += resf[(size_t)m_g * N + n_g];
                    if (flags & BG_RELU) v = fmaxf(v, 0.f);
                    if (Cf) Cf[(size_t)m_g * N + n_g] = v;
                    if (Cbh) {
                        unsigned short h = f2bf(v);
                        Cbh[(size_t)m_g * N + n_g] = h;
                        if (Cbl) Cbl[(size_t)m_g * N + n_g] = f2bf(v - bf2f(h));
                    }
                }
            }
        }
}

// ---------------------------------------------------------------- LayerNorm bf16 hi/lo out
__global__ __launch_bounds__(256) void ln_split_kernel(const float* __restrict__ X,
    unsigned short* __restrict__ Yh, unsigned short* __restrict__ Yl,
    const float* __restrict__ g, const float* __restrict__ bt, int M)
{
    int wave = threadIdx.x >> 6, lane = threadIdx.x & 63;
    int row = blockIdx.x * 4 + wave;
    if (row >= M) return;
    const float* x = X + (size_t)row * DM;
    float4 v0 = ((const float4*)x)[lane * 2];
    float4 v1 = ((const float4*)x)[lane * 2 + 1];
    float s = v0.x + v0.y + v0.z + v0.w + v1.x + v1.y + v1.z + v1.w;
    #pragma unroll
    for (int off = 32; off; off >>= 1) s += __shfl_xor(s, off, 64);
    float m = s * (1.f / DM);
    float q = (v0.x - m) * (v0.x - m) + (v0.y - m) * (v0.y - m)
            + (v0.z - m) * (v0.z - m) + (v0.w - m) * (v0.w - m)
            + (v1.x - m) * (v1.x - m) + (v1.y - m) * (v1.y - m)
            + (v1.z - m) * (v1.z - m) + (v1.w - m) * (v1.w - m);
    #pragma unroll
    for (int off = 32; off; off >>= 1) q += __shfl_xor(q, off, 64);
    float rstd = 1.f / sqrtf(q * (1.f / DM) + 1e-5f);
    float vals[8] = {v0.x, v0.y, v0.z, v0.w, v1.x, v1.y, v1.z, v1.w};
    unsigned short* yh = Yh + (size_t)row * DM + lane * 8;
    unsigned short* yl = Yl + (size_t)row * DM + lane * 8;
    const float* gp = g + lane * 8;
    const float* bp = bt + lane * 8;
    #pragma unroll
    for (int i = 0; i < 8; i++) {
        float y = (vals[i] - m) * rstd * gp[i] + bp[i];
        unsigned short h = f2bf(y);
        yh[i] = h;
        yl[i] = f2bf(y - bf2f(h));
    }
}

// ---------------------------------------------------------------- key norms (fp32 k)
__global__ __launch_bounds__(256) void cnorm_kernel(const float* __restrict__ Kc,
    float* __restrict__ cn, int N)
{
    int wave = threadIdx.x >> 6, lane = threadIdx.x & 63;
    int row = blockIdx.x * 4 + wave;
    if (row >= N) return;
    const float* x = Kc + (size_t)row * DM;
    float4 v0 = ((const float4*)x)[lane * 2];
    float4 v1 = ((const float4*)x)[lane * 2 + 1];
    float s = v0.x * v0.x + v0.y * v0.y + v0.z * v0.z + v0.w * v0.w
            + v1.x * v1.x + v1.y * v1.y + v1.z * v1.z + v1.w * v1.w;
    #pragma unroll
    for (int off = 32; off; off >>= 1) s += __shfl_xor(s, off, 64);
    if (lane == 0) cn[row] = s;
}

// ---------------------------------------------------------------- ctx init
__global__ void ctx_init_kernel(int* __restrict__ idx, float* __restrict__ sc)
{
    int i = blockIdx.x * 256 + threadIdx.x;
    if (i < NB * CTX) { idx[i] = 0; sc[i] = -1e30f; }
}

// ------------------------------------- running top-96 merge: exact radix select
// LDS-cached scores + wave-aggregated histogram atomics.
// Deterministic: selection set defined by (score desc, global idx asc) total order.
#define CANDCAP 2048
__global__ __launch_bounds__(256) void topk_merge_kernel(
    const float* __restrict__ S, int m, int base,
    const int* __restrict__ pidx, const float* __restrict__ pscore,
    int* __restrict__ nidx, float* __restrict__ nscore)
{
    __shared__ __align__(16) float sc[TOTMAX];
    __shared__ unsigned int hist[256];
    __shared__ unsigned int s_prefix;
    __shared__ int s_above;
    __shared__ int prev_i[CTX];
    __shared__ int nsel, neq;
    __shared__ float sel_s[CTX];
    __shared__ int   sel_g[CTX];
    __shared__ int   cnd_g[CANDCAP];

    int b = blockIdx.x, tid = threadIdx.x;
    int lane = tid & 63;
    const float* Sb = S + (size_t)b * m;
    int tot = m + CTX;

    // stage scores into LDS (one global pass, vectorized)
    int m4 = m >> 2;
    const float4* S4 = (const float4*)Sb;
    for (int i = tid; i < m4; i += 256) ((float4*)sc)[i] = S4[i];
    for (int i = (m4 << 2) + tid; i < m; i += 256) sc[i] = Sb[i];
    if (tid < CTX) {
        sc[m + tid] = pscore[b * CTX + tid];
        prev_i[tid] = pidx[b * CTX + tid];
    }
    if (tid == 0) { s_prefix = 0u; s_above = 0; nsel = 0; neq = 0; }
    __syncthreads();

    // 4 radix passes, MSB-first, over LDS
    for (int pass = 0; pass < 4; pass++) {
        int shift = 24 - pass * 8;
        for (int i = tid; i < 256; i += 256) hist[i] = 0;
        __syncthreads();
        unsigned int pref = s_prefix;
        unsigned int msk = (pass == 0) ? 0u : (0xFFFFFFFFu << (32 - 8 * pass));
        for (int i0 = 0; i0 < tot; i0 += 256) {
            int i = i0 + tid;
            int pred = 0, digit = 0;
            if (i < tot) {
                unsigned int k = f2key(sc[i]);
                pred = ((k & msk) == pref);
                digit = (int)((k >> shift) & 255u);
            }
            // wave-aggregated histogram update: one atomic per unique digit per wave
            unsigned long long rem = __ballot(pred);
            while (rem) {
                int src = (int)__ffsll(rem) - 1;
                int d = __shfl(digit, src, 64);
                unsigned long long mm = __ballot(pred && (digit == d));
                if (lane == src) atomicAdd(&hist[d], (unsigned int)__popcll(mm));
                rem &= ~mm;
            }
        }
        __syncthreads();
        if (tid == 0) {
            int above = s_above, bsel = 0;
            for (int i2 = 255; i2 >= 0; i2--) {
                int h = (int)hist[i2];
                if (above + h >= CTX) { bsel = i2; break; }
                above += h;
            }
            s_above = above;
            s_prefix = pref | ((unsigned int)bsel << shift);
        }
        __syncthreads();
    }
    unsigned int thrK = s_prefix;
    int msel = CTX - s_above;          // take msel among key==thrK by smallest idx
    float eqv = key2f(thrK);

    // collect from LDS: strictly above -> selected; equal -> candidates
    for (int i = tid; i < tot; i += 256) {
        float v = sc[i];
        unsigned int k = f2key(v);
        if (k < thrK) continue;
        int g = (i < m) ? (base + i) : prev_i[i - m];
        if (k > thrK) {
            int p = atomicAdd(&nsel, 1);
            sel_s[p] = v; sel_g[p] = g;
        } else {
            int p = atomicAdd(&neq, 1);
            if (p < CANDCAP) cnd_g[p] = g;
        }
    }
    __syncthreads();
    int ne = neq;
    if (ne <= CANDCAP) {
        for (int i = tid; i < ne; i += 256) {
            int gi = cnd_g[i];
            int rank = 0;
            for (int j = 0; j < ne; j++) rank += (cnd_g[j] < gi);
            if (rank < msel) {
                int p = atomicAdd(&nsel, 1);
                sel_s[p] = eqv; sel_g[p] = gi;
            }
        }
    } else {
        // pathological mass-tie fallback: deterministic idx-rank via full LDS scan
        for (int i = tid; i < tot; i += 256) {
            if (f2key(sc[i]) != thrK) continue;
            int g = (i < m) ? (base + i) : prev_i[i - m];
            int rank = 0;
            for (int j = 0; j < tot; j++) {
                if (f2key(sc[j]) == thrK) {
                    int gj = (j < m) ? (base + j) : prev_i[j - m];
                    rank += (gj < g);
                }
            }
            if (rank < msel) {
                int p = atomicAdd(&nsel, 1);
                sel_s[p] = eqv; sel_g[p] = g;
            }
        }
    }
    __syncthreads();
    if (tid < CTX) {
        nidx[b * CTX + tid] = sel_g[tid];
        nscore[b * CTX + tid] = sel_s[tid];
    }
}

// ------------------------------- softmax + label/value context aggregation
__global__ __launch_bounds__(256) void agg_kernel(
    const int* __restrict__ ctx_idx, const float* __restrict__ ctx_score,
    const float* __restrict__ cand_y, const float* __restrict__ T1b,
    const unsigned short* __restrict__ T1c, const float* __restrict__ T_b1,
    const float* __restrict__ x_batch,
    const float* __restrict__ label_w, const float* __restrict__ label_b,
    unsigned short* __restrict__ s_h, unsigned short* __restrict__ s_l,
    float* __restrict__ u_out)
{
    __shared__ float p_s[CTX];
    __shared__ int   p_i[CTX];
    __shared__ float s_ybar;
    int b = blockIdx.x, tid = threadIdx.x;
    if (tid < CTX) { p_s[tid] = ctx_score[b * CTX + tid]; p_i[tid] = ctx_idx[b * CTX + tid]; }
    __syncthreads();
    if (tid == 0) {
        float mx = -1e30f;
        for (int c = 0; c < CTX; c++) mx = fmaxf(mx, p_s[c]);
        float sum = 0.f;
        for (int c = 0; c < CTX; c++) { float e = __expf(p_s[c] - mx); p_s[c] = e; sum += e; }
        float inv = 1.f / sum, yb = 0.f;
        for (int c = 0; c < CTX; c++) { p_s[c] *= inv; yb += p_s[c] * cand_y[p_i[c]]; }
        s_ybar = yb;
    }
    __syncthreads();
    int j = tid * 4;
    float4 kv = *(const float4*)(T1b + (size_t)b * DBK + j);
    float4 tb = *(const float4*)(T_b1 + j);
    float base0 = kv.x + tb.x, base1 = kv.y + tb.y, base2 = kv.z + tb.z, base3 = kv.w + tb.w;
    float a0 = 0.f, a1 = 0.f, a2 = 0.f, a3 = 0.f;
    for (int c = 0; c < CTX; c++) {
        float p = p_s[c];
        ushort4 cu = *(const ushort4*)(T1c + (size_t)p_i[c] * DBK + j);
        a0 = fmaf(p, fmaxf(base0 - bf2f(cu.x), 0.f), a0);
        a1 = fmaf(p, fmaxf(base1 - bf2f(cu.y), 0.f), a1);
        a2 = fmaf(p, fmaxf(base2 - bf2f(cu.z), 0.f), a2);
        a3 = fmaf(p, fmaxf(base3 - bf2f(cu.w), 0.f), a3);
    }
    {
        ushort4 oh, ol;
        oh.x = f2bf(a0); ol.x = f2bf(a0 - bf2f(oh.x));
        oh.y = f2bf(a1); ol.y = f2bf(a1 - bf2f(oh.y));
        oh.z = f2bf(a2); ol.z = f2bf(a2 - bf2f(oh.z));
        oh.w = f2bf(a3); ol.w = f2bf(a3 - bf2f(oh.w));
        *(ushort4*)(s_h + (size_t)b * DBK + j) = oh;
        *(ushort4*)(s_l + (size_t)b * DBK + j) = ol;
    }
    if (tid < 128) {
        int d = tid * 4;
        float4 xv = *(const float4*)(x_batch + (size_t)b * DM + d);
        float4 lw = *(const float4*)(label_w + d);
        float4 lb = *(const float4*)(label_b + d);
        float yb = s_ybar;
        *(float4*)(u_out + (size_t)b * DM + d) =
            make_float4(xv.x + yb * lw.x + lb.x, xv.y + yb * lw.y + lb.y,
                        xv.z + yb * lw.z + lb.z, xv.w + yb * lw.w + lb.w);
    }
}

// ---------------------------------------------------------------- head
__global__ __launch_bounds__(256) void head_kernel(
    const float* __restrict__ X, const float* __restrict__ g,
    const float* __restrict__ bt, const float* __restrict__ w,
    const float* __restrict__ hb, float* __restrict__ out, int M)
{
    int wave = threadIdx.x >> 6, lane = threadIdx.x & 63;
    int row = blockIdx.x * 4 + wave;
    if (row >= M) return;
    const float* x = X + (size_t)row * DM;
    float4 v0 = ((const float4*)x)[lane * 2];
    float4 v1 = ((const float4*)x)[lane * 2 + 1];
    float s = v0.x + v0.y + v0.z + v0.w + v1.x + v1.y + v1.z + v1.w;
    #pragma unroll
    for (int off = 32; off; off >>= 1) s += __shfl_xor(s, off, 64);
    float m = s * (1.f / DM);
    float q = (v0.x - m) * (v0.x - m) + (v0.y - m) * (v0.y - m)
            + (v0.z - m) * (v0.z - m) + (v0.w - m) * (v0.w - m)
            + (v1.x - m) * (v1.x - m) + (v1.y - m) * (v1.y - m)
            + (v1.z - m) * (v1.z - m) + (v1.w - m) * (v1.w - m);
    #pragma unroll
    for (int off = 32; off; off >>= 1) q += __shfl_xor(q, off, 64);
    float rstd = 1.f / sqrtf(q * (1.f / DM) + 1e-5f);
    float4 g0 = ((const float4*)g)[lane * 2], g1 = ((const float4*)g)[lane * 2 + 1];
    float4 b0 = ((const float4*)bt)[lane * 2], b1 = ((const float4*)bt)[lane * 2 + 1];
    float4 w0 = ((const float4*)w)[lane * 2], w1 = ((const float4*)w)[lane * 2 + 1];
    float t = 0.f;
    t += fmaxf((v0.x - m) * rstd * g0.x + b0.x, 0.f) * w0.x;
    t += fmaxf((v0.y - m) * rstd * g0.y + b0.y, 0.f) * w0.y;
    t += fmaxf((v0.z - m) * rstd * g0.z + b0.z, 0.f) * w0.z;
    t += fmaxf((v0.w - m) * rstd * g0.w + b0.w, 0.f) * w0.w;
    t += fmaxf((v1.x - m) * rstd * g1.x + b1.x, 0.f) * w1.x;
    t += fmaxf((v1.y - m) * rstd * g1.y + b1.y, 0.f) * w1.y;
    t += fmaxf((v1.z - m) * rstd * g1.z + b1.z, 0.f) * w1.z;
    t += fmaxf((v1.w - m) * rstd * g1.w + b1.w, 0.f) * w1.w;
    #pragma unroll
    for (int off = 32; off; off >>= 1) t += __shfl_xor(t, off, 64);
    if (lane == 0) out[row] = t + hb[0];
}

// =================================================================== host
extern "C" void kernel_launch(void* const* d_in, const int* in_sizes, int n_in,
                              void* d_out, int out_size, void* d_ws, size_t ws_size,
                              hipStream_t stream) {
    (void)in_sizes; (void)n_in; (void)out_size;
    const float* x_num   = (const float*)d_in[0];
    const float* x_cat   = (const float*)d_in[1];
    const float* cxn     = (const float*)d_in[2];
    const float* cxc     = (const float*)d_in[3];
    const float* cand_y  = (const float*)d_in[4];
    const float* freq    = (const float*)d_in[6];
    const float* plr_w   = (const float*)d_in[7];
    const float* plr_b   = (const float*)d_in[8];
    const float* lin_w   = (const float*)d_in[9];
    const float* lin_b   = (const float*)d_in[10];
    const float* enc_w1  = (const float*)d_in[11];
    const float* enc_b1  = (const float*)d_in[12];
    const float* enc_w2  = (const float*)d_in[13];
    const float* enc_b2  = (const float*)d_in[14];
    const float* mix_g   = (const float*)d_in[15];
    const float* mix_b   = (const float*)d_in[16];
    const float* K_w     = (const float*)d_in[17];
    const float* K_b     = (const float*)d_in[18];
    const float* label_w = (const float*)d_in[19];
    const float* label_b = (const float*)d_in[20];
    const float* T_w1    = (const float*)d_in[21];
    const float* T_b1    = (const float*)d_in[22];
    const float* T_w2    = (const float*)d_in[23];
    const float* pred_g  = (const float*)d_in[24];
    const float* pred_b  = (const float*)d_in[25];
    const float* pred_w1 = (const float*)d_in[26];
    const float* pred_b1 = (const float*)d_in[27];
    const float* pred_w2 = (const float*)d_in[28];
    const float* pred_b2 = (const float*)d_in[29];
    const float* head_g  = (const float*)d_in[30];
    const float* head_b  = (const float*)d_in[31];
    const float* head_w  = (const float*)d_in[32];
    const float* head_bias = (const float*)d_in[33];
    float* out = (float*)d_out;

    char* ws = (char*)d_ws;
    size_t off = 0;
    auto alloc = [&](size_t n) { char* p = ws + off; off = (off + n + 255) & ~(size_t)255; return p; };

    typedef unsigned short u16;
    // --- bf16 weights (transposed to N x Kp), hi/lo ---
    u16* lin_wt_h = (u16*)alloc((size_t)DM * KP_IN * 2);
    u16* lin_wt_l = (u16*)alloc((size_t)DM * KP_IN * 2);
    u16* e1t_h    = (u16*)alloc((size_t)DBK * DM * 2);
    u16* e1t_l    = (u16*)alloc((size_t)DBK * DM * 2);
    u16* e2t_h    = (u16*)alloc((size_t)DM * DBK * 2);
    u16* e2t_l    = (u16*)alloc((size_t)DM * DBK * 2);
    u16* K_wt_h   = (u16*)alloc((size_t)DM * DM * 2);
    u16* K_wt_l   = (u16*)alloc((size_t)DM * DM * 2);
    u16* T_w1t    = (u16*)alloc((size_t)DBK * DM * 2);
    u16* T_w2t_h  = (u16*)alloc((size_t)DM * DBK * 2);
    u16* T_w2t_l  = (u16*)alloc((size_t)DM * DBK * 2);
    u16* p1t_h    = (u16*)alloc((size_t)DBK * DM * 2);
    u16* p1t_l    = (u16*)alloc((size_t)DBK * DM * 2);
    u16* p2t_h    = (u16*)alloc((size_t)DM * DBK * 2);
    u16* p2t_l    = (u16*)alloc((size_t)DM * DBK * 2);
    // --- persistent ---
    u16*   T1c  = (u16*)alloc((size_t)NCAND * DBK * 2);   // 102.4 MB
    float* T1b  = (float*)alloc((size_t)NB * DBK * 4);
    float* xB   = (float*)alloc((size_t)NB * DM * 4);
    u16*   kBh  = (u16*)alloc((size_t)NB * DM * 2);
    u16*   kBl  = (u16*)alloc((size_t)NB * DM * 2);
    // batch scratch
    u16* binh = (u16*)alloc((size_t)NB * KP_IN * 2);
    u16* binl = (u16*)alloc((size_t)NB * KP_IN * 2);
    u16* xBhh = (u16*)alloc((size_t)NB * DM * 2);
    u16* xBhl = (u16*)alloc((size_t)NB * DM * 2);
    u16* hBh  = (u16*)alloc((size_t)NB * DBK * 2);
    u16* hBl  = (u16*)alloc((size_t)NB * DBK * 2);
    u16* lnBh = (u16*)alloc((size_t)NB * DM * 2);
    u16* lnBl = (u16*)alloc((size_t)NB * DM * 2);
    // ctx + tail
    int*   ctxAi = (int*)alloc((size_t)NB * CTX * 4);
    float* ctxAs = (float*)alloc((size_t)NB * CTX * 4);
    int*   ctxBi = (int*)alloc((size_t)NB * CTX * 4);
    float* ctxBs = (float*)alloc((size_t)NB * CTX * 4);
    u16*   sbufh = (u16*)alloc((size_t)NB * DBK * 2);
    u16*   sbufl = (u16*)alloc((size_t)NB * DBK * 2);
    float* ubuf  = (float*)alloc((size_t)NB * DM * 4);
    float* x2    = (float*)alloc((size_t)NB * DM * 4);
    u16*   h2h   = (u16*)alloc((size_t)NB * DM * 2);
    u16*   h2l   = (u16*)alloc((size_t)NB * DM * 2);
    u16*   hph   = (u16*)alloc((size_t)NB * DBK * 2);
    u16*   hpl   = (u16*)alloc((size_t)NB * DBK * 2);
    float* x3    = (float*)alloc((size_t)NB * DM * 4);

    // --- chunk arenas with lifetime-based aliasing (11.5 KB/row) ---
    size_t remain = (ws_size > off + 8192) ? (ws_size - off - 8192) : 0;
    const size_t perrow = 3328 + 2048 + 2048 + 4096 + 64;
    long ncl = (long)(remain / perrow);
    int NC = (int)(ncl > NCMAX ? NCMAX : ncl);   // NCMAX: topk LDS cache bound
    NC &= ~127;
    if (NC < 256) NC = 256;
    char* arenaA = alloc((size_t)NC * 3328);   // inCh+inCl -> kC + cnC
    char* arenaB = alloc((size_t)NC * 2048);   // xC -> scoresC
    char* arenaC = alloc((size_t)NC * 2048);   // xCh/xCl -> lnCh/lnCl
    char* arenaD = alloc((size_t)NC * 4096);   // hCh/hCl -> kCh/kCl
    u16* inCh = (u16*)arenaA;
    u16* inCl = inCh + (size_t)NC * KP_IN;
    float* kC  = (float*)arenaA;                       // after lin: inC dead
    float* cnC = (float*)(arenaA + (size_t)NC * 2048);
    float* xC  = (float*)arenaB;
    float* scoresC = (float*)arenaB;                   // after ln: xC dead
    u16* xCh  = (u16*)arenaC;
    u16* xCl  = xCh + (size_t)NC * DM;
    u16* lnCh = (u16*)arenaC;                          // after enc1: xCh dead
    u16* lnCl = lnCh + (size_t)NC * DM;
    u16* hCh  = (u16*)arenaD;
    u16* hCl  = hCh + (size_t)NC * DBK;
    u16* kCh  = (u16*)arenaD;                          // after enc2: hC dead
    u16* kCl  = kCh + (size_t)NC * DM;

    auto bgemm = [&](const u16* A, const u16* Bt, int M, int N, int Kp,
                     float* Cf, u16* Cb, const float* bias, int flags) {
        dim3 grid((N + 127) / 128, (M + 127) / 128);
        bgemm_kernel<<<grid, 512, 0, stream>>>(A, Bt, M, N, Kp, Cf, Cb, bias, flags);
    };
    auto bgemm3 = [&](const u16* Ah, const u16* Al, const u16* Bh, const u16* Bl,
                      int M, int N, int Kp, float* Cf, u16* Cbh, u16* Cbl,
                      const float* bias, const float* resf, const float* cnorm, int flags) {
        dim3 grid((N + 127) / 128, (M + 127) / 128);
        bgemm3_kernel<<<grid, 512, 0, stream>>>(Ah, Al, Bh, Bl, M, N, Kp,
                                                Cf, Cbh, Cbl, bias, resf, cnorm, flags);
    };
    auto bgemm3s = [&](const u16* Ah, const u16* Al, const u16* Bh, const u16* Bl,
                       int M, int N, int Kp, float* Cf, u16* Cbh, u16* Cbl,
                       const float* bias, const float* resf, int flags) {
        dim3 grid((N + 63) / 64, (M + 63) / 64);
        bgemm3s_kernel<<<grid, 256, 0, stream>>>(Ah, Al, Bh, Bl, M, N, Kp,
                                                 Cf, Cbh, Cbl, bias, resf, flags);
    };
    auto wprep = [&](const float* W, int K, int N, int Kp, u16* Wh, u16* Wl) {
        int n = N * Kp;
        wprep_kernel<<<(n + 255) / 256, 256, 0, stream>>>(W, K, N, Kp, Wh, Wl);
    };

    // ---------- weight prep ----------
    wprep(lin_w, DIN, DM, KP_IN, lin_wt_h, lin_wt_l);
    wprep(enc_w1, DM, DBK, DM, e1t_h, e1t_l);
    wprep(enc_w2, DBK, DM, DBK, e2t_h, e2t_l);
    wprep(K_w, DM, DM, DM, K_wt_h, K_wt_l);
    wprep(T_w1, DM, DBK, DM, T_w1t, nullptr);
    wprep(T_w2, DBK, DM, DBK, T_w2t_h, T_w2t_l);
    wprep(pred_w1, DM, DBK, DM, p1t_h, p1t_l);
    wprep(pred_w2, DBK, DM, DBK, p2t_h, p2t_l);

    // ---------- batch encode (64-tile split GEMMs) ----------
    plr_bf16_kernel<<<(NB + 3) / 4, 256, 0, stream>>>(x_num, x_cat, NB, freq, plr_w, plr_b, binh, binl);
    bgemm3s(binh, binl, lin_wt_h, lin_wt_l, NB, DM, KP_IN, xB, xBhh, xBhl, lin_b, nullptr, 0);
    bgemm3s(xBhh, xBhl, e1t_h, e1t_l, NB, DBK, DM, nullptr, hBh, hBl, enc_b1, nullptr, BG_RELU);
    bgemm3s(hBh, hBl, e2t_h, e2t_l, NB, DM, DBK, xB, nullptr, nullptr, enc_b2, xB, 0);
    ln_split_kernel<<<(NB + 3) / 4, 256, 0, stream>>>(xB, lnBh, lnBl, mix_g, mix_b, NB);
    bgemm3s(lnBh, lnBl, K_wt_h, K_wt_l, NB, DM, DM, nullptr, kBh, kBl, K_b, nullptr, 0);
    bgemm3s(kBh, nullptr, T_w1t, nullptr, NB, DBK, DM, T1b, nullptr, nullptr, nullptr, nullptr, 0);
    ctx_init_kernel<<<(NB * CTX + 255) / 256, 256, 0, stream>>>(ctxAi, ctxAs);

    // ---------- candidate chunks (128-tile, 512-thread GEMMs) ----------
    const int* pI = ctxAi; const float* pS = ctxAs;
    int* nI = ctxBi; float* nS = ctxBs;
    int nch = (NCAND + NC - 1) / NC;
    for (int c = 0; c < nch; c++) {
        int s = c * NC;
        int m = NCAND - s; if (m > NC) m = NC;
        plr_bf16_kernel<<<(m + 3) / 4, 256, 0, stream>>>(cxn + (size_t)s * NFEAT,
                                                         cxc + (size_t)s * NCAT,
                                                         m, freq, plr_w, plr_b, inCh, inCl);
        bgemm3(inCh, inCl, lin_wt_h, lin_wt_l, m, DM, KP_IN, xC, xCh, xCl, lin_b, nullptr, nullptr, 0);
        bgemm3(xCh, xCl, e1t_h, e1t_l, m, DBK, DM, nullptr, hCh, hCl, enc_b1, nullptr, nullptr, BG_RELU);
        bgemm3(hCh, hCl, e2t_h, e2t_l, m, DM, DBK, xC, nullptr, nullptr, enc_b2, xC, nullptr, 0);
        ln_split_kernel<<<(m + 3) / 4, 256, 0, stream>>>(xC, lnCh, lnCl, mix_g, mix_b, m);
        bgemm3(lnCh, lnCl, K_wt_h, K_wt_l, m, DM, DM, kC, kCh, kCl, K_b, nullptr, nullptr, 0);
        cnorm_kernel<<<(m + 3) / 4, 256, 0, stream>>>(kC, cnC, m);
        bgemm(kCh, T_w1t, m, DBK, DM, nullptr, T1c + (size_t)s * DBK, nullptr, 0);
        bgemm3(kBh, kBl, kCh, kCl, NB, m, DM, scoresC, nullptr, nullptr,
               nullptr, nullptr, cnC, BG_SCORE);
        topk_merge_kernel<<<NB, 256, 0, stream>>>(scoresC, m, s, pI, pS, nI, nS);
        { const int* t = pI; pI = nI; nI = (int*)t; }
        { const float* t = pS; pS = nS; nS = (float*)t; }
    }

    // ---------- aggregation + predictor + head (64-tile split GEMMs) ----------
    agg_kernel<<<NB, 256, 0, stream>>>(pI, pS, cand_y, T1b, T1c, T_b1,
                                       xB, label_w, label_b, sbufh, sbufl, ubuf);
    bgemm3s(sbufh, sbufl, T_w2t_h, T_w2t_l, NB, DM, DBK, x2, nullptr, nullptr,
            nullptr, ubuf, 0);
    ln_split_kernel<<<(NB + 3) / 4, 256, 0, stream>>>(x2, h2h, h2l, pred_g, pred_b, NB);
    bgemm3s(h2h, h2l, p1t_h, p1t_l, NB, DBK, DM, nullptr, hph, hpl, pred_b1, nullptr, BG_RELU);
    bgemm3s(hph, hpl, p2t_h, p2t_l, NB, DM, DBK, x3, nullptr, nullptr, pred_b2, x2, 0);
    head_kernel<<<(NB + 3) / 4, 256, 0, stream>>>(x3, head_g, head_b, head_w, head_bias, out, NB);
}

// Round 9
// 2348.898 us; speedup vs baseline: 1.3807x; 1.3807x over previous
//
#include <hip/hip_runtime.h>

#define NCAND 50000
#define NB    512
#define DIN   820
#define KP_IN 832
#define DM    512
#define DBK   1024
#define NFEAT 50
#define NCAT  20
#define NFREQ 16
#define DEMB  16
#define CTX   96
#define NCMAX 9216
#define TOTMAX (NCMAX + CTX)

typedef __attribute__((ext_vector_type(8))) short short8;
typedef __attribute__((ext_vector_type(4))) float f32x4;

static __device__ __forceinline__ unsigned short f2bf(float f) {
    union { float f; unsigned int i; } u; u.f = f;
    unsigned int r = u.i + 0x7FFFu + ((u.i >> 16) & 1u);
    return (unsigned short)(r >> 16);
}
static __device__ __forceinline__ float bf2f(unsigned short s) {
    union { unsigned int i; float f; } u; u.i = ((unsigned int)s) << 16;
    return u.f;
}
// order-preserving float->uint key (ascending), exact bijection
static __device__ __forceinline__ unsigned int f2key(float f) {
    union { float f; unsigned int i; } u; u.f = f;
    return (u.i & 0x80000000u) ? ~u.i : (u.i | 0x80000000u);
}
static __device__ __forceinline__ float key2f(unsigned int k) {
    union { unsigned int i; float f; } u;
    u.i = (k & 0x80000000u) ? (k ^ 0x80000000u) : ~k;
    return u.f;
}

#define GLDS16(g, l) __builtin_amdgcn_global_load_lds( \
    (const __attribute__((address_space(1))) void*)(g), \
    (__attribute__((address_space(3))) void*)(l), 16, 0, 0)

#define BG_RELU  1
#define BG_SCORE 2

// LDS chunk swizzle: physical chunk c_p at row r holds logical chunk (c_p - (r>>1))&3.
// Staging (GLDS16, lane covers row base+(lane>>2), phys chunk lane&3):
//   scol = (((lane&3) - ((lane>>3)&3)) & 3) * 8      [valid: base row multiple of 16]
// Read (logical chunk q at row wr+i*16+fr, wr mult of 32):
//   pcs  = ((q + (fr>>1)) & 3) * 8

// ---------------------------------------------------------------- weight prep
__global__ __launch_bounds__(256) void wprep_kernel(
    const float* __restrict__ W, int K, int N, int Kp,
    unsigned short* __restrict__ Wh, unsigned short* __restrict__ Wl)
{
    int idx = blockIdx.x * 256 + threadIdx.x;
    if (idx >= N * Kp) return;
    int n = idx / Kp, k = idx % Kp;
    float v = (k < K) ? W[(size_t)k * N + n] : 0.f;
    unsigned short h = f2bf(v);
    Wh[idx] = h;
    if (Wl) Wl[idx] = f2bf(v - bf2f(h));
}

// ---------------------------------------------------------------- PLR encode (bf16 hi/lo out)
__global__ __launch_bounds__(256) void plr_bf16_kernel(
    const float* __restrict__ xn_, const float* __restrict__ xc_, int nrows,
    const float* __restrict__ freq, const float* __restrict__ plr_w,
    const float* __restrict__ plr_b,
    unsigned short* __restrict__ oh, unsigned short* __restrict__ ol)
{
    __shared__ float sW[32 * 16];
    __shared__ float sB[16];
    __shared__ float sF[NFEAT * NFREQ];
    int tid = threadIdx.x;
    for (int i = tid; i < 512; i += 256) sW[i] = plr_w[i];
    if (tid < 16) sB[tid] = plr_b[tid];
    for (int i = tid; i < NFEAT * NFREQ; i += 256) sF[i] = freq[i];
    __syncthreads();
    int wave = tid >> 6, lane = tid & 63;
    int row = blockIdx.x * 4 + wave;
    if (row >= nrows) return;
    const float* xn = xn_ + (size_t)row * NFEAT;
    const float* xc = xc_ + (size_t)row * NCAT;
    unsigned short* ph = oh + (size_t)row * KP_IN;
    unsigned short* pl = ol + (size_t)row * KP_IN;
    if (lane < NFEAT) {
        float x = xn[lane];
        float cs[NFREQ], sn[NFREQ];
        #pragma unroll
        for (int j = 0; j < NFREQ; j++) {
            float p = 6.28318530717958647692f * sF[lane * NFREQ + j] * x;
            sn[j] = __sinf(p);
            cs[j] = __cosf(p);
        }
        #pragma unroll
        for (int d = 0; d < DEMB; d++) {
            float acc = sB[d];
            #pragma unroll
            for (int j = 0; j < NFREQ; j++)
                acc = fmaf(cs[j], sW[j * DEMB + d], fmaf(sn[j], sW[(NFREQ + j) * DEMB + d], acc));
            float v = fmaxf(acc, 0.f);
            unsigned short h = f2bf(v);
            ph[lane * DEMB + d] = h;
            pl[lane * DEMB + d] = f2bf(v - bf2f(h));
        }
    }
    if (lane < NCAT) {
        float v = xc[lane];
        unsigned short h = f2bf(v);
        ph[800 + lane] = h;
        pl[800 + lane] = f2bf(v - bf2f(h));
    }
    if (lane >= NCAT && lane < 32) {
        ph[800 + lane] = 0;
        pl[800 + lane] = 0;
    }
}

// ------------------------------- bf16 MFMA GEMM (plain 1-term), 128 tile, 512 threads
__global__ __launch_bounds__(512) void bgemm_kernel(
    const unsigned short* __restrict__ A, const unsigned short* __restrict__ Bt,
    int M, int N, int Kp,
    float* __restrict__ Cf, unsigned short* __restrict__ Cb,
    const float* __restrict__ bias, int flags)
{
    __shared__ unsigned short As[128 * 32];
    __shared__ unsigned short Bs[128 * 32];
    int tid = threadIdx.x;
    int w = tid >> 6, lane = tid & 63;
    int m0 = blockIdx.y * 128, n0 = blockIdx.x * 128;
    int wr = (w >> 1) * 32, wc = (w & 1) * 64;

    f32x4 acc[2][4];
    #pragma unroll
    for (int i = 0; i < 2; i++)
        #pragma unroll
        for (int j = 0; j < 4; j++) acc[i][j] = (f32x4){0.f, 0.f, 0.f, 0.f};

    int arr = w & 1;
    int qrt = (w >> 1) * 32;
    int scol = (((lane & 3) - ((lane >> 3) & 3)) & 3) * 8;
    const unsigned short* gsrc = arr ? Bt : A;
    int glim = arr ? (N - 1) : (M - 1);
    int gb   = arr ? n0 : m0;
    unsigned short* ldst = arr ? Bs : As;
    const unsigned short* gp0 = gsrc + (size_t)min(gb + qrt + (lane >> 2),      glim) * Kp + scol;
    const unsigned short* gp1 = gsrc + (size_t)min(gb + qrt + 16 + (lane >> 2), glim) * Kp + scol;
    unsigned short* lp0 = ldst + qrt * 32;
    unsigned short* lp1 = ldst + (qrt + 16) * 32;

    int fr = lane & 15, q = lane >> 4;
    int pcs = ((q + (fr >> 1)) & 3) * 8;

    for (int k0 = 0; k0 < Kp; k0 += 32) {
        __syncthreads();
        GLDS16(gp0 + k0, lp0);
        GLDS16(gp1 + k0, lp1);
        __syncthreads();
        short8 a[2], b[4];
        #pragma unroll
        for (int i = 0; i < 2; i++)
            a[i] = *(const short8*)&As[(wr + i * 16 + fr) * 32 + pcs];
        #pragma unroll
        for (int j = 0; j < 4; j++)
            b[j] = *(const short8*)&Bs[(wc + j * 16 + fr) * 32 + pcs];
        #pragma unroll
        for (int i = 0; i < 2; i++)
            #pragma unroll
            for (int j = 0; j < 4; j++)
                acc[i][j] = __builtin_amdgcn_mfma_f32_16x16x32_bf16(a[i], b[j], acc[i][j], 0, 0, 0);
    }

    int col = lane & 15, rq = (lane >> 4) * 4;
    #pragma unroll
    for (int i = 0; i < 2; i++)
        #pragma unroll
        for (int j = 0; j < 4; j++) {
            int n_g = n0 + wc + j * 16 + col;
            #pragma unroll
            for (int r = 0; r < 4; r++) {
                int m_g = m0 + wr + i * 16 + rq + r;
                if (m_g < M && n_g < N) {
                    float v = acc[i][j][r];
                    if (bias) v += bias[n_g];
                    if (flags & BG_RELU) v = fmaxf(v, 0.f);
                    if (Cf) Cf[(size_t)m_g * N + n_g] = v;
                    if (Cb) Cb[(size_t)m_g * N + n_g] = f2bf(v);
                }
            }
        }
}

// ------------------------- bf16 MFMA GEMM, 3-term split, 128 tile, 512 threads
__global__ __launch_bounds__(512) void bgemm3_kernel(
    const unsigned short* __restrict__ Ah, const unsigned short* __restrict__ Al,
    const unsigned short* __restrict__ Bh, const unsigned short* __restrict__ Bl,
    int M, int N, int Kp,
    float* __restrict__ Cf, unsigned short* __restrict__ Cbh, unsigned short* __restrict__ Cbl,
    const float* __restrict__ bias, const float* __restrict__ resf,
    const float* __restrict__ cnorm, int flags)
{
    __shared__ unsigned short Ash[128 * 32];
    __shared__ unsigned short Asl[128 * 32];
    __shared__ unsigned short Bsh[128 * 32];
    __shared__ unsigned short Bsl[128 * 32];
    int tid = threadIdx.x;
    int w = tid >> 6, lane = tid & 63;
    int m0 = blockIdx.y * 128, n0 = blockIdx.x * 128;
    int wr = (w >> 1) * 32, wc = (w & 1) * 64;

    f32x4 acc[2][4];
    #pragma unroll
    for (int i = 0; i < 2; i++)
        #pragma unroll
        for (int j = 0; j < 4; j++) acc[i][j] = (f32x4){0.f, 0.f, 0.f, 0.f};

    int arr = w & 3;
    int half = (w >> 2) * 64;
    int scol = (((lane & 3) - ((lane >> 3) & 3)) & 3) * 8;
    const unsigned short* gsrc = (arr == 0) ? Ah : (arr == 1) ? Al : (arr == 2) ? Bh : Bl;
    int glim = (arr < 2) ? (M - 1) : (N - 1);
    int gb   = (arr < 2) ? m0 : n0;
    unsigned short* ldst = (arr == 0) ? Ash : (arr == 1) ? Asl : (arr == 2) ? Bsh : Bsl;
    const unsigned short* gp[4];
    unsigned short* lp[4];
    #pragma unroll
    for (int t = 0; t < 4; t++) {
        int r = half + t * 16;
        gp[t] = gsrc + (size_t)min(gb + r + (lane >> 2), glim) * Kp + scol;
        lp[t] = ldst + r * 32;
    }

    int fr = lane & 15, q = lane >> 4;
    int pcs = ((q + (fr >> 1)) & 3) * 8;

    for (int k0 = 0; k0 < Kp; k0 += 32) {
        __syncthreads();
        GLDS16(gp[0] + k0, lp[0]);
        GLDS16(gp[1] + k0, lp[1]);
        GLDS16(gp[2] + k0, lp[2]);
        GLDS16(gp[3] + k0, lp[3]);
        __syncthreads();
        short8 a[2], b[4];
        #pragma unroll
        for (int i = 0; i < 2; i++)
            a[i] = *(const short8*)&Ash[(wr + i * 16 + fr) * 32 + pcs];
        #pragma unroll
        for (int j = 0; j < 4; j++)
            b[j] = *(const short8*)&Bsh[(wc + j * 16 + fr) * 32 + pcs];
        #pragma unroll
        for (int i = 0; i < 2; i++)
            #pragma unroll
            for (int j = 0; j < 4; j++)
                acc[i][j] = __builtin_amdgcn_mfma_f32_16x16x32_bf16(a[i], b[j], acc[i][j], 0, 0, 0);
        short8 al2[2];
        #pragma unroll
        for (int i = 0; i < 2; i++)
            al2[i] = *(const short8*)&Asl[(wr + i * 16 + fr) * 32 + pcs];
        #pragma unroll
        for (int i = 0; i < 2; i++)
            #pragma unroll
            for (int j = 0; j < 4; j++)
                acc[i][j] = __builtin_amdgcn_mfma_f32_16x16x32_bf16(al2[i], b[j], acc[i][j], 0, 0, 0);
        short8 bl2[4];
        #pragma unroll
        for (int j = 0; j < 4; j++)
            bl2[j] = *(const short8*)&Bsl[(wc + j * 16 + fr) * 32 + pcs];
        #pragma unroll
        for (int i = 0; i < 2; i++)
            #pragma unroll
            for (int j = 0; j < 4; j++)
                acc[i][j] = __builtin_amdgcn_mfma_f32_16x16x32_bf16(a[i], bl2[j], acc[i][j], 0, 0, 0);
    }

    int col = lane & 15, rq = (lane >> 4) * 4;
    #pragma unroll
    for (int i = 0; i < 2; i++)
        #pragma unroll
        for (int j = 0; j < 4; j++) {
            int n_g = n0 + wc + j * 16 + col;
            #pragma unroll
            for (int r = 0; r < 4; r++) {
                int m_g = m0 + wr + i * 16 + rq + r;
                if (m_g < M && n_g < N) {
                    float v = acc[i][j][r];
                    if (bias) v += bias[n_g];
                    if (resf) v += resf[(size_t)m_g * N + n_g];
                    if (flags & BG_RELU) v = fmaxf(v, 0.f);
                    if (flags & BG_SCORE) v = 2.f * v - cnorm[n_g];
                    if (Cf) Cf[(size_t)m_g * N + n_g] = v;
                    if (Cbh) {
                        unsigned short h = f2bf(v);
                        Cbh[(size_t)m_g * N + n_g] = h;
                        if (Cbl) Cbl[(size_t)m_g * N + n_g] = f2bf(v - bf2f(h));
                    }
                }
            }
        }
}

// ------------------------- small-M GEMM: 64x64 tile, 1- or 3-term (Al null => 1-term)
__global__ __launch_bounds__(256) void bgemm3s_kernel(
    const unsigned short* __restrict__ Ah, const unsigned short* __restrict__ Al,
    const unsigned short* __restrict__ Bh, const unsigned short* __restrict__ Bl,
    int M, int N, int Kp,
    float* __restrict__ Cf, unsigned short* __restrict__ Cbh, unsigned short* __restrict__ Cbl,
    const float* __restrict__ bias, const float* __restrict__ resf, int flags)
{
    __shared__ unsigned short Ash[64 * 32];
    __shared__ unsigned short Asl[64 * 32];
    __shared__ unsigned short Bsh[64 * 32];
    __shared__ unsigned short Bsl[64 * 32];
    int tid = threadIdx.x;
    int w = tid >> 6, lane = tid & 63;
    int m0 = blockIdx.y * 64, n0 = blockIdx.x * 64;
    int wr = (w >> 1) * 32, wc = (w & 1) * 32;
    int three = (Al != nullptr);

    f32x4 acc[2][2];
    #pragma unroll
    for (int i = 0; i < 2; i++)
        #pragma unroll
        for (int j = 0; j < 2; j++) acc[i][j] = (f32x4){0.f, 0.f, 0.f, 0.f};

    int srow = w * 16 + (lane >> 2);
    int scol = (((lane & 3) - ((lane >> 3) & 3)) & 3) * 8;
    size_t ra = (size_t)min(m0 + srow, M - 1) * Kp + scol;
    size_t rb = (size_t)min(n0 + srow, N - 1) * Kp + scol;
    unsigned short* lah = &Ash[(w * 16) * 32];
    unsigned short* lal = &Asl[(w * 16) * 32];
    unsigned short* lbh = &Bsh[(w * 16) * 32];
    unsigned short* lbl = &Bsl[(w * 16) * 32];

    int fr = lane & 15, q = lane >> 4;
    int pcs = ((q + (fr >> 1)) & 3) * 8;

    for (int k0 = 0; k0 < Kp; k0 += 32) {
        __syncthreads();
        GLDS16(Ah + ra + k0, lah);
        GLDS16(Bh + rb + k0, lbh);
        if (three) {
            GLDS16(Al + ra + k0, lal);
            GLDS16(Bl + rb + k0, lbl);
        }
        __syncthreads();
        short8 a[2], b[2];
        #pragma unroll
        for (int i = 0; i < 2; i++)
            a[i] = *(const short8*)&Ash[(wr + i * 16 + fr) * 32 + pcs];
        #pragma unroll
        for (int j = 0; j < 2; j++)
            b[j] = *(const short8*)&Bsh[(wc + j * 16 + fr) * 32 + pcs];
        #pragma unroll
        for (int i = 0; i < 2; i++)
            #pragma unroll
            for (int j = 0; j < 2; j++)
                acc[i][j] = __builtin_amdgcn_mfma_f32_16x16x32_bf16(a[i], b[j], acc[i][j], 0, 0, 0);
        if (three) {
            short8 al2[2], bl2[2];
            #pragma unroll
            for (int i = 0; i < 2; i++)
                al2[i] = *(const short8*)&Asl[(wr + i * 16 + fr) * 32 + pcs];
            #pragma unroll
            for (int j = 0; j < 2; j++)
                bl2[j] = *(const short8*)&Bsl[(wc + j * 16 + fr) * 32 + pcs];
            #pragma unroll
            for (int i = 0; i < 2; i++)
                #pragma unroll
                for (int j = 0; j < 2; j++) {
                    acc[i][j] = __builtin_amdgcn_mfma_f32_16x16x32_bf16(al2[i], b[j], acc[i][j], 0, 0, 0);
                    acc[i][j] = __builtin_amdgcn_mfma_f32_16x16x32_bf16(a[i], bl2[j], acc[i][j], 0, 0, 0);
                }
        }
    }

    int col = lane & 15, rq = (lane >> 4) * 4;
    #pragma unroll
    for (int i = 0; i < 2; i++)
        #pragma unroll
        for (int j = 0; j < 2; j++) {
            int n_g = n0 + wc + j * 16 + col;
            #pragma unroll
            for (int r = 0; r < 4; r++) {
                int m_g = m0 + wr + i * 16 + rq + r;
                if (m_g < M && n_g < N) {
                    float v = acc[i][j][r];
                    if (bias) v += bias[n_g];
                    if (resf) v += resf[(size_t)m_g * N + n_g];
                    if (flags & BG_RELU) v = fmaxf(v, 0.f);
                    if (Cf) Cf[(size_t)m_g * N + n_g] = v;
                    if (Cbh) {
                        unsigned short h = f2bf(v);
                        Cbh[(size_t)m_g * N + n_g] = h;
                        if (Cbl) Cbl[(size_t)m_g * N + n_g] = f2bf(v - bf2f(h));
                    }
                }
            }
        }
}

// ---------------------------------------------------------------- LayerNorm bf16 hi/lo out
__global__ __launch_bounds__(256) void ln_split_kernel(const float* __restrict__ X,
    unsigned short* __restrict__ Yh, unsigned short* __restrict__ Yl,
    const float* __restrict__ g, const float* __restrict__ bt, int M)
{
    int wave = threadIdx.x >> 6, lane = threadIdx.x & 63;
    int row = blockIdx.x * 4 + wave;
    if (row >= M) return;
    const float* x = X + (size_t)row * DM;
    float4 v0 = ((const float4*)x)[lane * 2];
    float4 v1 = ((const float4*)x)[lane * 2 + 1];
    float s = v0.x + v0.y + v0.z + v0.w + v1.x + v1.y + v1.z + v1.w;
    #pragma unroll
    for (int off = 32; off; off >>= 1) s += __shfl_xor(s, off, 64);
    float m = s * (1.f / DM);
    float q = (v0.x - m) * (v0.x - m) + (v0.y - m) * (v0.y - m)
            + (v0.z - m) * (v0.z - m) + (v0.w - m) * (v0.w - m)
            + (v1.x - m) * (v1.x - m) + (v1.y - m) * (v1.y - m)
            + (v1.z - m) * (v1.z - m) + (v1.w - m) * (v1.w - m);
    #pragma unroll
    for (int off = 32; off; off >>= 1) q += __shfl_xor(q, off, 64);
    float rstd = 1.f / sqrtf(q * (1.f / DM) + 1e-5f);
    float vals[8] = {v0.x, v0.y, v0.z, v0.w, v1.x, v1.y, v1.z, v1.w};
    unsigned short* yh = Yh + (size_t)row * DM + lane * 8;
    unsigned short* yl = Yl + (size_t)row * DM + lane * 8;
    const float* gp = g + lane * 8;
    const float* bp = bt + lane * 8;
    #pragma unroll
    for (int i = 0; i < 8; i++) {
        float y = (vals[i] - m) * rstd * gp[i] + bp[i];
        unsigned short h = f2bf(y);
        yh[i] = h;
        yl[i] = f2bf(y - bf2f(h));
    }
}

// ---------------------------------------------------------------- key norms (fp32 k)
__global__ __launch_bounds__(256) void cnorm_kernel(const float* __restrict__ Kc,
    float* __restrict__ cn, int N)
{
    int wave = threadIdx.x >> 6, lane = threadIdx.x & 63;
    int row = blockIdx.x * 4 + wave;
    if (row >= N) return;
    const float* x = Kc + (size_t)row * DM;
    float4 v0 = ((const float4*)x)[lane * 2];
    float4 v1 = ((const float4*)x)[lane * 2 + 1];
    float s = v0.x * v0.x + v0.y * v0.y + v0.z * v0.z + v0.w * v0.w
            + v1.x * v1.x + v1.y * v1.y + v1.z * v1.z + v1.w * v1.w;
    #pragma unroll
    for (int off = 32; off; off >>= 1) s += __shfl_xor(s, off, 64);
    if (lane == 0) cn[row] = s;
}

// ---------------------------------------------------------------- ctx init
__global__ void ctx_init_kernel(int* __restrict__ idx, float* __restrict__ sc)
{
    int i = blockIdx.x * 256 + threadIdx.x;
    if (i < NB * CTX) { idx[i] = 0; sc[i] = -1e30f; }
}

// ------------------------------------- running top-96 merge: exact radix select
// LDS key cache + hybrid histogram (wave-uniform fast path, else plain atomics)
// + per-wave privatized histograms. Deterministic: (score desc, idx asc) order.
#define CANDCAP 2048
__global__ __launch_bounds__(256) void topk_merge_kernel(
    const float* __restrict__ S, int m, int base,
    const int* __restrict__ pidx, const float* __restrict__ pscore,
    int* __restrict__ nidx, float* __restrict__ nscore)
{
    __shared__ __align__(16) unsigned int ks[TOTMAX];
    __shared__ unsigned int hist[4 * 256];
    __shared__ unsigned int s_prefix;
    __shared__ int s_above;
    __shared__ int prev_i[CTX];
    __shared__ int nsel, neq;
    __shared__ float sel_s[CTX];
    __shared__ int   sel_g[CTX];
    __shared__ int   cnd_g[CANDCAP];

    int b = blockIdx.x, tid = threadIdx.x;
    int lane = tid & 63, wv = tid >> 6;
    const float* Sb = S + (size_t)b * m;
    int tot = m + CTX;

    // stage keys into LDS (one global pass, vectorized, key-converted once)
    int m4 = m >> 2;
    const float4* S4 = (const float4*)Sb;
    for (int i = tid; i < m4; i += 256) {
        float4 v = S4[i];
        uint4 kk;
        kk.x = f2key(v.x); kk.y = f2key(v.y); kk.z = f2key(v.z); kk.w = f2key(v.w);
        ((uint4*)ks)[i] = kk;
    }
    for (int i = (m4 << 2) + tid; i < m; i += 256) ks[i] = f2key(Sb[i]);
    if (tid < CTX) {
        ks[m + tid] = f2key(pscore[b * CTX + tid]);
        prev_i[tid] = pidx[b * CTX + tid];
    }
    if (tid == 0) { s_prefix = 0u; s_above = 0; nsel = 0; neq = 0; }
    __syncthreads();

    unsigned int* myhist = &hist[wv * 256];

    // 4 radix passes, MSB-first, over LDS keys
    for (int pass = 0; pass < 4; pass++) {
        int shift = 24 - pass * 8;
        for (int i = tid; i < 1024; i += 256) hist[i] = 0;
        __syncthreads();
        unsigned int pref = s_prefix;
        unsigned int msk = (pass == 0) ? 0u : (0xFFFFFFFFu << (32 - 8 * pass));
        for (int i0 = 0; i0 < tot; i0 += 256) {
            int i = i0 + tid;
            int pred = 0, digit = 0;
            if (i < tot) {
                unsigned int k = ks[i];
                pred = ((k & msk) == pref);
                digit = (int)((k >> shift) & 255u);
            }
            unsigned long long act = __ballot(pred);
            if (!act) continue;
            int lead = (int)__ffsll(act) - 1;
            int d0 = __shfl(digit, lead, 64);
            unsigned long long same = __ballot(pred && (digit == d0));
            if (same == act) {
                // whole wave shares one digit: single aggregated atomic
                if (lane == lead) atomicAdd(&myhist[d0], (unsigned int)__popcll(act));
            } else {
                // diverse digits: HW-serialized atomics are near-conflict-free
                if (pred) atomicAdd(&myhist[digit], 1u);
            }
        }
        __syncthreads();
        unsigned int hm = 0;
        if (tid < 256) hm = hist[tid] + hist[256 + tid] + hist[512 + tid] + hist[768 + tid];
        __syncthreads();
        if (tid < 256) hist[tid] = hm;
        __syncthreads();
        if (tid == 0) {
            int above = s_above, bsel = 0;
            for (int i2 = 255; i2 >= 0; i2--) {
                int h = (int)hist[i2];
                if (above + h >= CTX) { bsel = i2; break; }
                above += h;
            }
            s_above = above;
            s_prefix = pref | ((unsigned int)bsel << shift);
        }
        __syncthreads();
    }
    unsigned int thrK = s_prefix;
    int msel = CTX - s_above;          // take msel among key==thrK by smallest idx
    float eqv = key2f(thrK);

    // collect: strictly above -> selected; equal -> candidates
    for (int i = tid; i < tot; i += 256) {
        unsigned int k = ks[i];
        if (k < thrK) continue;
        int g = (i < m) ? (base + i) : prev_i[i - m];
        if (k > thrK) {
            int p = atomicAdd(&nsel, 1);
            sel_s[p] = key2f(k); sel_g[p] = g;
        } else {
            int p = atomicAdd(&neq, 1);
            if (p < CANDCAP) cnd_g[p] = g;
        }
    }
    __syncthreads();
    int ne = neq;
    if (ne <= CANDCAP) {
        for (int i = tid; i < ne; i += 256) {
            int gi = cnd_g[i];
            int rank = 0;
            for (int j = 0; j < ne; j++) rank += (cnd_g[j] < gi);
            if (rank < msel) {
                int p = atomicAdd(&nsel, 1);
                sel_s[p] = eqv; sel_g[p] = gi;
            }
        }
    } else {
        // pathological mass-tie fallback: deterministic idx-rank via full LDS scan
        for (int i = tid; i < tot; i += 256) {
            if (ks[i] != thrK) continue;
            int g = (i < m) ? (base + i) : prev_i[i - m];
            int rank = 0;
            for (int j = 0; j < tot; j++) {
                if (ks[j] == thrK) {
                    int gj = (j < m) ? (base + j) : prev_i[j - m];
                    rank += (gj < g);
                }
            }
            if (rank < msel) {
                int p = atomicAdd(&nsel, 1);
                sel_s[p] = eqv; sel_g[p] = g;
            }
        }
    }
    __syncthreads();
    if (tid < CTX) {
        nidx[b * CTX + tid] = sel_g[tid];
        nscore[b * CTX + tid] = sel_s[tid];
    }
}

// ------------------------------- softmax + label/value context aggregation
__global__ __launch_bounds__(256) void agg_kernel(
    const int* __restrict__ ctx_idx, const float* __restrict__ ctx_score,
    const float* __restrict__ cand_y, const float* __restrict__ T1b,
    const unsigned short* __restrict__ T1c, const float* __restrict__ T_b1,
    const float* __restrict__ x_batch,
    const float* __restrict__ label_w, const float* __restrict__ label_b,
    unsigned short* __restrict__ s_h, unsigned short* __restrict__ s_l,
    float* __restrict__ u_out)
{
    __shared__ float p_s[CTX];
    __shared__ int   p_i[CTX];
    __shared__ float s_ybar;
    int b = blockIdx.x, tid = threadIdx.x;
    if (tid < CTX) { p_s[tid] = ctx_score[b * CTX + tid]; p_i[tid] = ctx_idx[b * CTX + tid]; }
    __syncthreads();
    if (tid == 0) {
        float mx = -1e30f;
        for (int c = 0; c < CTX; c++) mx = fmaxf(mx, p_s[c]);
        float sum = 0.f;
        for (int c = 0; c < CTX; c++) { float e = __expf(p_s[c] - mx); p_s[c] = e; sum += e; }
        float inv = 1.f / sum, yb = 0.f;
        for (int c = 0; c < CTX; c++) { p_s[c] *= inv; yb += p_s[c] * cand_y[p_i[c]]; }
        s_ybar = yb;
    }
    __syncthreads();
    int j = tid * 4;
    float4 kv = *(const float4*)(T1b + (size_t)b * DBK + j);
    float4 tb = *(const float4*)(T_b1 + j);
    float base0 = kv.x + tb.x, base1 = kv.y + tb.y, base2 = kv.z + tb.z, base3 = kv.w + tb.w;
    float a0 = 0.f, a1 = 0.f, a2 = 0.f, a3 = 0.f;
    for (int c = 0; c < CTX; c++) {
        float p = p_s[c];
        ushort4 cu = *(const ushort4*)(T1c + (size_t)p_i[c] * DBK + j);
        a0 = fmaf(p, fmaxf(base0 - bf2f(cu.x), 0.f), a0);
        a1 = fmaf(p, fmaxf(base1 - bf2f(cu.y), 0.f), a1);
        a2 = fmaf(p, fmaxf(base2 - bf2f(cu.z), 0.f), a2);
        a3 = fmaf(p, fmaxf(base3 - bf2f(cu.w), 0.f), a3);
    }
    {
        ushort4 oh, ol;
        oh.x = f2bf(a0); ol.x = f2bf(a0 - bf2f(oh.x));
        oh.y = f2bf(a1); ol.y = f2bf(a1 - bf2f(oh.y));
        oh.z = f2bf(a2); ol.z = f2bf(a2 - bf2f(oh.z));
        oh.w = f2bf(a3); ol.w = f2bf(a3 - bf2f(oh.w));
        *(ushort4*)(s_h + (size_t)b * DBK + j) = oh;
        *(ushort4*)(s_l + (size_t)b * DBK + j) = ol;
    }
    if (tid < 128) {
        int d = tid * 4;
        float4 xv = *(const float4*)(x_batch + (size_t)b * DM + d);
        float4 lw = *(const float4*)(label_w + d);
        float4 lb = *(const float4*)(label_b + d);
        float yb = s_ybar;
        *(float4*)(u_out + (size_t)b * DM + d) =
            make_float4(xv.x + yb * lw.x + lb.x, xv.y + yb * lw.y + lb.y,
                        xv.z + yb * lw.z + lb.z, xv.w + yb * lw.w + lb.w);
    }
}

// ---------------------------------------------------------------- head
__global__ __launch_bounds__(256) void head_kernel(
    const float* __restrict__ X, const float* __restrict__ g,
    const float* __restrict__ bt, const float* __restrict__ w,
    const float* __restrict__ hb, float* __restrict__ out, int M)
{
    int wave = threadIdx.x >> 6, lane = threadIdx.x & 63;
    int row = blockIdx.x * 4 + wave;
    if (row >= M) return;
    const float* x = X + (size_t)row * DM;
    float4 v0 = ((const float4*)x)[lane * 2];
    float4 v1 = ((const float4*)x)[lane * 2 + 1];
    float s = v0.x + v0.y + v0.z + v0.w + v1.x + v1.y + v1.z + v1.w;
    #pragma unroll
    for (int off = 32; off; off >>= 1) s += __shfl_xor(s, off, 64);
    float m = s * (1.f / DM);
    float q = (v0.x - m) * (v0.x - m) + (v0.y - m) * (v0.y - m)
            + (v0.z - m) * (v0.z - m) + (v0.w - m) * (v0.w - m)
            + (v1.x - m) * (v1.x - m) + (v1.y - m) * (v1.y - m)
            + (v1.z - m) * (v1.z - m) + (v1.w - m) * (v1.w - m);
    #pragma unroll
    for (int off = 32; off; off >>= 1) q += __shfl_xor(q, off, 64);
    float rstd = 1.f / sqrtf(q * (1.f / DM) + 1e-5f);
    float4 g0 = ((const float4*)g)[lane * 2], g1 = ((const float4*)g)[lane * 2 + 1];
    float4 b0 = ((const float4*)bt)[lane * 2], b1 = ((const float4*)bt)[lane * 2 + 1];
    float4 w0 = ((const float4*)w)[lane * 2], w1 = ((const float4*)w)[lane * 2 + 1];
    float t = 0.f;
    t += fmaxf((v0.x - m) * rstd * g0.x + b0.x, 0.f) * w0.x;
    t += fmaxf((v0.y - m) * rstd * g0.y + b0.y, 0.f) * w0.y;
    t += fmaxf((v0.z - m) * rstd * g0.z + b0.z, 0.f) * w0.z;
    t += fmaxf((v0.w - m) * rstd * g0.w + b0.w, 0.f) * w0.w;
    t += fmaxf((v1.x - m) * rstd * g1.x + b1.x, 0.f) * w1.x;
    t += fmaxf((v1.y - m) * rstd * g1.y + b1.y, 0.f) * w1.y;
    t += fmaxf((v1.z - m) * rstd * g1.z + b1.z, 0.f) * w1.z;
    t += fmaxf((v1.w - m) * rstd * g1.w + b1.w, 0.f) * w1.w;
    #pragma unroll
    for (int off = 32; off; off >>= 1) t += __shfl_xor(t, off, 64);
    if (lane == 0) out[row] = t + hb[0];
}

// =================================================================== host
extern "C" void kernel_launch(void* const* d_in, const int* in_sizes, int n_in,
                              void* d_out, int out_size, void* d_ws, size_t ws_size,
                              hipStream_t stream) {
    (void)in_sizes; (void)n_in; (void)out_size;
    const float* x_num   = (const float*)d_in[0];
    const float* x_cat   = (const float*)d_in[1];
    const float* cxn     = (const float*)d_in[2];
    const float* cxc     = (const float*)d_in[3];
    const float* cand_y  = (const float*)d_in[4];
    const float* freq    = (const float*)d_in[6];
    const float* plr_w   = (const float*)d_in[7];
    const float* plr_b   = (const float*)d_in[8];
    const float* lin_w   = (const float*)d_in[9];
    const float* lin_b   = (const float*)d_in[10];
    const float* enc_w1  = (const float*)d_in[11];
    const float* enc_b1  = (const float*)d_in[12];
    const float* enc_w2  = (const float*)d_in[13];
    const float* enc_b2  = (const float*)d_in[14];
    const float* mix_g   = (const float*)d_in[15];
    const float* mix_b   = (const float*)d_in[16];
    const float* K_w     = (const float*)d_in[17];
    const float* K_b     = (const float*)d_in[18];
    const float* label_w = (const float*)d_in[19];
    const float* label_b = (const float*)d_in[20];
    const float* T_w1    = (const float*)d_in[21];
    const float* T_b1    = (const float*)d_in[22];
    const float* T_w2    = (const float*)d_in[23];
    const float* pred_g  = (const float*)d_in[24];
    const float* pred_b  = (const float*)d_in[25];
    const float* pred_w1 = (const float*)d_in[26];
    const float* pred_b1 = (const float*)d_in[27];
    const float* pred_w2 = (const float*)d_in[28];
    const float* pred_b2 = (const float*)d_in[29];
    const float* head_g  = (const float*)d_in[30];
    const float* head_b  = (const float*)d_in[31];
    const float* head_w  = (const float*)d_in[32];
    const float* head_bias = (const float*)d_in[33];
    float* out = (float*)d_out;

    char* ws = (char*)d_ws;
    size_t off = 0;
    auto alloc = [&](size_t n) { char* p = ws + off; off = (off + n + 255) & ~(size_t)255; return p; };

    typedef unsigned short u16;
    // --- bf16 weights (transposed to N x Kp), hi/lo ---
    u16* lin_wt_h = (u16*)alloc((size_t)DM * KP_IN * 2);
    u16* lin_wt_l = (u16*)alloc((size_t)DM * KP_IN * 2);
    u16* e1t_h    = (u16*)alloc((size_t)DBK * DM * 2);
    u16* e1t_l    = (u16*)alloc((size_t)DBK * DM * 2);
    u16* e2t_h    = (u16*)alloc((size_t)DM * DBK * 2);
    u16* e2t_l    = (u16*)alloc((size_t)DM * DBK * 2);
    u16* K_wt_h   = (u16*)alloc((size_t)DM * DM * 2);
    u16* K_wt_l   = (u16*)alloc((size_t)DM * DM * 2);
    u16* T_w1t    = (u16*)alloc((size_t)DBK * DM * 2);
    u16* T_w2t_h  = (u16*)alloc((size_t)DM * DBK * 2);
    u16* T_w2t_l  = (u16*)alloc((size_t)DM * DBK * 2);
    u16* p1t_h    = (u16*)alloc((size_t)DBK * DM * 2);
    u16* p1t_l    = (u16*)alloc((size_t)DBK * DM * 2);
    u16* p2t_h    = (u16*)alloc((size_t)DM * DBK * 2);
    u16* p2t_l    = (u16*)alloc((size_t)DM * DBK * 2);
    // --- persistent ---
    u16*   T1c  = (u16*)alloc((size_t)NCAND * DBK * 2);   // 102.4 MB
    float* T1b  = (float*)alloc((size_t)NB * DBK * 4);
    float* xB   = (float*)alloc((size_t)NB * DM * 4);
    u16*   kBh  = (u16*)alloc((size_t)NB * DM * 2);
    u16*   kBl  = (u16*)alloc((size_t)NB * DM * 2);
    // batch scratch
    u16* binh = (u16*)alloc((size_t)NB * KP_IN * 2);
    u16* binl = (u16*)alloc((size_t)NB * KP_IN * 2);
    u16* xBhh = (u16*)alloc((size_t)NB * DM * 2);
    u16* xBhl = (u16*)alloc((size_t)NB * DM * 2);
    u16* hBh  = (u16*)alloc((size_t)NB * DBK * 2);
    u16* hBl  = (u16*)alloc((size_t)NB * DBK * 2);
    u16* lnBh = (u16*)alloc((size_t)NB * DM * 2);
    u16* lnBl = (u16*)alloc((size_t)NB * DM * 2);
    // ctx + tail
    int*   ctxAi = (int*)alloc((size_t)NB * CTX * 4);
    float* ctxAs = (float*)alloc((size_t)NB * CTX * 4);
    int*   ctxBi = (int*)alloc((size_t)NB * CTX * 4);
    float* ctxBs = (float*)alloc((size_t)NB * CTX * 4);
    u16*   sbufh = (u16*)alloc((size_t)NB * DBK * 2);
    u16*   sbufl = (u16*)alloc((size_t)NB * DBK * 2);
    float* ubuf  = (float*)alloc((size_t)NB * DM * 4);
    float* x2    = (float*)alloc((size_t)NB * DM * 4);
    u16*   h2h   = (u16*)alloc((size_t)NB * DM * 2);
    u16*   h2l   = (u16*)alloc((size_t)NB * DM * 2);
    u16*   hph   = (u16*)alloc((size_t)NB * DBK * 2);
    u16*   hpl   = (u16*)alloc((size_t)NB * DBK * 2);
    float* x3    = (float*)alloc((size_t)NB * DM * 4);

    // --- chunk arenas with lifetime-based aliasing (11.5 KB/row) ---
    size_t remain = (ws_size > off + 8192) ? (ws_size - off - 8192) : 0;
    const size_t perrow = 3328 + 2048 + 2048 + 4096 + 64;
    long ncl = (long)(remain / perrow);
    int NC = (int)(ncl > NCMAX ? NCMAX : ncl);   // NCMAX: topk LDS cache bound
    NC &= ~127;
    if (NC < 256) NC = 256;
    char* arenaA = alloc((size_t)NC * 3328);   // inCh+inCl -> kC + cnC
    char* arenaB = alloc((size_t)NC * 2048);   // xC -> scoresC
    char* arenaC = alloc((size_t)NC * 2048);   // xCh/xCl -> lnCh/lnCl
    char* arenaD = alloc((size_t)NC * 4096);   // hCh/hCl -> kCh/kCl
    u16* inCh = (u16*)arenaA;
    u16* inCl = inCh + (size_t)NC * KP_IN;
    float* kC  = (float*)arenaA;                       // after lin: inC dead
    float* cnC = (float*)(arenaA + (size_t)NC * 2048);
    float* xC  = (float*)arenaB;
    float* scoresC = (float*)arenaB;                   // after ln: xC dead
    u16* xCh  = (u16*)arenaC;
    u16* xCl  = xCh + (size_t)NC * DM;
    u16* lnCh = (u16*)arenaC;                          // after enc1: xCh dead
    u16* lnCl = lnCh + (size_t)NC * DM;
    u16* hCh  = (u16*)arenaD;
    u16* hCl  = hCh + (size_t)NC * DBK;
    u16* kCh  = (u16*)arenaD;                          // after enc2: hC dead
    u16* kCl  = kCh + (size_t)NC * DM;

    auto bgemm = [&](const u16* A, const u16* Bt, int M, int N, int Kp,
                     float* Cf, u16* Cb, const float* bias, int flags) {
        dim3 grid((N + 127) / 128, (M + 127) / 128);
        bgemm_kernel<<<grid, 512, 0, stream>>>(A, Bt, M, N, Kp, Cf, Cb, bias, flags);
    };
    auto bgemm3 = [&](const u16* Ah, const u16* Al, const u16* Bh, const u16* Bl,
                      int M, int N, int Kp, float* Cf, u16* Cbh, u16* Cbl,
                      const float* bias, const float* resf, const float* cnorm, int flags) {
        dim3 grid((N + 127) / 128, (M + 127) / 128);
        bgemm3_kernel<<<grid, 512, 0, stream>>>(Ah, Al, Bh, Bl, M, N, Kp,
                                                Cf, Cbh, Cbl, bias, resf, cnorm, flags);
    };
    auto bgemm3s = [&](const u16* Ah, const u16* Al, const u16* Bh, const u16* Bl,
                       int M, int N, int Kp, float* Cf, u16* Cbh, u16* Cbl,
                       const float* bias, const float* resf, int flags) {
        dim3 grid((N + 63) / 64, (M + 63) / 64);
        bgemm3s_kernel<<<grid, 256, 0, stream>>>(Ah, Al, Bh, Bl, M, N, Kp,
                                                 Cf, Cbh, Cbl, bias, resf, flags);
    };
    auto wprep = [&](const float* W, int K, int N, int Kp, u16* Wh, u16* Wl) {
        int n = N * Kp;
        wprep_kernel<<<(n + 255) / 256, 256, 0, stream>>>(W, K, N, Kp, Wh, Wl);
    };

    // ---------- weight prep ----------
    wprep(lin_w, DIN, DM, KP_IN, lin_wt_h, lin_wt_l);
    wprep(enc_w1, DM, DBK, DM, e1t_h, e1t_l);
    wprep(enc_w2, DBK, DM, DBK, e2t_h, e2t_l);
    wprep(K_w, DM, DM, DM, K_wt_h, K_wt_l);
    wprep(T_w1, DM, DBK, DM, T_w1t, nullptr);
    wprep(T_w2, DBK, DM, DBK, T_w2t_h, T_w2t_l);
    wprep(pred_w1, DM, DBK, DM, p1t_h, p1t_l);
    wprep(pred_w2, DBK, DM, DBK, p2t_h, p2t_l);

    // ---------- batch encode (64-tile split GEMMs) ----------
    plr_bf16_kernel<<<(NB + 3) / 4, 256, 0, stream>>>(x_num, x_cat, NB, freq, plr_w, plr_b, binh, binl);
    bgemm3s(binh, binl, lin_wt_h, lin_wt_l, NB, DM, KP_IN, xB, xBhh, xBhl, lin_b, nullptr, 0);
    bgemm3s(xBhh, xBhl, e1t_h, e1t_l, NB, DBK, DM, nullptr, hBh, hBl, enc_b1, nullptr, BG_RELU);
    bgemm3s(hBh, hBl, e2t_h, e2t_l, NB, DM, DBK, xB, nullptr, nullptr, enc_b2, xB, 0);
    ln_split_kernel<<<(NB + 3) / 4, 256, 0, stream>>>(xB, lnBh, lnBl, mix_g, mix_b, NB);
    bgemm3s(lnBh, lnBl, K_wt_h, K_wt_l, NB, DM, DM, nullptr, kBh, kBl, K_b, nullptr, 0);
    bgemm3s(kBh, nullptr, T_w1t, nullptr, NB, DBK, DM, T1b, nullptr, nullptr, nullptr, nullptr, 0);
    ctx_init_kernel<<<(NB * CTX + 255) / 256, 256, 0, stream>>>(ctxAi, ctxAs);

    // ---------- candidate chunks (128-tile, 512-thread GEMMs) ----------
    const int* pI = ctxAi; const float* pS = ctxAs;
    int* nI = ctxBi; float* nS = ctxBs;
    int nch = (NCAND + NC - 1) / NC;
    for (int c = 0; c < nch; c++) {
        int s = c * NC;
        int m = NCAND - s; if (m > NC) m = NC;
        plr_bf16_kernel<<<(m + 3) / 4, 256, 0, stream>>>(cxn + (size_t)s * NFEAT,
                                                         cxc + (size_t)s * NCAT,
                                                         m, freq, plr_w, plr_b, inCh, inCl);
        bgemm3(inCh, inCl, lin_wt_h, lin_wt_l, m, DM, KP_IN, xC, xCh, xCl, lin_b, nullptr, nullptr, 0);
        bgemm3(xCh, xCl, e1t_h, e1t_l, m, DBK, DM, nullptr, hCh, hCl, enc_b1, nullptr, nullptr, BG_RELU);
        bgemm3(hCh, hCl, e2t_h, e2t_l, m, DM, DBK, xC, nullptr, nullptr, enc_b2, xC, nullptr, 0);
        ln_split_kernel<<<(m + 3) / 4, 256, 0, stream>>>(xC, lnCh, lnCl, mix_g, mix_b, m);
        bgemm3(lnCh, lnCl, K_wt_h, K_wt_l, m, DM, DM, kC, kCh, kCl, K_b, nullptr, nullptr, 0);
        cnorm_kernel<<<(m + 3) / 4, 256, 0, stream>>>(kC, cnC, m);
        bgemm(kCh, T_w1t, m, DBK, DM, nullptr, T1c + (size_t)s * DBK, nullptr, 0);
        bgemm3(kBh, kBl, kCh, kCl, NB, m, DM, scoresC, nullptr, nullptr,
               nullptr, nullptr, cnC, BG_SCORE);
        topk_merge_kernel<<<NB, 256, 0, stream>>>(scoresC, m, s, pI, pS, nI, nS);
        { const int* t = pI; pI = nI; nI = (int*)t; }
        { const float* t = pS; pS = nS; nS = (float*)t; }
    }

    // ---------- aggregation + predictor + head (64-tile split GEMMs) ----------
    agg_kernel<<<NB, 256, 0, stream>>>(pI, pS, cand_y, T1b, T1c, T_b1,
                                       xB, label_w, label_b, sbufh, sbufl, ubuf);
    bgemm3s(sbufh, sbufl, T_w2t_h, T_w2t_l, NB, DM, DBK, x2, nullptr, nullptr,
            nullptr, ubuf, 0);
    ln_split_kernel<<<(NB + 3) / 4, 256, 0, stream>>>(x2, h2h, h2l, pred_g, pred_b, NB);
    bgemm3s(h2h, h2l, p1t_h, p1t_l, NB, DBK, DM, nullptr, hph, hpl, pred_b1, nullptr, BG_RELU);
    bgemm3s(hph, hpl, p2t_h, p2t_l, NB, DM, DBK, x3, nullptr, nullptr, pred_b2, x2, 0);
    head_kernel<<<(NB + 3) / 4, 256, 0, stream>>>(x3, head_g, head_b, head_w, head_bias, out, NB);
}

// Round 10
// 2195.354 us; speedup vs baseline: 1.4773x; 1.0699x over previous
//
#include <hip/hip_runtime.h>

#define NCAND 50000
#define NB    512
#define DIN   820
#define KP_IN 832
#define DM    512
#define DBK   1024
#define NFEAT 50
#define NCAT  20
#define NFREQ 16
#define DEMB  16
#define CTX   96
#define NCMAX 9216
#define TOTMAX (NCMAX + CTX)

typedef __attribute__((ext_vector_type(8))) short short8;
typedef __attribute__((ext_vector_type(4))) float f32x4;

static __device__ __forceinline__ unsigned short f2bf(float f) {
    union { float f; unsigned int i; } u; u.f = f;
    unsigned int r = u.i + 0x7FFFu + ((u.i >> 16) & 1u);
    return (unsigned short)(r >> 16);
}
static __device__ __forceinline__ float bf2f(unsigned short s) {
    union { unsigned int i; float f; } u; u.i = ((unsigned int)s) << 16;
    return u.f;
}
// order-preserving float->uint key (ascending), exact bijection
static __device__ __forceinline__ unsigned int f2key(float f) {
    union { float f; unsigned int i; } u; u.f = f;
    return (u.i & 0x80000000u) ? ~u.i : (u.i | 0x80000000u);
}
static __device__ __forceinline__ float key2f(unsigned int k) {
    union { unsigned int i; float f; } u;
    u.i = (k & 0x80000000u) ? (k ^ 0x80000000u) : ~k;
    return u.f;
}

#define GLDS16(g, l) __builtin_amdgcn_global_load_lds( \
    (const __attribute__((address_space(1))) void*)(g), \
    (__attribute__((address_space(3))) void*)(l), 16, 0, 0)

#define BG_RELU  1
#define BG_SCORE 2

// LDS chunk swizzle: physical chunk c_p at row r holds logical chunk (c_p - (r>>1))&3.
// Staging (GLDS16, lane covers row base+(lane>>2), phys chunk lane&3):
//   scol = (((lane&3) - ((lane>>3)&3)) & 3) * 8      [valid: base row multiple of 16]
// Read (logical chunk q at row wr+i*16+fr, wr mult of 32):
//   pcs  = ((q + (fr>>1)) & 3) * 8

// ---------------------------------------------------------------- weight prep
__global__ __launch_bounds__(256) void wprep_kernel(
    const float* __restrict__ W, int K, int N, int Kp,
    unsigned short* __restrict__ Wh, unsigned short* __restrict__ Wl)
{
    int idx = blockIdx.x * 256 + threadIdx.x;
    if (idx >= N * Kp) return;
    int n = idx / Kp, k = idx % Kp;
    float v = (k < K) ? W[(size_t)k * N + n] : 0.f;
    unsigned short h = f2bf(v);
    Wh[idx] = h;
    if (Wl) Wl[idx] = f2bf(v - bf2f(h));
}

// ---------------------------------------------------------------- PLR encode (bf16 hi/lo out)
__global__ __launch_bounds__(256) void plr_bf16_kernel(
    const float* __restrict__ xn_, const float* __restrict__ xc_, int nrows,
    const float* __restrict__ freq, const float* __restrict__ plr_w,
    const float* __restrict__ plr_b,
    unsigned short* __restrict__ oh, unsigned short* __restrict__ ol)
{
    __shared__ float sW[32 * 16];
    __shared__ float sB[16];
    __shared__ float sF[NFEAT * NFREQ];
    int tid = threadIdx.x;
    for (int i = tid; i < 512; i += 256) sW[i] = plr_w[i];
    if (tid < 16) sB[tid] = plr_b[tid];
    for (int i = tid; i < NFEAT * NFREQ; i += 256) sF[i] = freq[i];
    __syncthreads();
    int wave = tid >> 6, lane = tid & 63;
    int row = blockIdx.x * 4 + wave;
    if (row >= nrows) return;
    const float* xn = xn_ + (size_t)row * NFEAT;
    const float* xc = xc_ + (size_t)row * NCAT;
    unsigned short* ph = oh + (size_t)row * KP_IN;
    unsigned short* pl = ol + (size_t)row * KP_IN;
    if (lane < NFEAT) {
        float x = xn[lane];
        float cs[NFREQ], sn[NFREQ];
        #pragma unroll
        for (int j = 0; j < NFREQ; j++) {
            float p = 6.28318530717958647692f * sF[lane * NFREQ + j] * x;
            sn[j] = __sinf(p);
            cs[j] = __cosf(p);
        }
        #pragma unroll
        for (int d = 0; d < DEMB; d++) {
            float acc = sB[d];
            #pragma unroll
            for (int j = 0; j < NFREQ; j++)
                acc = fmaf(cs[j], sW[j * DEMB + d], fmaf(sn[j], sW[(NFREQ + j) * DEMB + d], acc));
            float v = fmaxf(acc, 0.f);
            unsigned short h = f2bf(v);
            ph[lane * DEMB + d] = h;
            pl[lane * DEMB + d] = f2bf(v - bf2f(h));
        }
    }
    if (lane < NCAT) {
        float v = xc[lane];
        unsigned short h = f2bf(v);
        ph[800 + lane] = h;
        pl[800 + lane] = f2bf(v - bf2f(h));
    }
    if (lane >= NCAT && lane < 32) {
        ph[800 + lane] = 0;
        pl[800 + lane] = 0;
    }
}

// ------------------------------- bf16 MFMA GEMM (plain 1-term), 128 tile, 512 threads
__global__ __launch_bounds__(512) void bgemm_kernel(
    const unsigned short* __restrict__ A, const unsigned short* __restrict__ Bt,
    int M, int N, int Kp,
    float* __restrict__ Cf, unsigned short* __restrict__ Cb,
    const float* __restrict__ bias, int flags)
{
    __shared__ unsigned short As[128 * 32];
    __shared__ unsigned short Bs[128 * 32];
    int tid = threadIdx.x;
    int w = tid >> 6, lane = tid & 63;
    int m0 = blockIdx.y * 128, n0 = blockIdx.x * 128;
    int wr = (w >> 1) * 32, wc = (w & 1) * 64;

    f32x4 acc[2][4];
    #pragma unroll
    for (int i = 0; i < 2; i++)
        #pragma unroll
        for (int j = 0; j < 4; j++) acc[i][j] = (f32x4){0.f, 0.f, 0.f, 0.f};

    int arr = w & 1;
    int qrt = (w >> 1) * 32;
    int scol = (((lane & 3) - ((lane >> 3) & 3)) & 3) * 8;
    const unsigned short* gsrc = arr ? Bt : A;
    int glim = arr ? (N - 1) : (M - 1);
    int gb   = arr ? n0 : m0;
    unsigned short* ldst = arr ? Bs : As;
    const unsigned short* gp0 = gsrc + (size_t)min(gb + qrt + (lane >> 2),      glim) * Kp + scol;
    const unsigned short* gp1 = gsrc + (size_t)min(gb + qrt + 16 + (lane >> 2), glim) * Kp + scol;
    unsigned short* lp0 = ldst + qrt * 32;
    unsigned short* lp1 = ldst + (qrt + 16) * 32;

    int fr = lane & 15, q = lane >> 4;
    int pcs = ((q + (fr >> 1)) & 3) * 8;

    for (int k0 = 0; k0 < Kp; k0 += 32) {
        __syncthreads();
        GLDS16(gp0 + k0, lp0);
        GLDS16(gp1 + k0, lp1);
        __syncthreads();
        short8 a[2], b[4];
        #pragma unroll
        for (int i = 0; i < 2; i++)
            a[i] = *(const short8*)&As[(wr + i * 16 + fr) * 32 + pcs];
        #pragma unroll
        for (int j = 0; j < 4; j++)
            b[j] = *(const short8*)&Bs[(wc + j * 16 + fr) * 32 + pcs];
        #pragma unroll
        for (int i = 0; i < 2; i++)
            #pragma unroll
            for (int j = 0; j < 4; j++)
                acc[i][j] = __builtin_amdgcn_mfma_f32_16x16x32_bf16(a[i], b[j], acc[i][j], 0, 0, 0);
    }

    int col = lane & 15, rq = (lane >> 4) * 4;
    #pragma unroll
    for (int i = 0; i < 2; i++)
        #pragma unroll
        for (int j = 0; j < 4; j++) {
            int n_g = n0 + wc + j * 16 + col;
            #pragma unroll
            for (int r = 0; r < 4; r++) {
                int m_g = m0 + wr + i * 16 + rq + r;
                if (m_g < M && n_g < N) {
                    float v = acc[i][j][r];
                    if (bias) v += bias[n_g];
                    if (flags & BG_RELU) v = fmaxf(v, 0.f);
                    if (Cf) Cf[(size_t)m_g * N + n_g] = v;
                    if (Cb) Cb[(size_t)m_g * N + n_g] = f2bf(v);
                }
            }
        }
}

// ------------------------- bf16 MFMA GEMM, 3-term split, 128 tile, 512 threads
__global__ __launch_bounds__(512) void bgemm3_kernel(
    const unsigned short* __restrict__ Ah, const unsigned short* __restrict__ Al,
    const unsigned short* __restrict__ Bh, const unsigned short* __restrict__ Bl,
    int M, int N, int Kp,
    float* __restrict__ Cf, unsigned short* __restrict__ Cbh, unsigned short* __restrict__ Cbl,
    const float* __restrict__ bias, const float* __restrict__ resf,
    const float* __restrict__ cnorm, int flags)
{
    __shared__ unsigned short Ash[128 * 32];
    __shared__ unsigned short Asl[128 * 32];
    __shared__ unsigned short Bsh[128 * 32];
    __shared__ unsigned short Bsl[128 * 32];
    int tid = threadIdx.x;
    int w = tid >> 6, lane = tid & 63;
    int m0 = blockIdx.y * 128, n0 = blockIdx.x * 128;
    int wr = (w >> 1) * 32, wc = (w & 1) * 64;

    f32x4 acc[2][4];
    #pragma unroll
    for (int i = 0; i < 2; i++)
        #pragma unroll
        for (int j = 0; j < 4; j++) acc[i][j] = (f32x4){0.f, 0.f, 0.f, 0.f};

    int arr = w & 3;
    int half = (w >> 2) * 64;
    int scol = (((lane & 3) - ((lane >> 3) & 3)) & 3) * 8;
    const unsigned short* gsrc = (arr == 0) ? Ah : (arr == 1) ? Al : (arr == 2) ? Bh : Bl;
    int glim = (arr < 2) ? (M - 1) : (N - 1);
    int gb   = (arr < 2) ? m0 : n0;
    unsigned short* ldst = (arr == 0) ? Ash : (arr == 1) ? Asl : (arr == 2) ? Bsh : Bsl;
    const unsigned short* gp[4];
    unsigned short* lp[4];
    #pragma unroll
    for (int t = 0; t < 4; t++) {
        int r = half + t * 16;
        gp[t] = gsrc + (size_t)min(gb + r + (lane >> 2), glim) * Kp + scol;
        lp[t] = ldst + r * 32;
    }

    int fr = lane & 15, q = lane >> 4;
    int pcs = ((q + (fr >> 1)) & 3) * 8;

    for (int k0 = 0; k0 < Kp; k0 += 32) {
        __syncthreads();
        GLDS16(gp[0] + k0, lp[0]);
        GLDS16(gp[1] + k0, lp[1]);
        GLDS16(gp[2] + k0, lp[2]);
        GLDS16(gp[3] + k0, lp[3]);
        __syncthreads();
        short8 a[2], b[4];
        #pragma unroll
        for (int i = 0; i < 2; i++)
            a[i] = *(const short8*)&Ash[(wr + i * 16 + fr) * 32 + pcs];
        #pragma unroll
        for (int j = 0; j < 4; j++)
            b[j] = *(const short8*)&Bsh[(wc + j * 16 + fr) * 32 + pcs];
        #pragma unroll
        for (int i = 0; i < 2; i++)
            #pragma unroll
            for (int j = 0; j < 4; j++)
                acc[i][j] = __builtin_amdgcn_mfma_f32_16x16x32_bf16(a[i], b[j], acc[i][j], 0, 0, 0);
        short8 al2[2];
        #pragma unroll
        for (int i = 0; i < 2; i++)
            al2[i] = *(const short8*)&Asl[(wr + i * 16 + fr) * 32 + pcs];
        #pragma unroll
        for (int i = 0; i < 2; i++)
            #pragma unroll
            for (int j = 0; j < 4; j++)
                acc[i][j] = __builtin_amdgcn_mfma_f32_16x16x32_bf16(al2[i], b[j], acc[i][j], 0, 0, 0);
        short8 bl2[4];
        #pragma unroll
        for (int j = 0; j < 4; j++)
            bl2[j] = *(const short8*)&Bsl[(wc + j * 16 + fr) * 32 + pcs];
        #pragma unroll
        for (int i = 0; i < 2; i++)
            #pragma unroll
            for (int j = 0; j < 4; j++)
                acc[i][j] = __builtin_amdgcn_mfma_f32_16x16x32_bf16(a[i], bl2[j], acc[i][j], 0, 0, 0);
    }

    int col = lane & 15, rq = (lane >> 4) * 4;
    #pragma unroll
    for (int i = 0; i < 2; i++)
        #pragma unroll
        for (int j = 0; j < 4; j++) {
            int n_g = n0 + wc + j * 16 + col;
            #pragma unroll
            for (int r = 0; r < 4; r++) {
                int m_g = m0 + wr + i * 16 + rq + r;
                if (m_g < M && n_g < N) {
                    float v = acc[i][j][r];
                    if (bias) v += bias[n_g];
                    if (resf) v += resf[(size_t)m_g * N + n_g];
                    if (flags & BG_RELU) v = fmaxf(v, 0.f);
                    if (flags & BG_SCORE) v = 2.f * v - cnorm[n_g];
                    if (Cf) Cf[(size_t)m_g * N + n_g] = v;
                    if (Cbh) {
                        unsigned short h = f2bf(v);
                        Cbh[(size_t)m_g * N + n_g] = h;
                        if (Cbl) Cbl[(size_t)m_g * N + n_g] = f2bf(v - bf2f(h));
                    }
                }
            }
        }
}

// ------------------------- small-M GEMM: 64x64 tile, 1- or 3-term (Al null => 1-term)
__global__ __launch_bounds__(256) void bgemm3s_kernel(
    const unsigned short* __restrict__ Ah, const unsigned short* __restrict__ Al,
    const unsigned short* __restrict__ Bh, const unsigned short* __restrict__ Bl,
    int M, int N, int Kp,
    float* __restrict__ Cf, unsigned short* __restrict__ Cbh, unsigned short* __restrict__ Cbl,
    const float* __restrict__ bias, const float* __restrict__ resf, int flags)
{
    __shared__ unsigned short Ash[64 * 32];
    __shared__ unsigned short Asl[64 * 32];
    __shared__ unsigned short Bsh[64 * 32];
    __shared__ unsigned short Bsl[64 * 32];
    int tid = threadIdx.x;
    int w = tid >> 6, lane = tid & 63;
    int m0 = blockIdx.y * 64, n0 = blockIdx.x * 64;
    int wr = (w >> 1) * 32, wc = (w & 1) * 32;
    int three = (Al != nullptr);

    f32x4 acc[2][2];
    #pragma unroll
    for (int i = 0; i < 2; i++)
        #pragma unroll
        for (int j = 0; j < 2; j++) acc[i][j] = (f32x4){0.f, 0.f, 0.f, 0.f};

    int srow = w * 16 + (lane >> 2);
    int scol = (((lane & 3) - ((lane >> 3) & 3)) & 3) * 8;
    size_t ra = (size_t)min(m0 + srow, M - 1) * Kp + scol;
    size_t rb = (size_t)min(n0 + srow, N - 1) * Kp + scol;
    unsigned short* lah = &Ash[(w * 16) * 32];
    unsigned short* lal = &Asl[(w * 16) * 32];
    unsigned short* lbh = &Bsh[(w * 16) * 32];
    unsigned short* lbl = &Bsl[(w * 16) * 32];

    int fr = lane & 15, q = lane >> 4;
    int pcs = ((q + (fr >> 1)) & 3) * 8;

    for (int k0 = 0; k0 < Kp; k0 += 32) {
        __syncthreads();
        GLDS16(Ah + ra + k0, lah);
        GLDS16(Bh + rb + k0, lbh);
        if (three) {
            GLDS16(Al + ra + k0, lal);
            GLDS16(Bl + rb + k0, lbl);
        }
        __syncthreads();
        short8 a[2], b[2];
        #pragma unroll
        for (int i = 0; i < 2; i++)
            a[i] = *(const short8*)&Ash[(wr + i * 16 + fr) * 32 + pcs];
        #pragma unroll
        for (int j = 0; j < 2; j++)
            b[j] = *(const short8*)&Bsh[(wc + j * 16 + fr) * 32 + pcs];
        #pragma unroll
        for (int i = 0; i < 2; i++)
            #pragma unroll
            for (int j = 0; j < 2; j++)
                acc[i][j] = __builtin_amdgcn_mfma_f32_16x16x32_bf16(a[i], b[j], acc[i][j], 0, 0, 0);
        if (three) {
            short8 al2[2], bl2[2];
            #pragma unroll
            for (int i = 0; i < 2; i++)
                al2[i] = *(const short8*)&Asl[(wr + i * 16 + fr) * 32 + pcs];
            #pragma unroll
            for (int j = 0; j < 2; j++)
                bl2[j] = *(const short8*)&Bsl[(wc + j * 16 + fr) * 32 + pcs];
            #pragma unroll
            for (int i = 0; i < 2; i++)
                #pragma unroll
                for (int j = 0; j < 2; j++) {
                    acc[i][j] = __builtin_amdgcn_mfma_f32_16x16x32_bf16(al2[i], b[j], acc[i][j], 0, 0, 0);
                    acc[i][j] = __builtin_amdgcn_mfma_f32_16x16x32_bf16(a[i], bl2[j], acc[i][j], 0, 0, 0);
                }
        }
    }

    int col = lane & 15, rq = (lane >> 4) * 4;
    #pragma unroll
    for (int i = 0; i < 2; i++)
        #pragma unroll
        for (int j = 0; j < 2; j++) {
            int n_g = n0 + wc + j * 16 + col;
            #pragma unroll
            for (int r = 0; r < 4; r++) {
                int m_g = m0 + wr + i * 16 + rq + r;
                if (m_g < M && n_g < N) {
                    float v = acc[i][j][r];
                    if (bias) v += bias[n_g];
                    if (resf) v += resf[(size_t)m_g * N + n_g];
                    if (flags & BG_RELU) v = fmaxf(v, 0.f);
                    if (Cf) Cf[(size_t)m_g * N + n_g] = v;
                    if (Cbh) {
                        unsigned short h = f2bf(v);
                        Cbh[(size_t)m_g * N + n_g] = h;
                        if (Cbl) Cbl[(size_t)m_g * N + n_g] = f2bf(v - bf2f(h));
                    }
                }
            }
        }
}

// ---------------------------------------------------------------- LayerNorm bf16 hi/lo out
__global__ __launch_bounds__(256) void ln_split_kernel(const float* __restrict__ X,
    unsigned short* __restrict__ Yh, unsigned short* __restrict__ Yl,
    const float* __restrict__ g, const float* __restrict__ bt, int M)
{
    int wave = threadIdx.x >> 6, lane = threadIdx.x & 63;
    int row = blockIdx.x * 4 + wave;
    if (row >= M) return;
    const float* x = X + (size_t)row * DM;
    float4 v0 = ((const float4*)x)[lane * 2];
    float4 v1 = ((const float4*)x)[lane * 2 + 1];
    float s = v0.x + v0.y + v0.z + v0.w + v1.x + v1.y + v1.z + v1.w;
    #pragma unroll
    for (int off = 32; off; off >>= 1) s += __shfl_xor(s, off, 64);
    float m = s * (1.f / DM);
    float q = (v0.x - m) * (v0.x - m) + (v0.y - m) * (v0.y - m)
            + (v0.z - m) * (v0.z - m) + (v0.w - m) * (v0.w - m)
            + (v1.x - m) * (v1.x - m) + (v1.y - m) * (v1.y - m)
            + (v1.z - m) * (v1.z - m) + (v1.w - m) * (v1.w - m);
    #pragma unroll
    for (int off = 32; off; off >>= 1) q += __shfl_xor(q, off, 64);
    float rstd = 1.f / sqrtf(q * (1.f / DM) + 1e-5f);
    float vals[8] = {v0.x, v0.y, v0.z, v0.w, v1.x, v1.y, v1.z, v1.w};
    unsigned short* yh = Yh + (size_t)row * DM + lane * 8;
    unsigned short* yl = Yl + (size_t)row * DM + lane * 8;
    const float* gp = g + lane * 8;
    const float* bp = bt + lane * 8;
    #pragma unroll
    for (int i = 0; i < 8; i++) {
        float y = (vals[i] - m) * rstd * gp[i] + bp[i];
        unsigned short h = f2bf(y);
        yh[i] = h;
        yl[i] = f2bf(y - bf2f(h));
    }
}

// ---------------------------------------------------------------- key norms (fp32 k)
__global__ __launch_bounds__(256) void cnorm_kernel(const float* __restrict__ Kc,
    float* __restrict__ cn, int N)
{
    int wave = threadIdx.x >> 6, lane = threadIdx.x & 63;
    int row = blockIdx.x * 4 + wave;
    if (row >= N) return;
    const float* x = Kc + (size_t)row * DM;
    float4 v0 = ((const float4*)x)[lane * 2];
    float4 v1 = ((const float4*)x)[lane * 2 + 1];
    float s = v0.x * v0.x + v0.y * v0.y + v0.z * v0.z + v0.w * v0.w
            + v1.x * v1.x + v1.y * v1.y + v1.z * v1.z + v1.w * v1.w;
    #pragma unroll
    for (int off = 32; off; off >>= 1) s += __shfl_xor(s, off, 64);
    if (lane == 0) cn[row] = s;
}

// ---------------------------------------------------------------- ctx init
__global__ void ctx_init_kernel(int* __restrict__ idx, float* __restrict__ sc)
{
    int i = blockIdx.x * 256 + threadIdx.x;
    if (i < NB * CTX) { idx[i] = 0; sc[i] = -1e30f; }
}

// ------------------------------------- running top-96 merge: exact radix select
// LDS key cache + hybrid histogram + PARALLEL suffix-scan bin selection.
// Deterministic: (score desc, idx asc) order.
#define CANDCAP 2048
__global__ __launch_bounds__(256) void topk_merge_kernel(
    const float* __restrict__ S, int m, int base,
    const int* __restrict__ pidx, const float* __restrict__ pscore,
    int* __restrict__ nidx, float* __restrict__ nscore)
{
    __shared__ __align__(16) unsigned int ks[TOTMAX];
    __shared__ unsigned int hist[4 * 256];
    __shared__ unsigned int sfx[256];
    __shared__ unsigned int s_prefix;
    __shared__ int s_above;
    __shared__ int prev_i[CTX];
    __shared__ int nsel, neq;
    __shared__ float sel_s[CTX];
    __shared__ int   sel_g[CTX];
    __shared__ int   cnd_g[CANDCAP];

    int b = blockIdx.x, tid = threadIdx.x;
    int lane = tid & 63, wv = tid >> 6;
    const float* Sb = S + (size_t)b * m;
    int tot = m + CTX;

    // stage keys into LDS (one global pass, vectorized, key-converted once)
    int m4 = m >> 2;
    const float4* S4 = (const float4*)Sb;
    for (int i = tid; i < m4; i += 256) {
        float4 v = S4[i];
        uint4 kk;
        kk.x = f2key(v.x); kk.y = f2key(v.y); kk.z = f2key(v.z); kk.w = f2key(v.w);
        ((uint4*)ks)[i] = kk;
    }
    for (int i = (m4 << 2) + tid; i < m; i += 256) ks[i] = f2key(Sb[i]);
    if (tid < CTX) {
        ks[m + tid] = f2key(pscore[b * CTX + tid]);
        prev_i[tid] = pidx[b * CTX + tid];
    }
    if (tid == 0) { s_prefix = 0u; s_above = 0; nsel = 0; neq = 0; }
    __syncthreads();

    unsigned int* myhist = &hist[wv * 256];

    // 4 radix passes, MSB-first, over LDS keys
    for (int pass = 0; pass < 4; pass++) {
        int shift = 24 - pass * 8;
        for (int i = tid; i < 1024; i += 256) hist[i] = 0;
        __syncthreads();
        unsigned int pref = s_prefix;
        unsigned int msk = (pass == 0) ? 0u : (0xFFFFFFFFu << (32 - 8 * pass));
        for (int i0 = 0; i0 < tot; i0 += 256) {
            int i = i0 + tid;
            int pred = 0, digit = 0;
            if (i < tot) {
                unsigned int k = ks[i];
                pred = ((k & msk) == pref);
                digit = (int)((k >> shift) & 255u);
            }
            unsigned long long act = __ballot(pred);
            if (!act) continue;
            int lead = (int)__ffsll(act) - 1;
            int d0 = __shfl(digit, lead, 64);
            unsigned long long same = __ballot(pred && (digit == d0));
            if (same == act) {
                // whole wave shares one digit: single aggregated atomic
                if (lane == lead) atomicAdd(&myhist[d0], (unsigned int)__popcll(act));
            } else {
                // diverse digits: HW-serialized atomics are near-conflict-free
                if (pred) atomicAdd(&myhist[digit], 1u);
            }
        }
        __syncthreads();
        // merge privatized histograms -> per-thread bin count
        unsigned int hb = hist[tid] + hist[256 + tid] + hist[512 + tid] + hist[768 + tid];
        __syncthreads();
        hist[tid] = hb;                 // hist[0..255] = merged counts
        sfx[tid] = hb;
        __syncthreads();
        // inclusive suffix scan over 256 bins (Hillis-Steele)
        #pragma unroll
        for (int offd = 1; offd < 256; offd <<= 1) {
            unsigned int v = (tid + offd < 256) ? sfx[tid + offd] : 0u;
            __syncthreads();
            sfx[tid] += v;
            __syncthreads();
        }
        // boundary bin: s_above + excl < CTX <= s_above + incl  (unique winner)
        {
            int incl = s_above + (int)sfx[tid];
            int excl = incl - (int)hb;
            if (excl < CTX && incl >= CTX) {
                s_prefix = pref | ((unsigned int)tid << shift);
                s_above = excl;
            }
        }
        __syncthreads();
    }
    unsigned int thrK = s_prefix;
    int msel = CTX - s_above;          // take msel among key==thrK by smallest idx
    float eqv = key2f(thrK);

    // collect: strictly above -> selected; equal -> candidates
    for (int i = tid; i < tot; i += 256) {
        unsigned int k = ks[i];
        if (k < thrK) continue;
        int g = (i < m) ? (base + i) : prev_i[i - m];
        if (k > thrK) {
            int p = atomicAdd(&nsel, 1);
            sel_s[p] = key2f(k); sel_g[p] = g;
        } else {
            int p = atomicAdd(&neq, 1);
            if (p < CANDCAP) cnd_g[p] = g;
        }
    }
    __syncthreads();
    int ne = neq;
    if (ne <= CANDCAP) {
        for (int i = tid; i < ne; i += 256) {
            int gi = cnd_g[i];
            int rank = 0;
            for (int j = 0; j < ne; j++) rank += (cnd_g[j] < gi);
            if (rank < msel) {
                int p = atomicAdd(&nsel, 1);
                sel_s[p] = eqv; sel_g[p] = gi;
            }
        }
    } else {
        // pathological mass-tie fallback: deterministic idx-rank via full LDS scan
        for (int i = tid; i < tot; i += 256) {
            if (ks[i] != thrK) continue;
            int g = (i < m) ? (base + i) : prev_i[i - m];
            int rank = 0;
            for (int j = 0; j < tot; j++) {
                if (ks[j] == thrK) {
                    int gj = (j < m) ? (base + j) : prev_i[j - m];
                    rank += (gj < g);
                }
            }
            if (rank < msel) {
                int p = atomicAdd(&nsel, 1);
                sel_s[p] = eqv; sel_g[p] = g;
            }
        }
    }
    __syncthreads();
    if (tid < CTX) {
        nidx[b * CTX + tid] = sel_g[tid];
        nscore[b * CTX + tid] = sel_s[tid];
    }
}

// ------------------------------- softmax + label/value context aggregation
__global__ __launch_bounds__(256) void agg_kernel(
    const int* __restrict__ ctx_idx, const float* __restrict__ ctx_score,
    const float* __restrict__ cand_y, const float* __restrict__ T1b,
    const unsigned short* __restrict__ T1c, const float* __restrict__ T_b1,
    const float* __restrict__ x_batch,
    const float* __restrict__ label_w, const float* __restrict__ label_b,
    unsigned short* __restrict__ s_h, unsigned short* __restrict__ s_l,
    float* __restrict__ u_out)
{
    __shared__ float p_s[CTX];
    __shared__ int   p_i[CTX];
    __shared__ float s_ybar;
    int b = blockIdx.x, tid = threadIdx.x;
    if (tid < CTX) { p_s[tid] = ctx_score[b * CTX + tid]; p_i[tid] = ctx_idx[b * CTX + tid]; }
    __syncthreads();
    if (tid == 0) {
        float mx = -1e30f;
        for (int c = 0; c < CTX; c++) mx = fmaxf(mx, p_s[c]);
        float sum = 0.f;
        for (int c = 0; c < CTX; c++) { float e = __expf(p_s[c] - mx); p_s[c] = e; sum += e; }
        float inv = 1.f / sum, yb = 0.f;
        for (int c = 0; c < CTX; c++) { p_s[c] *= inv; yb += p_s[c] * cand_y[p_i[c]]; }
        s_ybar = yb;
    }
    __syncthreads();
    int j = tid * 4;
    float4 kv = *(const float4*)(T1b + (size_t)b * DBK + j);
    float4 tb = *(const float4*)(T_b1 + j);
    float base0 = kv.x + tb.x, base1 = kv.y + tb.y, base2 = kv.z + tb.z, base3 = kv.w + tb.w;
    float a0 = 0.f, a1 = 0.f, a2 = 0.f, a3 = 0.f;
    for (int c = 0; c < CTX; c++) {
        float p = p_s[c];
        ushort4 cu = *(const ushort4*)(T1c + (size_t)p_i[c] * DBK + j);
        a0 = fmaf(p, fmaxf(base0 - bf2f(cu.x), 0.f), a0);
        a1 = fmaf(p, fmaxf(base1 - bf2f(cu.y), 0.f), a1);
        a2 = fmaf(p, fmaxf(base2 - bf2f(cu.z), 0.f), a2);
        a3 = fmaf(p, fmaxf(base3 - bf2f(cu.w), 0.f), a3);
    }
    {
        ushort4 oh, ol;
        oh.x = f2bf(a0); ol.x = f2bf(a0 - bf2f(oh.x));
        oh.y = f2bf(a1); ol.y = f2bf(a1 - bf2f(oh.y));
        oh.z = f2bf(a2); ol.z = f2bf(a2 - bf2f(oh.z));
        oh.w = f2bf(a3); ol.w = f2bf(a3 - bf2f(oh.w));
        *(ushort4*)(s_h + (size_t)b * DBK + j) = oh;
        *(ushort4*)(s_l + (size_t)b * DBK + j) = ol;
    }
    if (tid < 128) {
        int d = tid * 4;
        float4 xv = *(const float4*)(x_batch + (size_t)b * DM + d);
        float4 lw = *(const float4*)(label_w + d);
        float4 lb = *(const float4*)(label_b + d);
        float yb = s_ybar;
        *(float4*)(u_out + (size_t)b * DM + d) =
            make_float4(xv.x + yb * lw.x + lb.x, xv.y + yb * lw.y + lb.y,
                        xv.z + yb * lw.z + lb.z, xv.w + yb * lw.w + lb.w);
    }
}

// ---------------------------------------------------------------- head
__global__ __launch_bounds__(256) void head_kernel(
    const float* __restrict__ X, const float* __restrict__ g,
    const float* __restrict__ bt, const float* __restrict__ w,
    const float* __restrict__ hb, float* __restrict__ out, int M)
{
    int wave = threadIdx.x >> 6, lane = threadIdx.x & 63;
    int row = blockIdx.x * 4 + wave;
    if (row >= M) return;
    const float* x = X + (size_t)row * DM;
    float4 v0 = ((const float4*)x)[lane * 2];
    float4 v1 = ((const float4*)x)[lane * 2 + 1];
    float s = v0.x + v0.y + v0.z + v0.w + v1.x + v1.y + v1.z + v1.w;
    #pragma unroll
    for (int off = 32; off; off >>= 1) s += __shfl_xor(s, off, 64);
    float m = s * (1.f / DM);
    float q = (v0.x - m) * (v0.x - m) + (v0.y - m) * (v0.y - m)
            + (v0.z - m) * (v0.z - m) + (v0.w - m) * (v0.w - m)
            + (v1.x - m) * (v1.x - m) + (v1.y - m) * (v1.y - m)
            + (v1.z - m) * (v1.z - m) + (v1.w - m) * (v1.w - m);
    #pragma unroll
    for (int off = 32; off; off >>= 1) q += __shfl_xor(q, off, 64);
    float rstd = 1.f / sqrtf(q * (1.f / DM) + 1e-5f);
    float4 g0 = ((const float4*)g)[lane * 2], g1 = ((const float4*)g)[lane * 2 + 1];
    float4 b0 = ((const float4*)bt)[lane * 2], b1 = ((const float4*)bt)[lane * 2 + 1];
    float4 w0 = ((const float4*)w)[lane * 2], w1 = ((const float4*)w)[lane * 2 + 1];
    float t = 0.f;
    t += fmaxf((v0.x - m) * rstd * g0.x + b0.x, 0.f) * w0.x;
    t += fmaxf((v0.y - m) * rstd * g0.y + b0.y, 0.f) * w0.y;
    t += fmaxf((v0.z - m) * rstd * g0.z + b0.z, 0.f) * w0.z;
    t += fmaxf((v0.w - m) * rstd * g0.w + b0.w, 0.f) * w0.w;
    t += fmaxf((v1.x - m) * rstd * g1.x + b1.x, 0.f) * w1.x;
    t += fmaxf((v1.y - m) * rstd * g1.y + b1.y, 0.f) * w1.y;
    t += fmaxf((v1.z - m) * rstd * g1.z + b1.z, 0.f) * w1.z;
    t += fmaxf((v1.w - m) * rstd * g1.w + b1.w, 0.f) * w1.w;
    #pragma unroll
    for (int off = 32; off; off >>= 1) t += __shfl_xor(t, off, 64);
    if (lane == 0) out[row] = t + hb[0];
}

// =================================================================== host
extern "C" void kernel_launch(void* const* d_in, const int* in_sizes, int n_in,
                              void* d_out, int out_size, void* d_ws, size_t ws_size,
                              hipStream_t stream) {
    (void)in_sizes; (void)n_in; (void)out_size;
    const float* x_num   = (const float*)d_in[0];
    const float* x_cat   = (const float*)d_in[1];
    const float* cxn     = (const float*)d_in[2];
    const float* cxc     = (const float*)d_in[3];
    const float* cand_y  = (const float*)d_in[4];
    const float* freq    = (const float*)d_in[6];
    const float* plr_w   = (const float*)d_in[7];
    const float* plr_b   = (const float*)d_in[8];
    const float* lin_w   = (const float*)d_in[9];
    const float* lin_b   = (const float*)d_in[10];
    const float* enc_w1  = (const float*)d_in[11];
    const float* enc_b1  = (const float*)d_in[12];
    const float* enc_w2  = (const float*)d_in[13];
    const float* enc_b2  = (const float*)d_in[14];
    const float* mix_g   = (const float*)d_in[15];
    const float* mix_b   = (const float*)d_in[16];
    const float* K_w     = (const float*)d_in[17];
    const float* K_b     = (const float*)d_in[18];
    const float* label_w = (const float*)d_in[19];
    const float* label_b = (const float*)d_in[20];
    const float* T_w1    = (const float*)d_in[21];
    const float* T_b1    = (const float*)d_in[22];
    const float* T_w2    = (const float*)d_in[23];
    const float* pred_g  = (const float*)d_in[24];
    const float* pred_b  = (const float*)d_in[25];
    const float* pred_w1 = (const float*)d_in[26];
    const float* pred_b1 = (const float*)d_in[27];
    const float* pred_w2 = (const float*)d_in[28];
    const float* pred_b2 = (const float*)d_in[29];
    const float* head_g  = (const float*)d_in[30];
    const float* head_b  = (const float*)d_in[31];
    const float* head_w  = (const float*)d_in[32];
    const float* head_bias = (const float*)d_in[33];
    float* out = (float*)d_out;

    char* ws = (char*)d_ws;
    size_t off = 0;
    auto alloc = [&](size_t n) { char* p = ws + off; off = (off + n + 255) & ~(size_t)255; return p; };

    typedef unsigned short u16;
    // --- bf16 weights (transposed to N x Kp), hi/lo ---
    u16* lin_wt_h = (u16*)alloc((size_t)DM * KP_IN * 2);
    u16* lin_wt_l = (u16*)alloc((size_t)DM * KP_IN * 2);
    u16* e1t_h    = (u16*)alloc((size_t)DBK * DM * 2);
    u16* e1t_l    = (u16*)alloc((size_t)DBK * DM * 2);
    u16* e2t_h    = (u16*)alloc((size_t)DM * DBK * 2);
    u16* e2t_l    = (u16*)alloc((size_t)DM * DBK * 2);
    u16* K_wt_h   = (u16*)alloc((size_t)DM * DM * 2);
    u16* K_wt_l   = (u16*)alloc((size_t)DM * DM * 2);
    u16* T_w1t    = (u16*)alloc((size_t)DBK * DM * 2);
    u16* T_w2t_h  = (u16*)alloc((size_t)DM * DBK * 2);
    u16* T_w2t_l  = (u16*)alloc((size_t)DM * DBK * 2);
    u16* p1t_h    = (u16*)alloc((size_t)DBK * DM * 2);
    u16* p1t_l    = (u16*)alloc((size_t)DBK * DM * 2);
    u16* p2t_h    = (u16*)alloc((size_t)DM * DBK * 2);
    u16* p2t_l    = (u16*)alloc((size_t)DM * DBK * 2);
    // --- persistent ---
    u16*   T1c  = (u16*)alloc((size_t)NCAND * DBK * 2);   // 102.4 MB
    float* T1b  = (float*)alloc((size_t)NB * DBK * 4);
    float* xB   = (float*)alloc((size_t)NB * DM * 4);
    u16*   kBh  = (u16*)alloc((size_t)NB * DM * 2);
    u16*   kBl  = (u16*)alloc((size_t)NB * DM * 2);
    // batch scratch
    u16* binh = (u16*)alloc((size_t)NB * KP_IN * 2);
    u16* binl = (u16*)alloc((size_t)NB * KP_IN * 2);
    u16* xBhh = (u16*)alloc((size_t)NB * DM * 2);
    u16* xBhl = (u16*)alloc((size_t)NB * DM * 2);
    u16* hBh  = (u16*)alloc((size_t)NB * DBK * 2);
    u16* hBl  = (u16*)alloc((size_t)NB * DBK * 2);
    u16* lnBh = (u16*)alloc((size_t)NB * DM * 2);
    u16* lnBl = (u16*)alloc((size_t)NB * DM * 2);
    // ctx + tail
    int*   ctxAi = (int*)alloc((size_t)NB * CTX * 4);
    float* ctxAs = (float*)alloc((size_t)NB * CTX * 4);
    int*   ctxBi = (int*)alloc((size_t)NB * CTX * 4);
    float* ctxBs = (float*)alloc((size_t)NB * CTX * 4);
    u16*   sbufh = (u16*)alloc((size_t)NB * DBK * 2);
    u16*   sbufl = (u16*)alloc((size_t)NB * DBK * 2);
    float* ubuf  = (float*)alloc((size_t)NB * DM * 4);
    float* x2    = (float*)alloc((size_t)NB * DM * 4);
    u16*   h2h   = (u16*)alloc((size_t)NB * DM * 2);
    u16*   h2l   = (u16*)alloc((size_t)NB * DM * 2);
    u16*   hph   = (u16*)alloc((size_t)NB * DBK * 2);
    u16*   hpl   = (u16*)alloc((size_t)NB * DBK * 2);
    float* x3    = (float*)alloc((size_t)NB * DM * 4);

    // --- chunk arenas with lifetime-based aliasing (11.5 KB/row) ---
    size_t remain = (ws_size > off + 8192) ? (ws_size - off - 8192) : 0;
    const size_t perrow = 3328 + 2048 + 2048 + 4096 + 64;
    long ncl = (long)(remain / perrow);
    int NC = (int)(ncl > NCMAX ? NCMAX : ncl);   // NCMAX: topk LDS cache bound
    NC &= ~127;
    if (NC < 256) NC = 256;
    char* arenaA = alloc((size_t)NC * 3328);   // inCh+inCl -> kC + cnC
    char* arenaB = alloc((size_t)NC * 2048);   // xC -> scoresC
    char* arenaC = alloc((size_t)NC * 2048);   // xCh/xCl -> lnCh/lnCl
    char* arenaD = alloc((size_t)NC * 4096);   // hCh/hCl -> kCh/kCl
    u16* inCh = (u16*)arenaA;
    u16* inCl = inCh + (size_t)NC * KP_IN;
    float* kC  = (float*)arenaA;                       // after lin: inC dead
    float* cnC = (float*)(arenaA + (size_t)NC * 2048);
    float* xC  = (float*)arenaB;
    float* scoresC = (float*)arenaB;                   // after ln: xC dead
    u16* xCh  = (u16*)arenaC;
    u16* xCl  = xCh + (size_t)NC * DM;
    u16* lnCh = (u16*)arenaC;                          // after enc1: xCh dead
    u16* lnCl = lnCh + (size_t)NC * DM;
    u16* hCh  = (u16*)arenaD;
    u16* hCl  = hCh + (size_t)NC * DBK;
    u16* kCh  = (u16*)arenaD;                          // after enc2: hC dead
    u16* kCl  = kCh + (size_t)NC * DM;

    auto bgemm = [&](const u16* A, const u16* Bt, int M, int N, int Kp,
                     float* Cf, u16* Cb, const float* bias, int flags) {
        dim3 grid((N + 127) / 128, (M + 127) / 128);
        bgemm_kernel<<<grid, 512, 0, stream>>>(A, Bt, M, N, Kp, Cf, Cb, bias, flags);
    };
    auto bgemm3 = [&](const u16* Ah, const u16* Al, const u16* Bh, const u16* Bl,
                      int M, int N, int Kp, float* Cf, u16* Cbh, u16* Cbl,
                      const float* bias, const float* resf, const float* cnorm, int flags) {
        dim3 grid((N + 127) / 128, (M + 127) / 128);
        bgemm3_kernel<<<grid, 512, 0, stream>>>(Ah, Al, Bh, Bl, M, N, Kp,
                                                Cf, Cbh, Cbl, bias, resf, cnorm, flags);
    };
    auto bgemm3s = [&](const u16* Ah, const u16* Al, const u16* Bh, const u16* Bl,
                       int M, int N, int Kp, float* Cf, u16* Cbh, u16* Cbl,
                       const float* bias, const float* resf, int flags) {
        dim3 grid((N + 63) / 64, (M + 63) / 64);
        bgemm3s_kernel<<<grid, 256, 0, stream>>>(Ah, Al, Bh, Bl, M, N, Kp,
                                                 Cf, Cbh, Cbl, bias, resf, flags);
    };
    auto wprep = [&](const float* W, int K, int N, int Kp, u16* Wh, u16* Wl) {
        int n = N * Kp;
        wprep_kernel<<<(n + 255) / 256, 256, 0, stream>>>(W, K, N, Kp, Wh, Wl);
    };

    // ---------- weight prep ----------
    wprep(lin_w, DIN, DM, KP_IN, lin_wt_h, lin_wt_l);
    wprep(enc_w1, DM, DBK, DM, e1t_h, e1t_l);
    wprep(enc_w2, DBK, DM, DBK, e2t_h, e2t_l);
    wprep(K_w, DM, DM, DM, K_wt_h, K_wt_l);
    wprep(T_w1, DM, DBK, DM, T_w1t, nullptr);
    wprep(T_w2, DBK, DM, DBK, T_w2t_h, T_w2t_l);
    wprep(pred_w1, DM, DBK, DM, p1t_h, p1t_l);
    wprep(pred_w2, DBK, DM, DBK, p2t_h, p2t_l);

    // ---------- batch encode (64-tile split GEMMs) ----------
    plr_bf16_kernel<<<(NB + 3) / 4, 256, 0, stream>>>(x_num, x_cat, NB, freq, plr_w, plr_b, binh, binl);
    bgemm3s(binh, binl, lin_wt_h, lin_wt_l, NB, DM, KP_IN, xB, xBhh, xBhl, lin_b, nullptr, 0);
    bgemm3s(xBhh, xBhl, e1t_h, e1t_l, NB, DBK, DM, nullptr, hBh, hBl, enc_b1, nullptr, BG_RELU);
    bgemm3s(hBh, hBl, e2t_h, e2t_l, NB, DM, DBK, xB, nullptr, nullptr, enc_b2, xB, 0);
    ln_split_kernel<<<(NB + 3) / 4, 256, 0, stream>>>(xB, lnBh, lnBl, mix_g, mix_b, NB);
    bgemm3s(lnBh, lnBl, K_wt_h, K_wt_l, NB, DM, DM, nullptr, kBh, kBl, K_b, nullptr, 0);
    bgemm3s(kBh, nullptr, T_w1t, nullptr, NB, DBK, DM, T1b, nullptr, nullptr, nullptr, nullptr, 0);
    ctx_init_kernel<<<(NB * CTX + 255) / 256, 256, 0, stream>>>(ctxAi, ctxAs);

    // ---------- candidate chunks (128-tile, 512-thread GEMMs) ----------
    const int* pI = ctxAi; const float* pS = ctxAs;
    int* nI = ctxBi; float* nS = ctxBs;
    int nch = (NCAND + NC - 1) / NC;
    for (int c = 0; c < nch; c++) {
        int s = c * NC;
        int m = NCAND - s; if (m > NC) m = NC;
        plr_bf16_kernel<<<(m + 3) / 4, 256, 0, stream>>>(cxn + (size_t)s * NFEAT,
                                                         cxc + (size_t)s * NCAT,
                                                         m, freq, plr_w, plr_b, inCh, inCl);
        bgemm3(inCh, inCl, lin_wt_h, lin_wt_l, m, DM, KP_IN, xC, xCh, xCl, lin_b, nullptr, nullptr, 0);
        bgemm3(xCh, xCl, e1t_h, e1t_l, m, DBK, DM, nullptr, hCh, hCl, enc_b1, nullptr, nullptr, BG_RELU);
        bgemm3(hCh, hCl, e2t_h, e2t_l, m, DM, DBK, xC, nullptr, nullptr, enc_b2, xC, nullptr, 0);
        ln_split_kernel<<<(m + 3) / 4, 256, 0, stream>>>(xC, lnCh, lnCl, mix_g, mix_b, m);
        bgemm3(lnCh, lnCl, K_wt_h, K_wt_l, m, DM, DM, kC, kCh, kCl, K_b, nullptr, nullptr, 0);
        cnorm_kernel<<<(m + 3) / 4, 256, 0, stream>>>(kC, cnC, m);
        bgemm(kCh, T_w1t, m, DBK, DM, nullptr, T1c + (size_t)s * DBK, nullptr, 0);
        bgemm3(kBh, kBl, kCh, kCl, NB, m, DM, scoresC, nullptr, nullptr,
               nullptr, nullptr, cnC, BG_SCORE);
        topk_merge_kernel<<<NB, 256, 0, stream>>>(scoresC, m, s, pI, pS, nI, nS);
        { const int* t = pI; pI = nI; nI = (int*)t; }
        { const float* t = pS; pS = nS; nS = (float*)t; }
    }

    // ---------- aggregation + predictor + head (64-tile split GEMMs) ----------
    agg_kernel<<<NB, 256, 0, stream>>>(pI, pS, cand_y, T1b, T1c, T_b1,
                                       xB, label_w, label_b, sbufh, sbufl, ubuf);
    bgemm3s(sbufh, sbufl, T_w2t_h, T_w2t_l, NB, DM, DBK, x2, nullptr, nullptr,
            nullptr, ubuf, 0);
    ln_split_kernel<<<(NB + 3) / 4, 256, 0, stream>>>(x2, h2h, h2l, pred_g, pred_b, NB);
    bgemm3s(h2h, h2l, p1t_h, p1t_l, NB, DBK, DM, nullptr, hph, hpl, pred_b1, nullptr, BG_RELU);
    bgemm3s(hph, hpl, p2t_h, p2t_l, NB, DM, DBK, x3, nullptr, nullptr, pred_b2, x2, 0);
    head_kernel<<<(NB + 3) / 4, 256, 0, stream>>>(x3, head_g, head_b, head_w, head_bias, out, NB);
}

// Round 11
// 2157.811 us; speedup vs baseline: 1.5030x; 1.0174x over previous
//
#include <hip/hip_runtime.h>

#define NCAND 50000
#define NB    512
#define DIN   820
#define KP_IN 832
#define DM    512
#define DBK   1024
#define NFEAT 50
#define NCAT  20
#define NFREQ 16
#define DEMB  16
#define CTX   96
#define NCMAX 9216
#define TOTMAX (NCMAX + CTX)

typedef __attribute__((ext_vector_type(8))) short short8;
typedef __attribute__((ext_vector_type(4))) float f32x4;

static __device__ __forceinline__ unsigned short f2bf(float f) {
    union { float f; unsigned int i; } u; u.f = f;
    unsigned int r = u.i + 0x7FFFu + ((u.i >> 16) & 1u);
    return (unsigned short)(r >> 16);
}
static __device__ __forceinline__ float bf2f(unsigned short s) {
    union { unsigned int i; float f; } u; u.i = ((unsigned int)s) << 16;
    return u.f;
}
// order-preserving float->uint key (ascending), exact bijection
static __device__ __forceinline__ unsigned int f2key(float f) {
    union { float f; unsigned int i; } u; u.f = f;
    return (u.i & 0x80000000u) ? ~u.i : (u.i | 0x80000000u);
}
static __device__ __forceinline__ float key2f(unsigned int k) {
    union { unsigned int i; float f; } u;
    u.i = (k & 0x80000000u) ? (k ^ 0x80000000u) : ~k;
    return u.f;
}

#define GLDS16(g, l) __builtin_amdgcn_global_load_lds( \
    (const __attribute__((address_space(1))) void*)(g), \
    (__attribute__((address_space(3))) void*)(l), 16, 0, 0)

#define BG_RELU  1
#define BG_SCORE 2

// XCD swizzle: blocks sharing the big-dimension tile get linear IDs congruent
// mod 8 -> same XCD under round-robin dispatch -> shared tile fetched once/XCD.
// bigx=0: big dim is y (M); bigx=1: big dim is x (N).
static __device__ __forceinline__ int swizzle_blk(int L, int nbx, int nby, int bigx,
                                                  int* bx, int* by)
{
    int nsm = bigx ? nby : nbx;
    int xcd = L & 7, slot = L >> 3;
    int big = xcd + 8 * (slot / nsm);
    int sml = slot % nsm;
    *bx = bigx ? big : sml;
    *by = bigx ? sml : big;
    return (*bx < nbx) && (*by < nby);
}

// ---------------------------------------------------------------- weight prep
__global__ __launch_bounds__(256) void wprep_kernel(
    const float* __restrict__ W, int K, int N, int Kp,
    unsigned short* __restrict__ Wh, unsigned short* __restrict__ Wl)
{
    int idx = blockIdx.x * 256 + threadIdx.x;
    if (idx >= N * Kp) return;
    int n = idx / Kp, k = idx % Kp;
    float v = (k < K) ? W[(size_t)k * N + n] : 0.f;
    unsigned short h = f2bf(v);
    Wh[idx] = h;
    if (Wl) Wl[idx] = f2bf(v - bf2f(h));
}

// ---------------------------------------------------------------- PLR encode (bf16 hi/lo out)
__global__ __launch_bounds__(256) void plr_bf16_kernel(
    const float* __restrict__ xn_, const float* __restrict__ xc_, int nrows,
    const float* __restrict__ freq, const float* __restrict__ plr_w,
    const float* __restrict__ plr_b,
    unsigned short* __restrict__ oh, unsigned short* __restrict__ ol)
{
    __shared__ float sW[32 * 16];
    __shared__ float sB[16];
    __shared__ float sF[NFEAT * NFREQ];
    int tid = threadIdx.x;
    for (int i = tid; i < 512; i += 256) sW[i] = plr_w[i];
    if (tid < 16) sB[tid] = plr_b[tid];
    for (int i = tid; i < NFEAT * NFREQ; i += 256) sF[i] = freq[i];
    __syncthreads();
    int wave = tid >> 6, lane = tid & 63;
    int row = blockIdx.x * 4 + wave;
    if (row >= nrows) return;
    const float* xn = xn_ + (size_t)row * NFEAT;
    const float* xc = xc_ + (size_t)row * NCAT;
    unsigned short* ph = oh + (size_t)row * KP_IN;
    unsigned short* pl = ol + (size_t)row * KP_IN;
    if (lane < NFEAT) {
        float x = xn[lane];
        float cs[NFREQ], sn[NFREQ];
        #pragma unroll
        for (int j = 0; j < NFREQ; j++) {
            float p = 6.28318530717958647692f * sF[lane * NFREQ + j] * x;
            sn[j] = __sinf(p);
            cs[j] = __cosf(p);
        }
        #pragma unroll
        for (int d = 0; d < DEMB; d++) {
            float acc = sB[d];
            #pragma unroll
            for (int j = 0; j < NFREQ; j++)
                acc = fmaf(cs[j], sW[j * DEMB + d], fmaf(sn[j], sW[(NFREQ + j) * DEMB + d], acc));
            float v = fmaxf(acc, 0.f);
            unsigned short h = f2bf(v);
            ph[lane * DEMB + d] = h;
            pl[lane * DEMB + d] = f2bf(v - bf2f(h));
        }
    }
    if (lane < NCAT) {
        float v = xc[lane];
        unsigned short h = f2bf(v);
        ph[800 + lane] = h;
        pl[800 + lane] = f2bf(v - bf2f(h));
    }
    if (lane >= NCAT && lane < 32) {
        ph[800 + lane] = 0;
        pl[800 + lane] = 0;
    }
}

// ------------------------------- bf16 MFMA GEMM (plain 1-term), 128 tile, 512 threads
__global__ __launch_bounds__(512) void bgemm_kernel(
    const unsigned short* __restrict__ A, const unsigned short* __restrict__ Bt,
    int M, int N, int Kp, int nbx, int nby, int bigx,
    float* __restrict__ Cf, unsigned short* __restrict__ Cb,
    const float* __restrict__ bias, int flags)
{
    __shared__ unsigned short As[128 * 32];
    __shared__ unsigned short Bs[128 * 32];
    int bxi, byi;
    if (!swizzle_blk(blockIdx.x, nbx, nby, bigx, &bxi, &byi)) return;
    int tid = threadIdx.x;
    int w = tid >> 6, lane = tid & 63;
    int m0 = byi * 128, n0 = bxi * 128;
    int wr = (w >> 1) * 32, wc = (w & 1) * 64;

    f32x4 acc[2][4];
    #pragma unroll
    for (int i = 0; i < 2; i++)
        #pragma unroll
        for (int j = 0; j < 4; j++) acc[i][j] = (f32x4){0.f, 0.f, 0.f, 0.f};

    int arr = w & 1;
    int qrt = (w >> 1) * 32;
    int scol = (((lane & 3) - ((lane >> 3) & 3)) & 3) * 8;
    const unsigned short* gsrc = arr ? Bt : A;
    int glim = arr ? (N - 1) : (M - 1);
    int gb   = arr ? n0 : m0;
    unsigned short* ldst = arr ? Bs : As;
    const unsigned short* gp0 = gsrc + (size_t)min(gb + qrt + (lane >> 2),      glim) * Kp + scol;
    const unsigned short* gp1 = gsrc + (size_t)min(gb + qrt + 16 + (lane >> 2), glim) * Kp + scol;
    unsigned short* lp0 = ldst + qrt * 32;
    unsigned short* lp1 = ldst + (qrt + 16) * 32;

    int fr = lane & 15, q = lane >> 4;
    int pcs = ((q + (fr >> 1)) & 3) * 8;

    for (int k0 = 0; k0 < Kp; k0 += 32) {
        __syncthreads();
        GLDS16(gp0 + k0, lp0);
        GLDS16(gp1 + k0, lp1);
        __syncthreads();
        short8 a[2], b[4];
        #pragma unroll
        for (int i = 0; i < 2; i++)
            a[i] = *(const short8*)&As[(wr + i * 16 + fr) * 32 + pcs];
        #pragma unroll
        for (int j = 0; j < 4; j++)
            b[j] = *(const short8*)&Bs[(wc + j * 16 + fr) * 32 + pcs];
        #pragma unroll
        for (int i = 0; i < 2; i++)
            #pragma unroll
            for (int j = 0; j < 4; j++)
                acc[i][j] = __builtin_amdgcn_mfma_f32_16x16x32_bf16(a[i], b[j], acc[i][j], 0, 0, 0);
    }

    int col = lane & 15, rq = (lane >> 4) * 4;
    #pragma unroll
    for (int i = 0; i < 2; i++)
        #pragma unroll
        for (int j = 0; j < 4; j++) {
            int n_g = n0 + wc + j * 16 + col;
            #pragma unroll
            for (int r = 0; r < 4; r++) {
                int m_g = m0 + wr + i * 16 + rq + r;
                if (m_g < M && n_g < N) {
                    float v = acc[i][j][r];
                    if (bias) v += bias[n_g];
                    if (flags & BG_RELU) v = fmaxf(v, 0.f);
                    if (Cf) Cf[(size_t)m_g * N + n_g] = v;
                    if (Cb) Cb[(size_t)m_g * N + n_g] = f2bf(v);
                }
            }
        }
}

// ------------------------- bf16 MFMA GEMM, 3-term split, 128 tile, 512 threads
__global__ __launch_bounds__(512) void bgemm3_kernel(
    const unsigned short* __restrict__ Ah, const unsigned short* __restrict__ Al,
    const unsigned short* __restrict__ Bh, const unsigned short* __restrict__ Bl,
    int M, int N, int Kp, int nbx, int nby, int bigx,
    float* __restrict__ Cf, unsigned short* __restrict__ Cbh, unsigned short* __restrict__ Cbl,
    const float* __restrict__ bias, const float* __restrict__ resf,
    const float* __restrict__ cnorm, int flags)
{
    __shared__ unsigned short Ash[128 * 32];
    __shared__ unsigned short Asl[128 * 32];
    __shared__ unsigned short Bsh[128 * 32];
    __shared__ unsigned short Bsl[128 * 32];
    int bxi, byi;
    if (!swizzle_blk(blockIdx.x, nbx, nby, bigx, &bxi, &byi)) return;
    int tid = threadIdx.x;
    int w = tid >> 6, lane = tid & 63;
    int m0 = byi * 128, n0 = bxi * 128;
    int wr = (w >> 1) * 32, wc = (w & 1) * 64;

    f32x4 acc[2][4];
    #pragma unroll
    for (int i = 0; i < 2; i++)
        #pragma unroll
        for (int j = 0; j < 4; j++) acc[i][j] = (f32x4){0.f, 0.f, 0.f, 0.f};

    int arr = w & 3;
    int half = (w >> 2) * 64;
    int scol = (((lane & 3) - ((lane >> 3) & 3)) & 3) * 8;
    const unsigned short* gsrc = (arr == 0) ? Ah : (arr == 1) ? Al : (arr == 2) ? Bh : Bl;
    int glim = (arr < 2) ? (M - 1) : (N - 1);
    int gb   = (arr < 2) ? m0 : n0;
    unsigned short* ldst = (arr == 0) ? Ash : (arr == 1) ? Asl : (arr == 2) ? Bsh : Bsl;
    const unsigned short* gp[4];
    unsigned short* lp[4];
    #pragma unroll
    for (int t = 0; t < 4; t++) {
        int r = half + t * 16;
        gp[t] = gsrc + (size_t)min(gb + r + (lane >> 2), glim) * Kp + scol;
        lp[t] = ldst + r * 32;
    }

    int fr = lane & 15, q = lane >> 4;
    int pcs = ((q + (fr >> 1)) & 3) * 8;

    for (int k0 = 0; k0 < Kp; k0 += 32) {
        __syncthreads();
        GLDS16(gp[0] + k0, lp[0]);
        GLDS16(gp[1] + k0, lp[1]);
        GLDS16(gp[2] + k0, lp[2]);
        GLDS16(gp[3] + k0, lp[3]);
        __syncthreads();
        short8 a[2], b[4];
        #pragma unroll
        for (int i = 0; i < 2; i++)
            a[i] = *(const short8*)&Ash[(wr + i * 16 + fr) * 32 + pcs];
        #pragma unroll
        for (int j = 0; j < 4; j++)
            b[j] = *(const short8*)&Bsh[(wc + j * 16 + fr) * 32 + pcs];
        #pragma unroll
        for (int i = 0; i < 2; i++)
            #pragma unroll
            for (int j = 0; j < 4; j++)
                acc[i][j] = __builtin_amdgcn_mfma_f32_16x16x32_bf16(a[i], b[j], acc[i][j], 0, 0, 0);
        short8 al2[2];
        #pragma unroll
        for (int i = 0; i < 2; i++)
            al2[i] = *(const short8*)&Asl[(wr + i * 16 + fr) * 32 + pcs];
        #pragma unroll
        for (int i = 0; i < 2; i++)
            #pragma unroll
            for (int j = 0; j < 4; j++)
                acc[i][j] = __builtin_amdgcn_mfma_f32_16x16x32_bf16(al2[i], b[j], acc[i][j], 0, 0, 0);
        short8 bl2[4];
        #pragma unroll
        for (int j = 0; j < 4; j++)
            bl2[j] = *(const short8*)&Bsl[(wc + j * 16 + fr) * 32 + pcs];
        #pragma unroll
        for (int i = 0; i < 2; i++)
            #pragma unroll
            for (int j = 0; j < 4; j++)
                acc[i][j] = __builtin_amdgcn_mfma_f32_16x16x32_bf16(a[i], bl2[j], acc[i][j], 0, 0, 0);
    }

    int col = lane & 15, rq = (lane >> 4) * 4;
    #pragma unroll
    for (int i = 0; i < 2; i++)
        #pragma unroll
        for (int j = 0; j < 4; j++) {
            int n_g = n0 + wc + j * 16 + col;
            #pragma unroll
            for (int r = 0; r < 4; r++) {
                int m_g = m0 + wr + i * 16 + rq + r;
                if (m_g < M && n_g < N) {
                    float v = acc[i][j][r];
                    if (bias) v += bias[n_g];
                    if (resf) v += resf[(size_t)m_g * N + n_g];
                    if (flags & BG_RELU) v = fmaxf(v, 0.f);
                    if (flags & BG_SCORE) v = 2.f * v - cnorm[n_g];
                    if (Cf) Cf[(size_t)m_g * N + n_g] = v;
                    if (Cbh) {
                        unsigned short h = f2bf(v);
                        Cbh[(size_t)m_g * N + n_g] = h;
                        if (Cbl) Cbl[(size_t)m_g * N + n_g] = f2bf(v - bf2f(h));
                    }
                }
            }
        }
}

// ------------------------- small-M GEMM: 64x64 tile, 1- or 3-term (Al null => 1-term)
__global__ __launch_bounds__(256) void bgemm3s_kernel(
    const unsigned short* __restrict__ Ah, const unsigned short* __restrict__ Al,
    const unsigned short* __restrict__ Bh, const unsigned short* __restrict__ Bl,
    int M, int N, int Kp,
    float* __restrict__ Cf, unsigned short* __restrict__ Cbh, unsigned short* __restrict__ Cbl,
    const float* __restrict__ bias, const float* __restrict__ resf, int flags)
{
    __shared__ unsigned short Ash[64 * 32];
    __shared__ unsigned short Asl[64 * 32];
    __shared__ unsigned short Bsh[64 * 32];
    __shared__ unsigned short Bsl[64 * 32];
    int tid = threadIdx.x;
    int w = tid >> 6, lane = tid & 63;
    int m0 = blockIdx.y * 64, n0 = blockIdx.x * 64;
    int wr = (w >> 1) * 32, wc = (w & 1) * 32;
    int three = (Al != nullptr);

    f32x4 acc[2][2];
    #pragma unroll
    for (int i = 0; i < 2; i++)
        #pragma unroll
        for (int j = 0; j < 2; j++) acc[i][j] = (f32x4){0.f, 0.f, 0.f, 0.f};

    int srow = w * 16 + (lane >> 2);
    int scol = (((lane & 3) - ((lane >> 3) & 3)) & 3) * 8;
    size_t ra = (size_t)min(m0 + srow, M - 1) * Kp + scol;
    size_t rb = (size_t)min(n0 + srow, N - 1) * Kp + scol;
    unsigned short* lah = &Ash[(w * 16) * 32];
    unsigned short* lal = &Asl[(w * 16) * 32];
    unsigned short* lbh = &Bsh[(w * 16) * 32];
    unsigned short* lbl = &Bsl[(w * 16) * 32];

    int fr = lane & 15, q = lane >> 4;
    int pcs = ((q + (fr >> 1)) & 3) * 8;

    for (int k0 = 0; k0 < Kp; k0 += 32) {
        __syncthreads();
        GLDS16(Ah + ra + k0, lah);
        GLDS16(Bh + rb + k0, lbh);
        if (three) {
            GLDS16(Al + ra + k0, lal);
            GLDS16(Bl + rb + k0, lbl);
        }
        __syncthreads();
        short8 a[2], b[2];
        #pragma unroll
        for (int i = 0; i < 2; i++)
            a[i] = *(const short8*)&Ash[(wr + i * 16 + fr) * 32 + pcs];
        #pragma unroll
        for (int j = 0; j < 2; j++)
            b[j] = *(const short8*)&Bsh[(wc + j * 16 + fr) * 32 + pcs];
        #pragma unroll
        for (int i = 0; i < 2; i++)
            #pragma unroll
            for (int j = 0; j < 2; j++)
                acc[i][j] = __builtin_amdgcn_mfma_f32_16x16x32_bf16(a[i], b[j], acc[i][j], 0, 0, 0);
        if (three) {
            short8 al2[2], bl2[2];
            #pragma unroll
            for (int i = 0; i < 2; i++)
                al2[i] = *(const short8*)&Asl[(wr + i * 16 + fr) * 32 + pcs];
            #pragma unroll
            for (int j = 0; j < 2; j++)
                bl2[j] = *(const short8*)&Bsl[(wc + j * 16 + fr) * 32 + pcs];
            #pragma unroll
            for (int i = 0; i < 2; i++)
                #pragma unroll
                for (int j = 0; j < 2; j++) {
                    acc[i][j] = __builtin_amdgcn_mfma_f32_16x16x32_bf16(al2[i], b[j], acc[i][j], 0, 0, 0);
                    acc[i][j] = __builtin_amdgcn_mfma_f32_16x16x32_bf16(a[i], bl2[j], acc[i][j], 0, 0, 0);
                }
        }
    }

    int col = lane & 15, rq = (lane >> 4) * 4;
    #pragma unroll
    for (int i = 0; i < 2; i++)
        #pragma unroll
        for (int j = 0; j < 2; j++) {
            int n_g = n0 + wc + j * 16 + col;
            #pragma unroll
            for (int r = 0; r < 4; r++) {
                int m_g = m0 + wr + i * 16 + rq + r;
                if (m_g < M && n_g < N) {
                    float v = acc[i][j][r];
                    if (bias) v += bias[n_g];
                    if (resf) v += resf[(size_t)m_g * N + n_g];
                    if (flags & BG_RELU) v = fmaxf(v, 0.f);
                    if (Cf) Cf[(size_t)m_g * N + n_g] = v;
                    if (Cbh) {
                        unsigned short h = f2bf(v);
                        Cbh[(size_t)m_g * N + n_g] = h;
                        if (Cbl) Cbl[(size_t)m_g * N + n_g] = f2bf(v - bf2f(h));
                    }
                }
            }
        }
}

// ---------------------------------------------------------------- LayerNorm bf16 hi/lo out
__global__ __launch_bounds__(256) void ln_split_kernel(const float* __restrict__ X,
    unsigned short* __restrict__ Yh, unsigned short* __restrict__ Yl,
    const float* __restrict__ g, const float* __restrict__ bt, int M)
{
    int wave = threadIdx.x >> 6, lane = threadIdx.x & 63;
    int row = blockIdx.x * 4 + wave;
    if (row >= M) return;
    const float* x = X + (size_t)row * DM;
    float4 v0 = ((const float4*)x)[lane * 2];
    float4 v1 = ((const float4*)x)[lane * 2 + 1];
    float s = v0.x + v0.y + v0.z + v0.w + v1.x + v1.y + v1.z + v1.w;
    #pragma unroll
    for (int off = 32; off; off >>= 1) s += __shfl_xor(s, off, 64);
    float m = s * (1.f / DM);
    float q = (v0.x - m) * (v0.x - m) + (v0.y - m) * (v0.y - m)
            + (v0.z - m) * (v0.z - m) + (v0.w - m) * (v0.w - m)
            + (v1.x - m) * (v1.x - m) + (v1.y - m) * (v1.y - m)
            + (v1.z - m) * (v1.z - m) + (v1.w - m) * (v1.w - m);
    #pragma unroll
    for (int off = 32; off; off >>= 1) q += __shfl_xor(q, off, 64);
    float rstd = 1.f / sqrtf(q * (1.f / DM) + 1e-5f);
    float vals[8] = {v0.x, v0.y, v0.z, v0.w, v1.x, v1.y, v1.z, v1.w};
    unsigned short* yh = Yh + (size_t)row * DM + lane * 8;
    unsigned short* yl = Yl + (size_t)row * DM + lane * 8;
    const float* gp = g + lane * 8;
    const float* bp = bt + lane * 8;
    #pragma unroll
    for (int i = 0; i < 8; i++) {
        float y = (vals[i] - m) * rstd * gp[i] + bp[i];
        unsigned short h = f2bf(y);
        yh[i] = h;
        yl[i] = f2bf(y - bf2f(h));
    }
}

// ---------------------------------------------------------------- key norms (fp32 k)
__global__ __launch_bounds__(256) void cnorm_kernel(const float* __restrict__ Kc,
    float* __restrict__ cn, int N)
{
    int wave = threadIdx.x >> 6, lane = threadIdx.x & 63;
    int row = blockIdx.x * 4 + wave;
    if (row >= N) return;
    const float* x = Kc + (size_t)row * DM;
    float4 v0 = ((const float4*)x)[lane * 2];
    float4 v1 = ((const float4*)x)[lane * 2 + 1];
    float s = v0.x * v0.x + v0.y * v0.y + v0.z * v0.z + v0.w * v0.w
            + v1.x * v1.x + v1.y * v1.y + v1.z * v1.z + v1.w * v1.w;
    #pragma unroll
    for (int off = 32; off; off >>= 1) s += __shfl_xor(s, off, 64);
    if (lane == 0) cn[row] = s;
}

// ---------------------------------------------------------------- ctx init
__global__ void ctx_init_kernel(int* __restrict__ idx, float* __restrict__ sc)
{
    int i = blockIdx.x * 256 + threadIdx.x;
    if (i < NB * CTX) { idx[i] = 0; sc[i] = -1e30f; }
}

// ------------------------------------- running top-96 merge: exact radix select
// LDS key cache + hybrid histogram + parallel suffix-scan bin selection.
// Deterministic: (score desc, idx asc) order.
#define CANDCAP 2048
__global__ __launch_bounds__(256) void topk_merge_kernel(
    const float* __restrict__ S, int m, int base,
    const int* __restrict__ pidx, const float* __restrict__ pscore,
    int* __restrict__ nidx, float* __restrict__ nscore)
{
    __shared__ __align__(16) unsigned int ks[TOTMAX];
    __shared__ unsigned int hist[4 * 256];
    __shared__ unsigned int sfx[256];
    __shared__ unsigned int s_prefix;
    __shared__ int s_above;
    __shared__ int prev_i[CTX];
    __shared__ int nsel, neq;
    __shared__ float sel_s[CTX];
    __shared__ int   sel_g[CTX];
    __shared__ int   cnd_g[CANDCAP];

    int b = blockIdx.x, tid = threadIdx.x;
    int lane = tid & 63, wv = tid >> 6;
    const float* Sb = S + (size_t)b * m;
    int tot = m + CTX;

    int m4 = m >> 2;
    const float4* S4 = (const float4*)Sb;
    for (int i = tid; i < m4; i += 256) {
        float4 v = S4[i];
        uint4 kk;
        kk.x = f2key(v.x); kk.y = f2key(v.y); kk.z = f2key(v.z); kk.w = f2key(v.w);
        ((uint4*)ks)[i] = kk;
    }
    for (int i = (m4 << 2) + tid; i < m; i += 256) ks[i] = f2key(Sb[i]);
    if (tid < CTX) {
        ks[m + tid] = f2key(pscore[b * CTX + tid]);
        prev_i[tid] = pidx[b * CTX + tid];
    }
    if (tid == 0) { s_prefix = 0u; s_above = 0; nsel = 0; neq = 0; }
    __syncthreads();

    unsigned int* myhist = &hist[wv * 256];

    for (int pass = 0; pass < 4; pass++) {
        int shift = 24 - pass * 8;
        for (int i = tid; i < 1024; i += 256) hist[i] = 0;
        __syncthreads();
        unsigned int pref = s_prefix;
        unsigned int msk = (pass == 0) ? 0u : (0xFFFFFFFFu << (32 - 8 * pass));
        for (int i0 = 0; i0 < tot; i0 += 256) {
            int i = i0 + tid;
            int pred = 0, digit = 0;
            if (i < tot) {
                unsigned int k = ks[i];
                pred = ((k & msk) == pref);
                digit = (int)((k >> shift) & 255u);
            }
            unsigned long long act = __ballot(pred);
            if (!act) continue;
            int lead = (int)__ffsll(act) - 1;
            int d0 = __shfl(digit, lead, 64);
            unsigned long long same = __ballot(pred && (digit == d0));
            if (same == act) {
                if (lane == lead) atomicAdd(&myhist[d0], (unsigned int)__popcll(act));
            } else {
                if (pred) atomicAdd(&myhist[digit], 1u);
            }
        }
        __syncthreads();
        unsigned int hb = hist[tid] + hist[256 + tid] + hist[512 + tid] + hist[768 + tid];
        __syncthreads();
        hist[tid] = hb;
        sfx[tid] = hb;
        __syncthreads();
        #pragma unroll
        for (int offd = 1; offd < 256; offd <<= 1) {
            unsigned int v = (tid + offd < 256) ? sfx[tid + offd] : 0u;
            __syncthreads();
            sfx[tid] += v;
            __syncthreads();
        }
        {
            int incl = s_above + (int)sfx[tid];
            int excl = incl - (int)hb;
            if (excl < CTX && incl >= CTX) {
                s_prefix = pref | ((unsigned int)tid << shift);
                s_above = excl;
            }
        }
        __syncthreads();
    }
    unsigned int thrK = s_prefix;
    int msel = CTX - s_above;
    float eqv = key2f(thrK);

    for (int i = tid; i < tot; i += 256) {
        unsigned int k = ks[i];
        if (k < thrK) continue;
        int g = (i < m) ? (base + i) : prev_i[i - m];
        if (k > thrK) {
            int p = atomicAdd(&nsel, 1);
            sel_s[p] = key2f(k); sel_g[p] = g;
        } else {
            int p = atomicAdd(&neq, 1);
            if (p < CANDCAP) cnd_g[p] = g;
        }
    }
    __syncthreads();
    int ne = neq;
    if (ne <= CANDCAP) {
        for (int i = tid; i < ne; i += 256) {
            int gi = cnd_g[i];
            int rank = 0;
            for (int j = 0; j < ne; j++) rank += (cnd_g[j] < gi);
            if (rank < msel) {
                int p = atomicAdd(&nsel, 1);
                sel_s[p] = eqv; sel_g[p] = gi;
            }
        }
    } else {
        for (int i = tid; i < tot; i += 256) {
            if (ks[i] != thrK) continue;
            int g = (i < m) ? (base + i) : prev_i[i - m];
            int rank = 0;
            for (int j = 0; j < tot; j++) {
                if (ks[j] == thrK) {
                    int gj = (j < m) ? (base + j) : prev_i[j - m];
                    rank += (gj < g);
                }
            }
            if (rank < msel) {
                int p = atomicAdd(&nsel, 1);
                sel_s[p] = eqv; sel_g[p] = g;
            }
        }
    }
    __syncthreads();
    if (tid < CTX) {
        nidx[b * CTX + tid] = sel_g[tid];
        nscore[b * CTX + tid] = sel_s[tid];
    }
}

// ------------------------------- softmax + label/value context aggregation
__global__ __launch_bounds__(256) void agg_kernel(
    const int* __restrict__ ctx_idx, const float* __restrict__ ctx_score,
    const float* __restrict__ cand_y, const float* __restrict__ T1b,
    const unsigned short* __restrict__ T1c, const float* __restrict__ T_b1,
    const float* __restrict__ x_batch,
    const float* __restrict__ label_w, const float* __restrict__ label_b,
    unsigned short* __restrict__ s_h, unsigned short* __restrict__ s_l,
    float* __restrict__ u_out)
{
    __shared__ float p_s[CTX];
    __shared__ int   p_i[CTX];
    __shared__ float s_ybar;
    int b = blockIdx.x, tid = threadIdx.x;
    if (tid < CTX) { p_s[tid] = ctx_score[b * CTX + tid]; p_i[tid] = ctx_idx[b * CTX + tid]; }
    __syncthreads();
    if (tid == 0) {
        float mx = -1e30f;
        for (int c = 0; c < CTX; c++) mx = fmaxf(mx, p_s[c]);
        float sum = 0.f;
        for (int c = 0; c < CTX; c++) { float e = __expf(p_s[c] - mx); p_s[c] = e; sum += e; }
        float inv = 1.f / sum, yb = 0.f;
        for (int c = 0; c < CTX; c++) { p_s[c] *= inv; yb += p_s[c] * cand_y[p_i[c]]; }
        s_ybar = yb;
    }
    __syncthreads();
    int j = tid * 4;
    float4 kv = *(const float4*)(T1b + (size_t)b * DBK + j);
    float4 tb = *(const float4*)(T_b1 + j);
    float base0 = kv.x + tb.x, base1 = kv.y + tb.y, base2 = kv.z + tb.z, base3 = kv.w + tb.w;
    float a0 = 0.f, a1 = 0.f, a2 = 0.f, a3 = 0.f;
    for (int c = 0; c < CTX; c++) {
        float p = p_s[c];
        ushort4 cu = *(const ushort4*)(T1c + (size_t)p_i[c] * DBK + j);
        a0 = fmaf(p, fmaxf(base0 - bf2f(cu.x), 0.f), a0);
        a1 = fmaf(p, fmaxf(base1 - bf2f(cu.y), 0.f), a1);
        a2 = fmaf(p, fmaxf(base2 - bf2f(cu.z), 0.f), a2);
        a3 = fmaf(p, fmaxf(base3 - bf2f(cu.w), 0.f), a3);
    }
    {
        ushort4 oh, ol;
        oh.x = f2bf(a0); ol.x = f2bf(a0 - bf2f(oh.x));
        oh.y = f2bf(a1); ol.y = f2bf(a1 - bf2f(oh.y));
        oh.z = f2bf(a2); ol.z = f2bf(a2 - bf2f(oh.z));
        oh.w = f2bf(a3); ol.w = f2bf(a3 - bf2f(oh.w));
        *(ushort4*)(s_h + (size_t)b * DBK + j) = oh;
        *(ushort4*)(s_l + (size_t)b * DBK + j) = ol;
    }
    if (tid < 128) {
        int d = tid * 4;
        float4 xv = *(const float4*)(x_batch + (size_t)b * DM + d);
        float4 lw = *(const float4*)(label_w + d);
        float4 lb = *(const float4*)(label_b + d);
        float yb = s_ybar;
        *(float4*)(u_out + (size_t)b * DM + d) =
            make_float4(xv.x + yb * lw.x + lb.x, xv.y + yb * lw.y + lb.y,
                        xv.z + yb * lw.z + lb.z, xv.w + yb * lw.w + lb.w);
    }
}

// ---------------------------------------------------------------- head
__global__ __launch_bounds__(256) void head_kernel(
    const float* __restrict__ X, const float* __restrict__ g,
    const float* __restrict__ bt, const float* __restrict__ w,
    const float* __restrict__ hb, float* __restrict__ out, int M)
{
    int wave = threadIdx.x >> 6, lane = threadIdx.x & 63;
    int row = blockIdx.x * 4 + wave;
    if (row >= M) return;
    const float* x = X + (size_t)row * DM;
    float4 v0 = ((const float4*)x)[lane * 2];
    float4 v1 = ((const float4*)x)[lane * 2 + 1];
    float s = v0.x + v0.y + v0.z + v0.w + v1.x + v1.y + v1.z + v1.w;
    #pragma unroll
    for (int off = 32; off; off >>= 1) s += __shfl_xor(s, off, 64);
    float m = s * (1.f / DM);
    float q = (v0.x - m) * (v0.x - m) + (v0.y - m) * (v0.y - m)
            + (v0.z - m) * (v0.z - m) + (v0.w - m) * (v0.w - m)
            + (v1.x - m) * (v1.x - m) + (v1.y - m) * (v1.y - m)
            + (v1.z - m) * (v1.z - m) + (v1.w - m) * (v1.w - m);
    #pragma unroll
    for (int off = 32; off; off >>= 1) q += __shfl_xor(q, off, 64);
    float rstd = 1.f / sqrtf(q * (1.f / DM) + 1e-5f);
    float4 g0 = ((const float4*)g)[lane * 2], g1 = ((const float4*)g)[lane * 2 + 1];
    float4 b0 = ((const float4*)bt)[lane * 2], b1 = ((const float4*)bt)[lane * 2 + 1];
    float4 w0 = ((const float4*)w)[lane * 2], w1 = ((const float4*)w)[lane * 2 + 1];
    float t = 0.f;
    t += fmaxf((v0.x - m) * rstd * g0.x + b0.x, 0.f) * w0.x;
    t += fmaxf((v0.y - m) * rstd * g0.y + b0.y, 0.f) * w0.y;
    t += fmaxf((v0.z - m) * rstd * g0.z + b0.z, 0.f) * w0.z;
    t += fmaxf((v0.w - m) * rstd * g0.w + b0.w, 0.f) * w0.w;
    t += fmaxf((v1.x - m) * rstd * g1.x + b1.x, 0.f) * w1.x;
    t += fmaxf((v1.y - m) * rstd * g1.y + b1.y, 0.f) * w1.y;
    t += fmaxf((v1.z - m) * rstd * g1.z + b1.z, 0.f) * w1.z;
    t += fmaxf((v1.w - m) * rstd * g1.w + b1.w, 0.f) * w1.w;
    #pragma unroll
    for (int off = 32; off; off >>= 1) t += __shfl_xor(t, off, 64);
    if (lane == 0) out[row] = t + hb[0];
}

// =================================================================== host
extern "C" void kernel_launch(void* const* d_in, const int* in_sizes, int n_in,
                              void* d_out, int out_size, void* d_ws, size_t ws_size,
                              hipStream_t stream) {
    (void)in_sizes; (void)n_in; (void)out_size;
    const float* x_num   = (const float*)d_in[0];
    const float* x_cat   = (const float*)d_in[1];
    const float* cxn     = (const float*)d_in[2];
    const float* cxc     = (const float*)d_in[3];
    const float* cand_y  = (const float*)d_in[4];
    const float* freq    = (const float*)d_in[6];
    const float* plr_w   = (const float*)d_in[7];
    const float* plr_b   = (const float*)d_in[8];
    const float* lin_w   = (const float*)d_in[9];
    const float* lin_b   = (const float*)d_in[10];
    const float* enc_w1  = (const float*)d_in[11];
    const float* enc_b1  = (const float*)d_in[12];
    const float* enc_w2  = (const float*)d_in[13];
    const float* enc_b2  = (const float*)d_in[14];
    const float* mix_g   = (const float*)d_in[15];
    const float* mix_b   = (const float*)d_in[16];
    const float* K_w     = (const float*)d_in[17];
    const float* K_b     = (const float*)d_in[18];
    const float* label_w = (const float*)d_in[19];
    const float* label_b = (const float*)d_in[20];
    const float* T_w1    = (const float*)d_in[21];
    const float* T_b1    = (const float*)d_in[22];
    const float* T_w2    = (const float*)d_in[23];
    const float* pred_g  = (const float*)d_in[24];
    const float* pred_b  = (const float*)d_in[25];
    const float* pred_w1 = (const float*)d_in[26];
    const float* pred_b1 = (const float*)d_in[27];
    const float* pred_w2 = (const float*)d_in[28];
    const float* pred_b2 = (const float*)d_in[29];
    const float* head_g  = (const float*)d_in[30];
    const float* head_b  = (const float*)d_in[31];
    const float* head_w  = (const float*)d_in[32];
    const float* head_bias = (const float*)d_in[33];
    float* out = (float*)d_out;

    char* ws = (char*)d_ws;
    size_t off = 0;
    auto alloc = [&](size_t n) { char* p = ws + off; off = (off + n + 255) & ~(size_t)255; return p; };

    typedef unsigned short u16;
    // --- bf16 weights (transposed to N x Kp), hi/lo ---
    u16* lin_wt_h = (u16*)alloc((size_t)DM * KP_IN * 2);
    u16* lin_wt_l = (u16*)alloc((size_t)DM * KP_IN * 2);
    u16* e1t_h    = (u16*)alloc((size_t)DBK * DM * 2);
    u16* e1t_l    = (u16*)alloc((size_t)DBK * DM * 2);
    u16* e2t_h    = (u16*)alloc((size_t)DM * DBK * 2);
    u16* e2t_l    = (u16*)alloc((size_t)DM * DBK * 2);
    u16* K_wt_h   = (u16*)alloc((size_t)DM * DM * 2);
    u16* K_wt_l   = (u16*)alloc((size_t)DM * DM * 2);
    u16* T_w1t    = (u16*)alloc((size_t)DBK * DM * 2);
    u16* T_w2t_h  = (u16*)alloc((size_t)DM * DBK * 2);
    u16* T_w2t_l  = (u16*)alloc((size_t)DM * DBK * 2);
    u16* p1t_h    = (u16*)alloc((size_t)DBK * DM * 2);
    u16* p1t_l    = (u16*)alloc((size_t)DBK * DM * 2);
    u16* p2t_h    = (u16*)alloc((size_t)DM * DBK * 2);
    u16* p2t_l    = (u16*)alloc((size_t)DM * DBK * 2);
    // --- persistent ---
    u16*   T1c  = (u16*)alloc((size_t)NCAND * DBK * 2);   // 102.4 MB
    float* T1b  = (float*)alloc((size_t)NB * DBK * 4);
    float* xB   = (float*)alloc((size_t)NB * DM * 4);
    u16*   kBh  = (u16*)alloc((size_t)NB * DM * 2);
    u16*   kBl  = (u16*)alloc((size_t)NB * DM * 2);
    // batch scratch
    u16* binh = (u16*)alloc((size_t)NB * KP_IN * 2);
    u16* binl = (u16*)alloc((size_t)NB * KP_IN * 2);
    u16* xBhh = (u16*)alloc((size_t)NB * DM * 2);
    u16* xBhl = (u16*)alloc((size_t)NB * DM * 2);
    u16* hBh  = (u16*)alloc((size_t)NB * DBK * 2);
    u16* hBl  = (u16*)alloc((size_t)NB * DBK * 2);
    u16* lnBh = (u16*)alloc((size_t)NB * DM * 2);
    u16* lnBl = (u16*)alloc((size_t)NB * DM * 2);
    // ctx + tail
    int*   ctxAi = (int*)alloc((size_t)NB * CTX * 4);
    float* ctxAs = (float*)alloc((size_t)NB * CTX * 4);
    int*   ctxBi = (int*)alloc((size_t)NB * CTX * 4);
    float* ctxBs = (float*)alloc((size_t)NB * CTX * 4);
    u16*   sbufh = (u16*)alloc((size_t)NB * DBK * 2);
    u16*   sbufl = (u16*)alloc((size_t)NB * DBK * 2);
    float* ubuf  = (float*)alloc((size_t)NB * DM * 4);
    float* x2    = (float*)alloc((size_t)NB * DM * 4);
    u16*   h2h   = (u16*)alloc((size_t)NB * DM * 2);
    u16*   h2l   = (u16*)alloc((size_t)NB * DM * 2);
    u16*   hph   = (u16*)alloc((size_t)NB * DBK * 2);
    u16*   hpl   = (u16*)alloc((size_t)NB * DBK * 2);
    float* x3    = (float*)alloc((size_t)NB * DM * 4);

    // --- chunk arenas with lifetime-based aliasing (11.5 KB/row) ---
    size_t remain = (ws_size > off + 8192) ? (ws_size - off - 8192) : 0;
    const size_t perrow = 3328 + 2048 + 2048 + 4096 + 64;
    long ncl = (long)(remain / perrow);
    int NC = (int)(ncl > NCMAX ? NCMAX : ncl);   // NCMAX: topk LDS cache bound
    NC &= ~127;
    if (NC < 256) NC = 256;
    char* arenaA = alloc((size_t)NC * 3328);   // inCh+inCl -> kC + cnC
    char* arenaB = alloc((size_t)NC * 2048);   // xC -> scoresC
    char* arenaC = alloc((size_t)NC * 2048);   // xCh/xCl -> lnCh/lnCl
    char* arenaD = alloc((size_t)NC * 4096);   // hCh/hCl -> kCh/kCl
    u16* inCh = (u16*)arenaA;
    u16* inCl = inCh + (size_t)NC * KP_IN;
    float* kC  = (float*)arenaA;                       // after lin: inC dead
    float* cnC = (float*)(arenaA + (size_t)NC * 2048);
    float* xC  = (float*)arenaB;
    float* scoresC = (float*)arenaB;                   // after ln: xC dead
    u16* xCh  = (u16*)arenaC;
    u16* xCl  = xCh + (size_t)NC * DM;
    u16* lnCh = (u16*)arenaC;                          // after enc1: xCh dead
    u16* lnCl = lnCh + (size_t)NC * DM;
    u16* hCh  = (u16*)arenaD;
    u16* hCl  = hCh + (size_t)NC * DBK;
    u16* kCh  = (u16*)arenaD;                          // after enc2: hC dead
    u16* kCl  = kCh + (size_t)NC * DM;

    auto bgemm = [&](const u16* A, const u16* Bt, int M, int N, int Kp,
                     float* Cf, u16* Cb, const float* bias, int flags) {
        int nbx = (N + 127) / 128, nby = (M + 127) / 128;
        int npad = (nby + 7) & ~7;               // big = y (M rows)
        bgemm_kernel<<<npad * nbx, 512, 0, stream>>>(A, Bt, M, N, Kp, nbx, nby, 0,
                                                     Cf, Cb, bias, flags);
    };
    auto bgemm3 = [&](const u16* Ah, const u16* Al, const u16* Bh, const u16* Bl,
                      int M, int N, int Kp, int bigx, float* Cf, u16* Cbh, u16* Cbl,
                      const float* bias, const float* resf, const float* cnorm, int flags) {
        int nbx = (N + 127) / 128, nby = (M + 127) / 128;
        int nbig = bigx ? nbx : nby, nsm = bigx ? nby : nbx;
        int npad = (nbig + 7) & ~7;
        bgemm3_kernel<<<npad * nsm, 512, 0, stream>>>(Ah, Al, Bh, Bl, M, N, Kp,
                                                      nbx, nby, bigx,
                                                      Cf, Cbh, Cbl, bias, resf, cnorm, flags);
    };
    auto bgemm3s = [&](const u16* Ah, const u16* Al, const u16* Bh, const u16* Bl,
                       int M, int N, int Kp, float* Cf, u16* Cbh, u16* Cbl,
                       const float* bias, const float* resf, int flags) {
        dim3 grid((N + 63) / 64, (M + 63) / 64);
        bgemm3s_kernel<<<grid, 256, 0, stream>>>(Ah, Al, Bh, Bl, M, N, Kp,
                                                 Cf, Cbh, Cbl, bias, resf, flags);
    };
    auto wprep = [&](const float* W, int K, int N, int Kp, u16* Wh, u16* Wl) {
        int n = N * Kp;
        wprep_kernel<<<(n + 255) / 256, 256, 0, stream>>>(W, K, N, Kp, Wh, Wl);
    };

    // ---------- weight prep ----------
    wprep(lin_w, DIN, DM, KP_IN, lin_wt_h, lin_wt_l);
    wprep(enc_w1, DM, DBK, DM, e1t_h, e1t_l);
    wprep(enc_w2, DBK, DM, DBK, e2t_h, e2t_l);
    wprep(K_w, DM, DM, DM, K_wt_h, K_wt_l);
    wprep(T_w1, DM, DBK, DM, T_w1t, nullptr);
    wprep(T_w2, DBK, DM, DBK, T_w2t_h, T_w2t_l);
    wprep(pred_w1, DM, DBK, DM, p1t_h, p1t_l);
    wprep(pred_w2, DBK, DM, DBK, p2t_h, p2t_l);

    // ---------- batch encode (64-tile split GEMMs) ----------
    plr_bf16_kernel<<<(NB + 3) / 4, 256, 0, stream>>>(x_num, x_cat, NB, freq, plr_w, plr_b, binh, binl);
    bgemm3s(binh, binl, lin_wt_h, lin_wt_l, NB, DM, KP_IN, xB, xBhh, xBhl, lin_b, nullptr, 0);
    bgemm3s(xBhh, xBhl, e1t_h, e1t_l, NB, DBK, DM, nullptr, hBh, hBl, enc_b1, nullptr, BG_RELU);
    bgemm3s(hBh, hBl, e2t_h, e2t_l, NB, DM, DBK, xB, nullptr, nullptr, enc_b2, xB, 0);
    ln_split_kernel<<<(NB + 3) / 4, 256, 0, stream>>>(xB, lnBh, lnBl, mix_g, mix_b, NB);
    bgemm3s(lnBh, lnBl, K_wt_h, K_wt_l, NB, DM, DM, nullptr, kBh, kBl, K_b, nullptr, 0);
    bgemm3s(kBh, nullptr, T_w1t, nullptr, NB, DBK, DM, T1b, nullptr, nullptr, nullptr, nullptr, 0);
    ctx_init_kernel<<<(NB * CTX + 255) / 256, 256, 0, stream>>>(ctxAi, ctxAs);

    // ---------- candidate chunks (128-tile, 512-thread, XCD-swizzled GEMMs) ----------
    const int* pI = ctxAi; const float* pS = ctxAs;
    int* nI = ctxBi; float* nS = ctxBs;
    int nch = (NCAND + NC - 1) / NC;
    for (int c = 0; c < nch; c++) {
        int s = c * NC;
        int m = NCAND - s; if (m > NC) m = NC;
        plr_bf16_kernel<<<(m + 3) / 4, 256, 0, stream>>>(cxn + (size_t)s * NFEAT,
                                                         cxc + (size_t)s * NCAT,
                                                         m, freq, plr_w, plr_b, inCh, inCl);
        bgemm3(inCh, inCl, lin_wt_h, lin_wt_l, m, DM, KP_IN, 0, xC, xCh, xCl, lin_b, nullptr, nullptr, 0);
        bgemm3(xCh, xCl, e1t_h, e1t_l, m, DBK, DM, 0, nullptr, hCh, hCl, enc_b1, nullptr, nullptr, BG_RELU);
        bgemm3(hCh, hCl, e2t_h, e2t_l, m, DM, DBK, 0, xC, nullptr, nullptr, enc_b2, xC, nullptr, 0);
        ln_split_kernel<<<(m + 3) / 4, 256, 0, stream>>>(xC, lnCh, lnCl, mix_g, mix_b, m);
        bgemm3(lnCh, lnCl, K_wt_h, K_wt_l, m, DM, DM, 0, kC, kCh, kCl, K_b, nullptr, nullptr, 0);
        cnorm_kernel<<<(m + 3) / 4, 256, 0, stream>>>(kC, cnC, m);
        bgemm(kCh, T_w1t, m, DBK, DM, nullptr, T1c + (size_t)s * DBK, nullptr, 0);
        // scores: big data is B-side (kC, N=m) -> group M-blocks per N-tile on one XCD
        bgemm3(kBh, kBl, kCh, kCl, NB, m, DM, 1, scoresC, nullptr, nullptr,
               nullptr, nullptr, cnC, BG_SCORE);
        topk_merge_kernel<<<NB, 256, 0, stream>>>(scoresC, m, s, pI, pS, nI, nS);
        { const int* t = pI; pI = nI; nI = (int*)t; }
        { const float* t = pS; pS = nS; nS = (float*)t; }
    }

    // ---------- aggregation + predictor + head (64-tile split GEMMs) ----------
    agg_kernel<<<NB, 256, 0, stream>>>(pI, pS, cand_y, T1b, T1c, T_b1,
                                       xB, label_w, label_b, sbufh, sbufl, ubuf);
    bgemm3s(sbufh, sbufl, T_w2t_h, T_w2t_l, NB, DM, DBK, x2, nullptr, nullptr,
            nullptr, ubuf, 0);
    ln_split_kernel<<<(NB + 3) / 4, 256, 0, stream>>>(x2, h2h, h2l, pred_g, pred_b, NB);
    bgemm3s(h2h, h2l, p1t_h, p1t_l, NB, DBK, DM, nullptr, hph, hpl, pred_b1, nullptr, BG_RELU);
    bgemm3s(hph, hpl, p2t_h, p2t_l, NB, DM, DBK, x3, nullptr, nullptr, pred_b2, x2, 0);
    head_kernel<<<(NB + 3) / 4, 256, 0, stream>>>(x3, head_g, head_b, head_w, head_bias, out, NB);
}

// Round 13
// 2029.729 us; speedup vs baseline: 1.5978x; 1.0631x over previous
//
#include <hip/hip_runtime.h>

#define NCAND 50000
#define NB    512
#define DIN   820
#define KP_IN 832
#define DM    512
#define DBK   1024
#define NFEAT 50
#define NCAT  20
#define NFREQ 16
#define DEMB  16
#define CTX   96
#define NCMAX 9216
#define TOTMAX (NCMAX + CTX)

typedef __attribute__((ext_vector_type(8))) short short8;
typedef __attribute__((ext_vector_type(4))) float f32x4;

static __device__ __forceinline__ unsigned short f2bf(float f) {
    union { float f; unsigned int i; } u; u.f = f;
    unsigned int r = u.i + 0x7FFFu + ((u.i >> 16) & 1u);
    return (unsigned short)(r >> 16);
}
static __device__ __forceinline__ float bf2f(unsigned short s) {
    union { unsigned int i; float f; } u; u.i = ((unsigned int)s) << 16;
    return u.f;
}
// order-preserving float->uint key (ascending), exact bijection
static __device__ __forceinline__ unsigned int f2key(float f) {
    union { float f; unsigned int i; } u; u.f = f;
    return (u.i & 0x80000000u) ? ~u.i : (u.i | 0x80000000u);
}
static __device__ __forceinline__ float key2f(unsigned int k) {
    union { unsigned int i; float f; } u;
    u.i = (k & 0x80000000u) ? (k ^ 0x80000000u) : ~k;
    return u.f;
}

#define GLDS16(g, l) __builtin_amdgcn_global_load_lds( \
    (const __attribute__((address_space(1))) void*)(g), \
    (__attribute__((address_space(3))) void*)(l), 16, 0, 0)

#define BG_RELU  1
#define BG_SCORE 2

// XCD swizzle: blocks sharing the big-dimension tile get linear IDs congruent
// mod 8 -> same XCD under round-robin dispatch -> shared tile fetched once/XCD.
static __device__ __forceinline__ int swizzle_blk(int L, int nbx, int nby, int bigx,
                                                  int* bx, int* by)
{
    int nsm = bigx ? nby : nbx;
    int xcd = L & 7, slot = L >> 3;
    int big = xcd + 8 * (slot / nsm);
    int sml = slot % nsm;
    *bx = bigx ? big : sml;
    *by = bigx ? sml : big;
    return (*bx < nbx) && (*by < nby);
}

// ---------------------------------------------------------------- weight prep
__global__ __launch_bounds__(256) void wprep_kernel(
    const float* __restrict__ W, int K, int N, int Kp,
    unsigned short* __restrict__ Wh, unsigned short* __restrict__ Wl)
{
    int idx = blockIdx.x * 256 + threadIdx.x;
    if (idx >= N * Kp) return;
    int n = idx / Kp, k = idx % Kp;
    float v = (k < K) ? W[(size_t)k * N + n] : 0.f;
    unsigned short h = f2bf(v);
    Wh[idx] = h;
    if (Wl) Wl[idx] = f2bf(v - bf2f(h));
}

// ---------------------------------------------------------------- PLR encode (bf16 hi/lo out)
__global__ __launch_bounds__(256) void plr_bf16_kernel(
    const float* __restrict__ xn_, const float* __restrict__ xc_, int nrows,
    const float* __restrict__ freq, const float* __restrict__ plr_w,
    const float* __restrict__ plr_b,
    unsigned short* __restrict__ oh, unsigned short* __restrict__ ol)
{
    __shared__ float sW[32 * 16];
    __shared__ float sB[16];
    __shared__ float sF[NFEAT * NFREQ];
    int tid = threadIdx.x;
    for (int i = tid; i < 512; i += 256) sW[i] = plr_w[i];
    if (tid < 16) sB[tid] = plr_b[tid];
    for (int i = tid; i < NFEAT * NFREQ; i += 256) sF[i] = freq[i];
    __syncthreads();
    int wave = tid >> 6, lane = tid & 63;
    int row = blockIdx.x * 4 + wave;
    if (row >= nrows) return;
    const float* xn = xn_ + (size_t)row * NFEAT;
    const float* xc = xc_ + (size_t)row * NCAT;
    unsigned short* ph = oh + (size_t)row * KP_IN;
    unsigned short* pl = ol + (size_t)row * KP_IN;
    if (lane < NFEAT) {
        float x = xn[lane];
        float cs[NFREQ], sn[NFREQ];
        #pragma unroll
        for (int j = 0; j < NFREQ; j++) {
            float p = 6.28318530717958647692f * sF[lane * NFREQ + j] * x;
            sn[j] = __sinf(p);
            cs[j] = __cosf(p);
        }
        #pragma unroll
        for (int d = 0; d < DEMB; d++) {
            float acc = sB[d];
            #pragma unroll
            for (int j = 0; j < NFREQ; j++)
                acc = fmaf(cs[j], sW[j * DEMB + d], fmaf(sn[j], sW[(NFREQ + j) * DEMB + d], acc));
            float v = fmaxf(acc, 0.f);
            unsigned short h = f2bf(v);
            ph[lane * DEMB + d] = h;
            pl[lane * DEMB + d] = f2bf(v - bf2f(h));
        }
    }
    if (lane < NCAT) {
        float v = xc[lane];
        unsigned short h = f2bf(v);
        ph[800 + lane] = h;
        pl[800 + lane] = f2bf(v - bf2f(h));
    }
    if (lane >= NCAT && lane < 32) {
        ph[800 + lane] = 0;
        pl[800 + lane] = 0;
    }
}

// --------------- bf16 MFMA GEMM (plain 1-term), 128 tile, 512 threads, LDS dbuf
__global__ __launch_bounds__(512) void bgemm_kernel(
    const unsigned short* __restrict__ A, const unsigned short* __restrict__ Bt,
    int M, int N, int Kp, int nbx, int nby, int bigx,
    float* __restrict__ Cf, unsigned short* __restrict__ Cb,
    const float* __restrict__ bias, int flags)
{
    __shared__ unsigned short SH[2][2][128 * 32];   // 32 KB
    int bxi, byi;
    if (!swizzle_blk(blockIdx.x, nbx, nby, bigx, &bxi, &byi)) return;
    int tid = threadIdx.x;
    int w = tid >> 6, lane = tid & 63;
    int m0 = byi * 128, n0 = bxi * 128;
    int wr = (w >> 1) * 32, wc = (w & 1) * 64;

    f32x4 acc[2][4];
    #pragma unroll
    for (int i = 0; i < 2; i++)
        #pragma unroll
        for (int j = 0; j < 4; j++) acc[i][j] = (f32x4){0.f, 0.f, 0.f, 0.f};

    int arr = w & 1;
    int qrt = (w >> 1) * 32;
    int scol = (((lane & 3) - ((lane >> 3) & 3)) & 3) * 8;
    const unsigned short* gsrc = arr ? Bt : A;
    int glim = arr ? (N - 1) : (M - 1);
    int gb   = arr ? n0 : m0;
    const unsigned short* gp0 = gsrc + (size_t)min(gb + qrt + (lane >> 2),      glim) * Kp + scol;
    const unsigned short* gp1 = gsrc + (size_t)min(gb + qrt + 16 + (lane >> 2), glim) * Kp + scol;
    int lo0 = qrt * 32, lo1 = (qrt + 16) * 32;

    int fr = lane & 15, q = lane >> 4;
    int pcs = ((q + (fr >> 1)) & 3) * 8;
    int niter = Kp >> 5;

    GLDS16(gp0, &SH[0][arr][lo0]);
    GLDS16(gp1, &SH[0][arr][lo1]);

    for (int it = 0; it < niter; it++) {
        __syncthreads();                       // drains stage for buffer it&1
        int bsel = it & 1;
        if (it + 1 < niter) {
            int k1 = (it + 1) << 5;
            GLDS16(gp0 + k1, &SH[bsel ^ 1][arr][lo0]);
            GLDS16(gp1 + k1, &SH[bsel ^ 1][arr][lo1]);
        }
        const unsigned short* As = SH[bsel][0];
        const unsigned short* Bs = SH[bsel][1];
        short8 a[2], b[4];
        #pragma unroll
        for (int i = 0; i < 2; i++)
            a[i] = *(const short8*)&As[(wr + i * 16 + fr) * 32 + pcs];
        #pragma unroll
        for (int j = 0; j < 4; j++)
            b[j] = *(const short8*)&Bs[(wc + j * 16 + fr) * 32 + pcs];
        #pragma unroll
        for (int i = 0; i < 2; i++)
            #pragma unroll
            for (int j = 0; j < 4; j++)
                acc[i][j] = __builtin_amdgcn_mfma_f32_16x16x32_bf16(a[i], b[j], acc[i][j], 0, 0, 0);
    }

    int col = lane & 15, rq = (lane >> 4) * 4;
    #pragma unroll
    for (int i = 0; i < 2; i++)
        #pragma unroll
        for (int j = 0; j < 4; j++) {
            int n_g = n0 + wc + j * 16 + col;
            #pragma unroll
            for (int r = 0; r < 4; r++) {
                int m_g = m0 + wr + i * 16 + rq + r;
                if (m_g < M && n_g < N) {
                    float v = acc[i][j][r];
                    if (bias) v += bias[n_g];
                    if (flags & BG_RELU) v = fmaxf(v, 0.f);
                    if (Cf) Cf[(size_t)m_g * N + n_g] = v;
                    if (Cb) Cb[(size_t)m_g * N + n_g] = f2bf(v);
                }
            }
        }
}

// ---------- bf16 MFMA GEMM, 3-term split, 128 tile, 512 threads, LDS dbuf
__global__ __launch_bounds__(512) void bgemm3_kernel(
    const unsigned short* __restrict__ Ah, const unsigned short* __restrict__ Al,
    const unsigned short* __restrict__ Bh, const unsigned short* __restrict__ Bl,
    int M, int N, int Kp, int nbx, int nby, int bigx,
    float* __restrict__ Cf, unsigned short* __restrict__ Cbh, unsigned short* __restrict__ Cbl,
    const float* __restrict__ bias, const float* __restrict__ resf,
    const float* __restrict__ cnorm, int flags)
{
    __shared__ unsigned short SH[2][4][128 * 32];   // 64 KB
    int bxi, byi;
    if (!swizzle_blk(blockIdx.x, nbx, nby, bigx, &bxi, &byi)) return;
    int tid = threadIdx.x;
    int w = tid >> 6, lane = tid & 63;
    int m0 = byi * 128, n0 = bxi * 128;
    int wr = (w >> 1) * 32, wc = (w & 1) * 64;

    f32x4 acc[2][4];
    #pragma unroll
    for (int i = 0; i < 2; i++)
        #pragma unroll
        for (int j = 0; j < 4; j++) acc[i][j] = (f32x4){0.f, 0.f, 0.f, 0.f};

    int arr = w & 3;
    int half = (w >> 2) * 64;
    int scol = (((lane & 3) - ((lane >> 3) & 3)) & 3) * 8;
    const unsigned short* gsrc = (arr == 0) ? Ah : (arr == 1) ? Al : (arr == 2) ? Bh : Bl;
    int glim = (arr < 2) ? (M - 1) : (N - 1);
    int gb   = (arr < 2) ? m0 : n0;
    const unsigned short* gp[4];
    int lofs[4];
    #pragma unroll
    for (int t = 0; t < 4; t++) {
        int r = half + t * 16;
        gp[t] = gsrc + (size_t)min(gb + r + (lane >> 2), glim) * Kp + scol;
        lofs[t] = r * 32;
    }

    int fr = lane & 15, q = lane >> 4;
    int pcs = ((q + (fr >> 1)) & 3) * 8;
    int niter = Kp >> 5;

    #pragma unroll
    for (int t = 0; t < 4; t++) GLDS16(gp[t], &SH[0][arr][lofs[t]]);

    for (int it = 0; it < niter; it++) {
        __syncthreads();                       // drains stage for buffer it&1
        int bsel = it & 1;
        if (it + 1 < niter) {
            int k1 = (it + 1) << 5;
            #pragma unroll
            for (int t = 0; t < 4; t++) GLDS16(gp[t] + k1, &SH[bsel ^ 1][arr][lofs[t]]);
        }
        const unsigned short* Ash = SH[bsel][0];
        const unsigned short* Asl = SH[bsel][1];
        const unsigned short* Bsh = SH[bsel][2];
        const unsigned short* Bsl = SH[bsel][3];
        short8 a[2], b[4];
        #pragma unroll
        for (int i = 0; i < 2; i++)
            a[i] = *(const short8*)&Ash[(wr + i * 16 + fr) * 32 + pcs];
        #pragma unroll
        for (int j = 0; j < 4; j++)
            b[j] = *(const short8*)&Bsh[(wc + j * 16 + fr) * 32 + pcs];
        #pragma unroll
        for (int i = 0; i < 2; i++)
            #pragma unroll
            for (int j = 0; j < 4; j++)
                acc[i][j] = __builtin_amdgcn_mfma_f32_16x16x32_bf16(a[i], b[j], acc[i][j], 0, 0, 0);
        short8 al2[2];
        #pragma unroll
        for (int i = 0; i < 2; i++)
            al2[i] = *(const short8*)&Asl[(wr + i * 16 + fr) * 32 + pcs];
        #pragma unroll
        for (int i = 0; i < 2; i++)
            #pragma unroll
            for (int j = 0; j < 4; j++)
                acc[i][j] = __builtin_amdgcn_mfma_f32_16x16x32_bf16(al2[i], b[j], acc[i][j], 0, 0, 0);
        short8 bl2[4];
        #pragma unroll
        for (int j = 0; j < 4; j++)
            bl2[j] = *(const short8*)&Bsl[(wc + j * 16 + fr) * 32 + pcs];
        #pragma unroll
        for (int i = 0; i < 2; i++)
            #pragma unroll
            for (int j = 0; j < 4; j++)
                acc[i][j] = __builtin_amdgcn_mfma_f32_16x16x32_bf16(a[i], bl2[j], acc[i][j], 0, 0, 0);
    }

    int col = lane & 15, rq = (lane >> 4) * 4;
    #pragma unroll
    for (int i = 0; i < 2; i++)
        #pragma unroll
        for (int j = 0; j < 4; j++) {
            int n_g = n0 + wc + j * 16 + col;
            #pragma unroll
            for (int r = 0; r < 4; r++) {
                int m_g = m0 + wr + i * 16 + rq + r;
                if (m_g < M && n_g < N) {
                    float v = acc[i][j][r];
                    if (bias) v += bias[n_g];
                    if (resf) v += resf[(size_t)m_g * N + n_g];
                    if (flags & BG_RELU) v = fmaxf(v, 0.f);
                    if (flags & BG_SCORE) v = 2.f * v - cnorm[n_g];
                    if (Cf) Cf[(size_t)m_g * N + n_g] = v;
                    if (Cbh) {
                        unsigned short h = f2bf(v);
                        Cbh[(size_t)m_g * N + n_g] = h;
                        if (Cbl) Cbl[(size_t)m_g * N + n_g] = f2bf(v - bf2f(h));
                    }
                }
            }
        }
}

// ------------------------- small-M GEMM: 64x64 tile, 1- or 3-term (Al null => 1-term)
__global__ __launch_bounds__(256) void bgemm3s_kernel(
    const unsigned short* __restrict__ Ah, const unsigned short* __restrict__ Al,
    const unsigned short* __restrict__ Bh, const unsigned short* __restrict__ Bl,
    int M, int N, int Kp,
    float* __restrict__ Cf, unsigned short* __restrict__ Cbh, unsigned short* __restrict__ Cbl,
    const float* __restrict__ bias, const float* __restrict__ resf, int flags)
{
    __shared__ unsigned short Ash[64 * 32];
    __shared__ unsigned short Asl[64 * 32];
    __shared__ unsigned short Bsh[64 * 32];
    __shared__ unsigned short Bsl[64 * 32];
    int tid = threadIdx.x;
    int w = tid >> 6, lane = tid & 63;
    int m0 = blockIdx.y * 64, n0 = blockIdx.x * 64;
    int wr = (w >> 1) * 32, wc = (w & 1) * 32;
    int three = (Al != nullptr);

    f32x4 acc[2][2];
    #pragma unroll
    for (int i = 0; i < 2; i++)
        #pragma unroll
        for (int j = 0; j < 2; j++) acc[i][j] = (f32x4){0.f, 0.f, 0.f, 0.f};

    int srow = w * 16 + (lane >> 2);
    int scol = (((lane & 3) - ((lane >> 3) & 3)) & 3) * 8;
    size_t ra = (size_t)min(m0 + srow, M - 1) * Kp + scol;
    size_t rb = (size_t)min(n0 + srow, N - 1) * Kp + scol;
    unsigned short* lah = &Ash[(w * 16) * 32];
    unsigned short* lal = &Asl[(w * 16) * 32];
    unsigned short* lbh = &Bsh[(w * 16) * 32];
    unsigned short* lbl = &Bsl[(w * 16) * 32];

    int fr = lane & 15, q = lane >> 4;
    int pcs = ((q + (fr >> 1)) & 3) * 8;

    for (int k0 = 0; k0 < Kp; k0 += 32) {
        __syncthreads();
        GLDS16(Ah + ra + k0, lah);
        GLDS16(Bh + rb + k0, lbh);
        if (three) {
            GLDS16(Al + ra + k0, lal);
            GLDS16(Bl + rb + k0, lbl);
        }
        __syncthreads();
        short8 a[2], b[2];
        #pragma unroll
        for (int i = 0; i < 2; i++)
            a[i] = *(const short8*)&Ash[(wr + i * 16 + fr) * 32 + pcs];
        #pragma unroll
        for (int j = 0; j < 2; j++)
            b[j] = *(const short8*)&Bsh[(wc + j * 16 + fr) * 32 + pcs];
        #pragma unroll
        for (int i = 0; i < 2; i++)
            #pragma unroll
            for (int j = 0; j < 2; j++)
                acc[i][j] = __builtin_amdgcn_mfma_f32_16x16x32_bf16(a[i], b[j], acc[i][j], 0, 0, 0);
        if (three) {
            short8 al2[2], bl2[2];
            #pragma unroll
            for (int i = 0; i < 2; i++)
                al2[i] = *(const short8*)&Asl[(wr + i * 16 + fr) * 32 + pcs];
            #pragma unroll
            for (int j = 0; j < 2; j++)
                bl2[j] = *(const short8*)&Bsl[(wc + j * 16 + fr) * 32 + pcs];
            #pragma unroll
            for (int i = 0; i < 2; i++)
                #pragma unroll
                for (int j = 0; j < 2; j++) {
                    acc[i][j] = __builtin_amdgcn_mfma_f32_16x16x32_bf16(al2[i], b[j], acc[i][j], 0, 0, 0);
                    acc[i][j] = __builtin_amdgcn_mfma_f32_16x16x32_bf16(a[i], bl2[j], acc[i][j], 0, 0, 0);
                }
        }
    }

    int col = lane & 15, rq = (lane >> 4) * 4;
    #pragma unroll
    for (int i = 0; i < 2; i++)
        #pragma unroll
        for (int j = 0; j < 2; j++) {
            int n_g = n0 + wc + j * 16 + col;
            #pragma unroll
            for (int r = 0; r < 4; r++) {
                int m_g = m0 + wr + i * 16 + rq + r;
                if (m_g < M && n_g < N) {
                    float v = acc[i][j][r];
                    if (bias) v += bias[n_g];
                    if (resf) v += resf[(size_t)m_g * N + n_g];
                    if (flags & BG_RELU) v = fmaxf(v, 0.f);
                    if (Cf) Cf[(size_t)m_g * N + n_g] = v;
                    if (Cbh) {
                        unsigned short h = f2bf(v);
                        Cbh[(size_t)m_g * N + n_g] = h;
                        if (Cbl) Cbl[(size_t)m_g * N + n_g] = f2bf(v - bf2f(h));
                    }
                }
            }
        }
}

// ---------------------------------------------------------------- LayerNorm bf16 hi/lo out
__global__ __launch_bounds__(256) void ln_split_kernel(const float* __restrict__ X,
    unsigned short* __restrict__ Yh, unsigned short* __restrict__ Yl,
    const float* __restrict__ g, const float* __restrict__ bt, int M)
{
    int wave = threadIdx.x >> 6, lane = threadIdx.x & 63;
    int row = blockIdx.x * 4 + wave;
    if (row >= M) return;
    const float* x = X + (size_t)row * DM;
    float4 v0 = ((const float4*)x)[lane * 2];
    float4 v1 = ((const float4*)x)[lane * 2 + 1];
    float s = v0.x + v0.y + v0.z + v0.w + v1.x + v1.y + v1.z + v1.w;
    #pragma unroll
    for (int off = 32; off; off >>= 1) s += __shfl_xor(s, off, 64);
    float m = s * (1.f / DM);
    float q = (v0.x - m) * (v0.x - m) + (v0.y - m) * (v0.y - m)
            + (v0.z - m) * (v0.z - m) + (v0.w - m) * (v0.w - m)
            + (v1.x - m) * (v1.x - m) + (v1.y - m) * (v1.y - m)
            + (v1.z - m) * (v1.z - m) + (v1.w - m) * (v1.w - m);
    #pragma unroll
    for (int off = 32; off; off >>= 1) q += __shfl_xor(q, off, 64);
    float rstd = 1.f / sqrtf(q * (1.f / DM) + 1e-5f);
    float vals[8] = {v0.x, v0.y, v0.z, v0.w, v1.x, v1.y, v1.z, v1.w};
    unsigned short* yh = Yh + (size_t)row * DM + lane * 8;
    unsigned short* yl = Yl + (size_t)row * DM + lane * 8;
    const float* gp = g + lane * 8;
    const float* bp = bt + lane * 8;
    #pragma unroll
    for (int i = 0; i < 8; i++) {
        float y = (vals[i] - m) * rstd * gp[i] + bp[i];
        unsigned short h = f2bf(y);
        yh[i] = h;
        yl[i] = f2bf(y - bf2f(h));
    }
}

// ---------------------------------------------------------------- key norms (fp32 k)
__global__ __launch_bounds__(256) void cnorm_kernel(const float* __restrict__ Kc,
    float* __restrict__ cn, int N)
{
    int wave = threadIdx.x >> 6, lane = threadIdx.x & 63;
    int row = blockIdx.x * 4 + wave;
    if (row >= N) return;
    const float* x = Kc + (size_t)row * DM;
    float4 v0 = ((const float4*)x)[lane * 2];
    float4 v1 = ((const float4*)x)[lane * 2 + 1];
    float s = v0.x * v0.x + v0.y * v0.y + v0.z * v0.z + v0.w * v0.w
            + v1.x * v1.x + v1.y * v1.y + v1.z * v1.z + v1.w * v1.w;
    #pragma unroll
    for (int off = 32; off; off >>= 1) s += __shfl_xor(s, off, 64);
    if (lane == 0) cn[row] = s;
}

// ---------------------------------------------------------------- ctx init
__global__ void ctx_init_kernel(int* __restrict__ idx, float* __restrict__ sc)
{
    int i = blockIdx.x * 256 + threadIdx.x;
    if (i < NB * CTX) { idx[i] = 0; sc[i] = -1e30f; }
}

// ------------------------------------- running top-96 merge: exact radix select
#define CANDCAP 2048
__global__ __launch_bounds__(256) void topk_merge_kernel(
    const float* __restrict__ S, int m, int base,
    const int* __restrict__ pidx, const float* __restrict__ pscore,
    int* __restrict__ nidx, float* __restrict__ nscore)
{
    __shared__ __align__(16) unsigned int ks[TOTMAX];
    __shared__ unsigned int hist[4 * 256];
    __shared__ unsigned int sfx[256];
    __shared__ unsigned int s_prefix;
    __shared__ int s_above;
    __shared__ int prev_i[CTX];
    __shared__ int nsel, neq;
    __shared__ float sel_s[CTX];
    __shared__ int   sel_g[CTX];
    __shared__ int   cnd_g[CANDCAP];

    int b = blockIdx.x, tid = threadIdx.x;
    int lane = tid & 63, wv = tid >> 6;
    const float* Sb = S + (size_t)b * m;
    int tot = m + CTX;

    int m4 = m >> 2;
    const float4* S4 = (const float4*)Sb;
    for (int i = tid; i < m4; i += 256) {
        float4 v = S4[i];
        uint4 kk;
        kk.x = f2key(v.x); kk.y = f2key(v.y); kk.z = f2key(v.z); kk.w = f2key(v.w);
        ((uint4*)ks)[i] = kk;
    }
    for (int i = (m4 << 2) + tid; i < m; i += 256) ks[i] = f2key(Sb[i]);
    if (tid < CTX) {
        ks[m + tid] = f2key(pscore[b * CTX + tid]);
        prev_i[tid] = pidx[b * CTX + tid];
    }
    if (tid == 0) { s_prefix = 0u; s_above = 0; nsel = 0; neq = 0; }
    __syncthreads();

    unsigned int* myhist = &hist[wv * 256];

    for (int pass = 0; pass < 4; pass++) {
        int shift = 24 - pass * 8;
        for (int i = tid; i < 1024; i += 256) hist[i] = 0;
        __syncthreads();
        unsigned int pref = s_prefix;
        unsigned int msk = (pass == 0) ? 0u : (0xFFFFFFFFu << (32 - 8 * pass));
        for (int i0 = 0; i0 < tot; i0 += 256) {
            int i = i0 + tid;
            int pred = 0, digit = 0;
            if (i < tot) {
                unsigned int k = ks[i];
                pred = ((k & msk) == pref);
                digit = (int)((k >> shift) & 255u);
            }
            unsigned long long act = __ballot(pred);
            if (!act) continue;
            int lead = (int)__ffsll(act) - 1;
            int d0 = __shfl(digit, lead, 64);
            unsigned long long same = __ballot(pred && (digit == d0));
            if (same == act) {
                if (lane == lead) atomicAdd(&myhist[d0], (unsigned int)__popcll(act));
            } else {
                if (pred) atomicAdd(&myhist[digit], 1u);
            }
        }
        __syncthreads();
        unsigned int hb = hist[tid] + hist[256 + tid] + hist[512 + tid] + hist[768 + tid];
        __syncthreads();
        hist[tid] = hb;
        sfx[tid] = hb;
        __syncthreads();
        #pragma unroll
        for (int offd = 1; offd < 256; offd <<= 1) {
            unsigned int v = (tid + offd < 256) ? sfx[tid + offd] : 0u;
            __syncthreads();
            sfx[tid] += v;
            __syncthreads();
        }
        {
            int incl = s_above + (int)sfx[tid];
            int excl = incl - (int)hb;
            if (excl < CTX && incl >= CTX) {
                s_prefix = pref | ((unsigned int)tid << shift);
                s_above = excl;
            }
        }
        __syncthreads();
    }
    unsigned int thrK = s_prefix;
    int msel = CTX - s_above;
    float eqv = key2f(thrK);

    for (int i = tid; i < tot; i += 256) {
        unsigned int k = ks[i];
        if (k < thrK) continue;
        int g = (i < m) ? (base + i) : prev_i[i - m];
        if (k > thrK) {
            int p = atomicAdd(&nsel, 1);
            sel_s[p] = key2f(k); sel_g[p] = g;
        } else {
            int p = atomicAdd(&neq, 1);
            if (p < CANDCAP) cnd_g[p] = g;
        }
    }
    __syncthreads();
    int ne = neq;
    if (ne <= CANDCAP) {
        for (int i = tid; i < ne; i += 256) {
            int gi = cnd_g[i];
            int rank = 0;
            for (int j = 0; j < ne; j++) rank += (cnd_g[j] < gi);
            if (rank < msel) {
                int p = atomicAdd(&nsel, 1);
                sel_s[p] = eqv; sel_g[p] = gi;
            }
        }
    } else {
        for (int i = tid; i < tot; i += 256) {
            if (ks[i] != thrK) continue;
            int g = (i < m) ? (base + i) : prev_i[i - m];
            int rank = 0;
            for (int j = 0; j < tot; j++) {
                if (ks[j] == thrK) {
                    int gj = (j < m) ? (base + j) : prev_i[j - m];
                    rank += (gj < g);
                }
            }
            if (rank < msel) {
                int p = atomicAdd(&nsel, 1);
                sel_s[p] = eqv; sel_g[p] = g;
            }
        }
    }
    __syncthreads();
    if (tid < CTX) {
        nidx[b * CTX + tid] = sel_g[tid];
        nscore[b * CTX + tid] = sel_s[tid];
    }
}

// ------------------------------- softmax + label/value context aggregation
__global__ __launch_bounds__(256) void agg_kernel(
    const int* __restrict__ ctx_idx, const float* __restrict__ ctx_score,
    const float* __restrict__ cand_y, const float* __restrict__ T1b,
    const unsigned short* __restrict__ T1c, const float* __restrict__ T_b1,
    const float* __restrict__ x_batch,
    const float* __restrict__ label_w, const float* __restrict__ label_b,
    unsigned short* __restrict__ s_h, unsigned short* __restrict__ s_l,
    float* __restrict__ u_out)
{
    __shared__ float p_s[CTX];
    __shared__ int   p_i[CTX];
    __shared__ float s_ybar;
    int b = blockIdx.x, tid = threadIdx.x;
    if (tid < CTX) { p_s[tid] = ctx_score[b * CTX + tid]; p_i[tid] = ctx_idx[b * CTX + tid]; }
    __syncthreads();
    if (tid == 0) {
        float mx = -1e30f;
        for (int c = 0; c < CTX; c++) mx = fmaxf(mx, p_s[c]);
        float sum = 0.f;
        for (int c = 0; c < CTX; c++) { float e = __expf(p_s[c] - mx); p_s[c] = e; sum += e; }
        float inv = 1.f / sum, yb = 0.f;
        for (int c = 0; c < CTX; c++) { p_s[c] *= inv; yb += p_s[c] * cand_y[p_i[c]]; }
        s_ybar = yb;
    }
    __syncthreads();
    int j = tid * 4;
    float4 kv = *(const float4*)(T1b + (size_t)b * DBK + j);
    float4 tb = *(const float4*)(T_b1 + j);
    float base0 = kv.x + tb.x, base1 = kv.y + tb.y, base2 = kv.z + tb.z, base3 = kv.w + tb.w;
    float a0 = 0.f, a1 = 0.f, a2 = 0.f, a3 = 0.f;
    for (int c = 0; c < CTX; c++) {
        float p = p_s[c];
        ushort4 cu = *(const ushort4*)(T1c + (size_t)p_i[c] * DBK + j);
        a0 = fmaf(p, fmaxf(base0 - bf2f(cu.x), 0.f), a0);
        a1 = fmaf(p, fmaxf(base1 - bf2f(cu.y), 0.f), a1);
        a2 = fmaf(p, fmaxf(base2 - bf2f(cu.z), 0.f), a2);
        a3 = fmaf(p, fmaxf(base3 - bf2f(cu.w), 0.f), a3);
    }
    {
        ushort4 oh, ol;
        oh.x = f2bf(a0); ol.x = f2bf(a0 - bf2f(oh.x));
        oh.y = f2bf(a1); ol.y = f2bf(a1 - bf2f(oh.y));
        oh.z = f2bf(a2); ol.z = f2bf(a2 - bf2f(oh.z));
        oh.w = f2bf(a3); ol.w = f2bf(a3 - bf2f(oh.w));
        *(ushort4*)(s_h + (size_t)b * DBK + j) = oh;
        *(ushort4*)(s_l + (size_t)b * DBK + j) = ol;
    }
    if (tid < 128) {
        int d = tid * 4;
        float4 xv = *(const float4*)(x_batch + (size_t)b * DM + d);
        float4 lw = *(const float4*)(label_w + d);
        float4 lb = *(const float4*)(label_b + d);
        float yb = s_ybar;
        *(float4*)(u_out + (size_t)b * DM + d) =
            make_float4(xv.x + yb * lw.x + lb.x, xv.y + yb * lw.y + lb.y,
                        xv.z + yb * lw.z + lb.z, xv.w + yb * lw.w + lb.w);
    }
}

// ---------------------------------------------------------------- head
__global__ __launch_bounds__(256) void head_kernel(
    const float* __restrict__ X, const float* __restrict__ g,
    const float* __restrict__ bt, const float* __restrict__ w,
    const float* __restrict__ hb, float* __restrict__ out, int M)
{
    int wave = threadIdx.x >> 6, lane = threadIdx.x & 63;
    int row = blockIdx.x * 4 + wave;
    if (row >= M) return;
    const float* x = X + (size_t)row * DM;
    float4 v0 = ((const float4*)x)[lane * 2];
    float4 v1 = ((const float4*)x)[lane * 2 + 1];
    float s = v0.x + v0.y + v0.z + v0.w + v1.x + v1.y + v1.z + v1.w;
    #pragma unroll
    for (int off = 32; off; off >>= 1) s += __shfl_xor(s, off, 64);
    float m = s * (1.f / DM);
    float q = (v0.x - m) * (v0.x - m) + (v0.y - m) * (v0.y - m)
            + (v0.z - m) * (v0.z - m) + (v0.w - m) * (v0.w - m)
            + (v1.x - m) * (v1.x - m) + (v1.y - m) * (v1.y - m)
            + (v1.z - m) * (v1.z - m) + (v1.w - m) * (v1.w - m);
    #pragma unroll
    for (int off = 32; off; off >>= 1) q += __shfl_xor(q, off, 64);
    float rstd = 1.f / sqrtf(q * (1.f / DM) + 1e-5f);
    float4 g0 = ((const float4*)g)[lane * 2], g1 = ((const float4*)g)[lane * 2 + 1];
    float4 b0 = ((const float4*)bt)[lane * 2], b1 = ((const float4*)bt)[lane * 2 + 1];
    float4 w0 = ((const float4*)w)[lane * 2], w1 = ((const float4*)w)[lane * 2 + 1];
    float t = 0.f;
    t += fmaxf((v0.x - m) * rstd * g0.x + b0.x, 0.f) * w0.x;
    t += fmaxf((v0.y - m) * rstd * g0.y + b0.y, 0.f) * w0.y;
    t += fmaxf((v0.z - m) * rstd * g0.z + b0.z, 0.f) * w0.z;
    t += fmaxf((v0.w - m) * rstd * g0.w + b0.w, 0.f) * w0.w;
    t += fmaxf((v1.x - m) * rstd * g1.x + b1.x, 0.f) * w1.x;
    t += fmaxf((v1.y - m) * rstd * g1.y + b1.y, 0.f) * w1.y;
    t += fmaxf((v1.z - m) * rstd * g1.z + b1.z, 0.f) * w1.z;
    t += fmaxf((v1.w - m) * rstd * g1.w + b1.w, 0.f) * w1.w;
    #pragma unroll
    for (int off = 32; off; off >>= 1) t += __shfl_xor(t, off, 64);
    if (lane == 0) out[row] = t + hb[0];
}

// =================================================================== host
extern "C" void kernel_launch(void* const* d_in, const int* in_sizes, int n_in,
                              void* d_out, int out_size, void* d_ws, size_t ws_size,
                              hipStream_t stream) {
    (void)in_sizes; (void)n_in; (void)out_size;
    const float* x_num   = (const float*)d_in[0];
    const float* x_cat   = (const float*)d_in[1];
    const float* cxn     = (const float*)d_in[2];
    const float* cxc     = (const float*)d_in[3];
    const float* cand_y  = (const float*)d_in[4];
    const float* freq    = (const float*)d_in[6];
    const float* plr_w   = (const float*)d_in[7];
    const float* plr_b   = (const float*)d_in[8];
    const float* lin_w   = (const float*)d_in[9];
    const float* lin_b   = (const float*)d_in[10];
    const float* enc_w1  = (const float*)d_in[11];
    const float* enc_b1  = (const float*)d_in[12];
    const float* enc_w2  = (const float*)d_in[13];
    const float* enc_b2  = (const float*)d_in[14];
    const float* mix_g   = (const float*)d_in[15];
    const float* mix_b   = (const float*)d_in[16];
    const float* K_w     = (const float*)d_in[17];
    const float* K_b     = (const float*)d_in[18];
    const float* label_w = (const float*)d_in[19];
    const float* label_b = (const float*)d_in[20];
    const float* T_w1    = (const float*)d_in[21];
    const float* T_b1    = (const float*)d_in[22];
    const float* T_w2    = (const float*)d_in[23];
    const float* pred_g  = (const float*)d_in[24];
    const float* pred_b  = (const float*)d_in[25];
    const float* pred_w1 = (const float*)d_in[26];
    const float* pred_b1 = (const float*)d_in[27];
    const float* pred_w2 = (const float*)d_in[28];
    const float* pred_b2 = (const float*)d_in[29];
    const float* head_g  = (const float*)d_in[30];
    const float* head_b  = (const float*)d_in[31];
    const float* head_w  = (const float*)d_in[32];
    const float* head_bias = (const float*)d_in[33];
    float* out = (float*)d_out;

    char* ws = (char*)d_ws;
    size_t off = 0;
    auto alloc = [&](size_t n) { char* p = ws + off; off = (off + n + 255) & ~(size_t)255; return p; };

    typedef unsigned short u16;
    u16* lin_wt_h = (u16*)alloc((size_t)DM * KP_IN * 2);
    u16* lin_wt_l = (u16*)alloc((size_t)DM * KP_IN * 2);
    u16* e1t_h    = (u16*)alloc((size_t)DBK * DM * 2);
    u16* e1t_l    = (u16*)alloc((size_t)DBK * DM * 2);
    u16* e2t_h    = (u16*)alloc((size_t)DM * DBK * 2);
    u16* e2t_l    = (u16*)alloc((size_t)DM * DBK * 2);
    u16* K_wt_h   = (u16*)alloc((size_t)DM * DM * 2);
    u16* K_wt_l   = (u16*)alloc((size_t)DM * DM * 2);
    u16* T_w1t    = (u16*)alloc((size_t)DBK * DM * 2);
    u16* T_w2t_h  = (u16*)alloc((size_t)DM * DBK * 2);
    u16* T_w2t_l  = (u16*)alloc((size_t)DM * DBK * 2);
    u16* p1t_h    = (u16*)alloc((size_t)DBK * DM * 2);
    u16* p1t_l    = (u16*)alloc((size_t)DBK * DM * 2);
    u16* p2t_h    = (u16*)alloc((size_t)DM * DBK * 2);
    u16* p2t_l    = (u16*)alloc((size_t)DM * DBK * 2);
    u16*   T1c  = (u16*)alloc((size_t)NCAND * DBK * 2);
    float* T1b  = (float*)alloc((size_t)NB * DBK * 4);
    float* xB   = (float*)alloc((size_t)NB * DM * 4);
    u16*   kBh  = (u16*)alloc((size_t)NB * DM * 2);
    u16*   kBl  = (u16*)alloc((size_t)NB * DM * 2);
    u16* binh = (u16*)alloc((size_t)NB * KP_IN * 2);
    u16* binl = (u16*)alloc((size_t)NB * KP_IN * 2);
    u16* xBhh = (u16*)alloc((size_t)NB * DM * 2);
    u16* xBhl = (u16*)alloc((size_t)NB * DM * 2);
    u16* hBh  = (u16*)alloc((size_t)NB * DBK * 2);
    u16* hBl  = (u16*)alloc((size_t)NB * DBK * 2);
    u16* lnBh = (u16*)alloc((size_t)NB * DM * 2);
    u16* lnBl = (u16*)alloc((size_t)NB * DM * 2);
    int*   ctxAi = (int*)alloc((size_t)NB * CTX * 4);
    float* ctxAs = (float*)alloc((size_t)NB * CTX * 4);
    int*   ctxBi = (int*)alloc((size_t)NB * CTX * 4);
    float* ctxBs = (float*)alloc((size_t)NB * CTX * 4);
    u16*   sbufh = (u16*)alloc((size_t)NB * DBK * 2);
    u16*   sbufl = (u16*)alloc((size_t)NB * DBK * 2);
    float* ubuf  = (float*)alloc((size_t)NB * DM * 4);
    float* x2    = (float*)alloc((size_t)NB * DM * 4);
    u16*   h2h   = (u16*)alloc((size_t)NB * DM * 2);
    u16*   h2l   = (u16*)alloc((size_t)NB * DM * 2);
    u16*   hph   = (u16*)alloc((size_t)NB * DBK * 2);
    u16*   hpl   = (u16*)alloc((size_t)NB * DBK * 2);
    float* x3    = (float*)alloc((size_t)NB * DM * 4);

    size_t remain = (ws_size > off + 8192) ? (ws_size - off - 8192) : 0;
    const size_t perrow = 3328 + 2048 + 2048 + 4096 + 64;
    long ncl = (long)(remain / perrow);
    int NC = (int)(ncl > NCMAX ? NCMAX : ncl);
    NC &= ~127;
    if (NC < 256) NC = 256;
    char* arenaA = alloc((size_t)NC * 3328);
    char* arenaB = alloc((size_t)NC * 2048);
    char* arenaC = alloc((size_t)NC * 2048);
    char* arenaD = alloc((size_t)NC * 4096);
    u16* inCh = (u16*)arenaA;
    u16* inCl = inCh + (size_t)NC * KP_IN;
    float* kC  = (float*)arenaA;
    float* cnC = (float*)(arenaA + (size_t)NC * 2048);
    float* xC  = (float*)arenaB;
    float* scoresC = (float*)arenaB;
    u16* xCh  = (u16*)arenaC;
    u16* xCl  = xCh + (size_t)NC * DM;
    u16* lnCh = (u16*)arenaC;
    u16* lnCl = lnCh + (size_t)NC * DM;
    u16* hCh  = (u16*)arenaD;
    u16* hCl  = hCh + (size_t)NC * DBK;
    u16* kCh  = (u16*)arenaD;
    u16* kCl  = kCh + (size_t)NC * DM;

    auto bgemm = [&](const u16* A, const u16* Bt, int M, int N, int Kp,
                     float* Cf, u16* Cb, const float* bias, int flags) {
        int nbx = (N + 127) / 128, nby = (M + 127) / 128;
        int npad = (nby + 7) & ~7;
        bgemm_kernel<<<npad * nbx, 512, 0, stream>>>(A, Bt, M, N, Kp, nbx, nby, 0,
                                                     Cf, Cb, bias, flags);
    };
    auto bgemm3 = [&](const u16* Ah, const u16* Al, const u16* Bh, const u16* Bl,
                      int M, int N, int Kp, int bigx, float* Cf, u16* Cbh, u16* Cbl,
                      const float* bias, const float* resf, const float* cnorm, int flags) {
        int nbx = (N + 127) / 128, nby = (M + 127) / 128;
        int nbig = bigx ? nbx : nby, nsm = bigx ? nby : nbx;
        int npad = (nbig + 7) & ~7;
        bgemm3_kernel<<<npad * nsm, 512, 0, stream>>>(Ah, Al, Bh, Bl, M, N, Kp,
                                                      nbx, nby, bigx,
                                                      Cf, Cbh, Cbl, bias, resf, cnorm, flags);
    };
    auto bgemm3s = [&](const u16* Ah, const u16* Al, const u16* Bh, const u16* Bl,
                       int M, int N, int Kp, float* Cf, u16* Cbh, u16* Cbl,
                       const float* bias, const float* resf, int flags) {
        dim3 grid((N + 63) / 64, (M + 63) / 64);
        bgemm3s_kernel<<<grid, 256, 0, stream>>>(Ah, Al, Bh, Bl, M, N, Kp,
                                                 Cf, Cbh, Cbl, bias, resf, flags);
    };
    auto wprep = [&](const float* W, int K, int N, int Kp, u16* Wh, u16* Wl) {
        int n = N * Kp;
        wprep_kernel<<<(n + 255) / 256, 256, 0, stream>>>(W, K, N, Kp, Wh, Wl);
    };

    // ---------- weight prep ----------
    wprep(lin_w, DIN, DM, KP_IN, lin_wt_h, lin_wt_l);
    wprep(enc_w1, DM, DBK, DM, e1t_h, e1t_l);
    wprep(enc_w2, DBK, DM, DBK, e2t_h, e2t_l);
    wprep(K_w, DM, DM, DM, K_wt_h, K_wt_l);
    wprep(T_w1, DM, DBK, DM, T_w1t, nullptr);
    wprep(T_w2, DBK, DM, DBK, T_w2t_h, T_w2t_l);
    wprep(pred_w1, DM, DBK, DM, p1t_h, p1t_l);
    wprep(pred_w2, DBK, DM, DBK, p2t_h, p2t_l);

    // ---------- batch encode (64-tile split GEMMs) ----------
    plr_bf16_kernel<<<(NB + 3) / 4, 256, 0, stream>>>(x_num, x_cat, NB, freq, plr_w, plr_b, binh, binl);
    bgemm3s(binh, binl, lin_wt_h, lin_wt_l, NB, DM, KP_IN, xB, xBhh, xBhl, lin_b, nullptr, 0);
    bgemm3s(xBhh, xBhl, e1t_h, e1t_l, NB, DBK, DM, nullptr, hBh, hBl, enc_b1, nullptr, BG_RELU);
    bgemm3s(hBh, hBl, e2t_h, e2t_l, NB, DM, DBK, xB, nullptr, nullptr, enc_b2, xB, 0);
    ln_split_kernel<<<(NB + 3) / 4, 256, 0, stream>>>(xB, lnBh, lnBl, mix_g, mix_b, NB);
    bgemm3s(lnBh, lnBl, K_wt_h, K_wt_l, NB, DM, DM, nullptr, kBh, kBl, K_b, nullptr, 0);
    bgemm3s(kBh, nullptr, T_w1t, nullptr, NB, DBK, DM, T1b, nullptr, nullptr, nullptr, nullptr, 0);
    ctx_init_kernel<<<(NB * CTX + 255) / 256, 256, 0, stream>>>(ctxAi, ctxAs);

    // ---------- candidate chunks (128-tile, 512-thread, swizzled, dbuf GEMMs) ----------
    const int* pI = ctxAi; const float* pS = ctxAs;
    int* nI = ctxBi; float* nS = ctxBs;
    int nch = (NCAND + NC - 1) / NC;
    for (int c = 0; c < nch; c++) {
        int s = c * NC;
        int m = NCAND - s; if (m > NC) m = NC;
        plr_bf16_kernel<<<(m + 3) / 4, 256, 0, stream>>>(cxn + (size_t)s * NFEAT,
                                                         cxc + (size_t)s * NCAT,
                                                         m, freq, plr_w, plr_b, inCh, inCl);
        bgemm3(inCh, inCl, lin_wt_h, lin_wt_l, m, DM, KP_IN, 0, xC, xCh, xCl, lin_b, nullptr, nullptr, 0);
        bgemm3(xCh, xCl, e1t_h, e1t_l, m, DBK, DM, 0, nullptr, hCh, hCl, enc_b1, nullptr, nullptr, BG_RELU);
        bgemm3(hCh, hCl, e2t_h, e2t_l, m, DM, DBK, 0, xC, nullptr, nullptr, enc_b2, xC, nullptr, 0);
        ln_split_kernel<<<(m + 3) / 4, 256, 0, stream>>>(xC, lnCh, lnCl, mix_g, mix_b, m);
        bgemm3(lnCh, lnCl, K_wt_h, K_wt_l, m, DM, DM, 0, kC, kCh, kCl, K_b, nullptr, nullptr, 0);
        cnorm_kernel<<<(m + 3) / 4, 256, 0, stream>>>(kC, cnC, m);
        bgemm(kCh, T_w1t, m, DBK, DM, nullptr, T1c + (size_t)s * DBK, nullptr, 0);
        bgemm3(kBh, kBl, kCh, kCl, NB, m, DM, 1, scoresC, nullptr, nullptr,
               nullptr, nullptr, cnC, BG_SCORE);
        topk_merge_kernel<<<NB, 256, 0, stream>>>(scoresC, m, s, pI, pS, nI, nS);
        { const int* t = pI; pI = nI; nI = (int*)t; }
        { const float* t = pS; pS = nS; nS = (float*)t; }
    }

    // ---------- aggregation + predictor + head (64-tile split GEMMs) ----------
    agg_kernel<<<NB, 256, 0, stream>>>(pI, pS, cand_y, T1b, T1c, T_b1,
                                       xB, label_w, label_b, sbufh, sbufl, ubuf);
    bgemm3s(sbufh, sbufl, T_w2t_h, T_w2t_l, NB, DM, DBK, x2, nullptr, nullptr,
            nullptr, ubuf, 0);
    ln_split_kernel<<<(NB + 3) / 4, 256, 0, stream>>>(x2, h2h, h2l, pred_g, pred_b, NB);
    bgemm3s(h2h, h2l, p1t_h, p1t_l, NB, DBK, DM, nullptr, hph, hpl, pred_b1, nullptr, BG_RELU);
    bgemm3s(hph, hpl, p2t_h, p2t_l, NB, DM, DBK, x3, nullptr, nullptr, pred_b2, x2, 0);
    head_kernel<<<(NB + 3) / 4, 256, 0, stream>>>(x3, head_g, head_b, head_w, head_bias, out, NB);
}

// Round 14
// 1716.254 us; speedup vs baseline: 1.8896x; 1.1827x over previous
//
#include <hip/hip_runtime.h>

#define NCAND 50000
#define NB    512
#define DIN   820
#define KP_IN 832
#define DM    512
#define DBK   1024
#define NFEAT 50
#define NCAT  20
#define NFREQ 16
#define DEMB  16
#define CTX   96
#define NCMAX 15872
#define TOTMAX (NCMAX + CTX)

typedef __attribute__((ext_vector_type(8))) short short8;
typedef __attribute__((ext_vector_type(4))) float f32x4;

static __device__ __forceinline__ unsigned short f2bf(float f) {
    union { float f; unsigned int i; } u; u.f = f;
    unsigned int r = u.i + 0x7FFFu + ((u.i >> 16) & 1u);
    return (unsigned short)(r >> 16);
}
static __device__ __forceinline__ float bf2f(unsigned short s) {
    union { unsigned int i; float f; } u; u.i = ((unsigned int)s) << 16;
    return u.f;
}
// order-preserving float->uint key (ascending), exact bijection
static __device__ __forceinline__ unsigned int f2key(float f) {
    union { float f; unsigned int i; } u; u.f = f;
    return (u.i & 0x80000000u) ? ~u.i : (u.i | 0x80000000u);
}
static __device__ __forceinline__ float key2f(unsigned int k) {
    union { unsigned int i; float f; } u;
    u.i = (k & 0x80000000u) ? (k ^ 0x80000000u) : ~k;
    return u.f;
}

#define GLDS16(g, l) __builtin_amdgcn_global_load_lds( \
    (const __attribute__((address_space(1))) void*)(g), \
    (__attribute__((address_space(3))) void*)(l), 16, 0, 0)

#define BG_RELU  1
#define BG_SCORE 2

// XCD swizzle: blocks sharing the big-dimension tile get linear IDs congruent
// mod 8 -> same XCD under round-robin dispatch -> shared tile fetched once/XCD.
static __device__ __forceinline__ int swizzle_blk(int L, int nbx, int nby, int bigx,
                                                  int* bx, int* by)
{
    int nsm = bigx ? nby : nbx;
    int xcd = L & 7, slot = L >> 3;
    int big = xcd + 8 * (slot / nsm);
    int sml = slot % nsm;
    *bx = bigx ? big : sml;
    *by = bigx ? sml : big;
    return (*bx < nbx) && (*by < nby);
}

// ---------------------------------------------------------------- weight prep
__global__ __launch_bounds__(256) void wprep_kernel(
    const float* __restrict__ W, int K, int N, int Kp,
    unsigned short* __restrict__ Wh, unsigned short* __restrict__ Wl)
{
    int idx = blockIdx.x * 256 + threadIdx.x;
    if (idx >= N * Kp) return;
    int n = idx / Kp, k = idx % Kp;
    float v = (k < K) ? W[(size_t)k * N + n] : 0.f;
    unsigned short h = f2bf(v);
    Wh[idx] = h;
    if (Wl) Wl[idx] = f2bf(v - bf2f(h));
}

// ---------------------------------------------------------------- PLR encode (bf16 hi/lo out)
__global__ __launch_bounds__(256) void plr_bf16_kernel(
    const float* __restrict__ xn_, const float* __restrict__ xc_, int nrows,
    const float* __restrict__ freq, const float* __restrict__ plr_w,
    const float* __restrict__ plr_b,
    unsigned short* __restrict__ oh, unsigned short* __restrict__ ol)
{
    __shared__ float sW[32 * 16];
    __shared__ float sB[16];
    __shared__ float sF[NFEAT * NFREQ];
    int tid = threadIdx.x;
    for (int i = tid; i < 512; i += 256) sW[i] = plr_w[i];
    if (tid < 16) sB[tid] = plr_b[tid];
    for (int i = tid; i < NFEAT * NFREQ; i += 256) sF[i] = freq[i];
    __syncthreads();
    int wave = tid >> 6, lane = tid & 63;
    int row = blockIdx.x * 4 + wave;
    if (row >= nrows) return;
    const float* xn = xn_ + (size_t)row * NFEAT;
    const float* xc = xc_ + (size_t)row * NCAT;
    unsigned short* ph = oh + (size_t)row * KP_IN;
    unsigned short* pl = ol + (size_t)row * KP_IN;
    if (lane < NFEAT) {
        float x = xn[lane];
        float cs[NFREQ], sn[NFREQ];
        #pragma unroll
        for (int j = 0; j < NFREQ; j++) {
            float p = 6.28318530717958647692f * sF[lane * NFREQ + j] * x;
            sn[j] = __sinf(p);
            cs[j] = __cosf(p);
        }
        #pragma unroll
        for (int d = 0; d < DEMB; d++) {
            float acc = sB[d];
            #pragma unroll
            for (int j = 0; j < NFREQ; j++)
                acc = fmaf(cs[j], sW[j * DEMB + d], fmaf(sn[j], sW[(NFREQ + j) * DEMB + d], acc));
            float v = fmaxf(acc, 0.f);
            unsigned short h = f2bf(v);
            ph[lane * DEMB + d] = h;
            pl[lane * DEMB + d] = f2bf(v - bf2f(h));
        }
    }
    if (lane < NCAT) {
        float v = xc[lane];
        unsigned short h = f2bf(v);
        ph[800 + lane] = h;
        pl[800 + lane] = f2bf(v - bf2f(h));
    }
    if (lane >= NCAT && lane < 32) {
        ph[800 + lane] = 0;
        pl[800 + lane] = 0;
    }
}

// --------------- bf16 MFMA GEMM (plain 1-term), 128 tile, 512 threads, LDS dbuf
__global__ __launch_bounds__(512) void bgemm_kernel(
    const unsigned short* __restrict__ A, const unsigned short* __restrict__ Bt,
    int M, int N, int Kp, int nbx, int nby, int bigx,
    float* __restrict__ Cf, unsigned short* __restrict__ Cb,
    const float* __restrict__ bias, int flags)
{
    __shared__ unsigned short SH[2][2][128 * 32];   // 32 KB
    int bxi, byi;
    if (!swizzle_blk(blockIdx.x, nbx, nby, bigx, &bxi, &byi)) return;
    int tid = threadIdx.x;
    int w = tid >> 6, lane = tid & 63;
    int m0 = byi * 128, n0 = bxi * 128;
    int wr = (w >> 1) * 32, wc = (w & 1) * 64;

    f32x4 acc[2][4];
    #pragma unroll
    for (int i = 0; i < 2; i++)
        #pragma unroll
        for (int j = 0; j < 4; j++) acc[i][j] = (f32x4){0.f, 0.f, 0.f, 0.f};

    int arr = w & 1;
    int qrt = (w >> 1) * 32;
    int scol = (((lane & 3) - ((lane >> 3) & 3)) & 3) * 8;
    const unsigned short* gsrc = arr ? Bt : A;
    int glim = arr ? (N - 1) : (M - 1);
    int gb   = arr ? n0 : m0;
    const unsigned short* gp0 = gsrc + (size_t)min(gb + qrt + (lane >> 2),      glim) * Kp + scol;
    const unsigned short* gp1 = gsrc + (size_t)min(gb + qrt + 16 + (lane >> 2), glim) * Kp + scol;
    int lo0 = qrt * 32, lo1 = (qrt + 16) * 32;

    int fr = lane & 15, q = lane >> 4;
    int pcs = ((q + (fr >> 1)) & 3) * 8;
    int niter = Kp >> 5;

    GLDS16(gp0, &SH[0][arr][lo0]);
    GLDS16(gp1, &SH[0][arr][lo1]);

    for (int it = 0; it < niter; it++) {
        __syncthreads();                       // drains stage for buffer it&1
        int bsel = it & 1;
        if (it + 1 < niter) {
            int k1 = (it + 1) << 5;
            GLDS16(gp0 + k1, &SH[bsel ^ 1][arr][lo0]);
            GLDS16(gp1 + k1, &SH[bsel ^ 1][arr][lo1]);
        }
        const unsigned short* As = SH[bsel][0];
        const unsigned short* Bs = SH[bsel][1];
        short8 a[2], b[4];
        #pragma unroll
        for (int i = 0; i < 2; i++)
            a[i] = *(const short8*)&As[(wr + i * 16 + fr) * 32 + pcs];
        #pragma unroll
        for (int j = 0; j < 4; j++)
            b[j] = *(const short8*)&Bs[(wc + j * 16 + fr) * 32 + pcs];
        #pragma unroll
        for (int i = 0; i < 2; i++)
            #pragma unroll
            for (int j = 0; j < 4; j++)
                acc[i][j] = __builtin_amdgcn_mfma_f32_16x16x32_bf16(a[i], b[j], acc[i][j], 0, 0, 0);
    }

    int col = lane & 15, rq = (lane >> 4) * 4;
    #pragma unroll
    for (int i = 0; i < 2; i++)
        #pragma unroll
        for (int j = 0; j < 4; j++) {
            int n_g = n0 + wc + j * 16 + col;
            #pragma unroll
            for (int r = 0; r < 4; r++) {
                int m_g = m0 + wr + i * 16 + rq + r;
                if (m_g < M && n_g < N) {
                    float v = acc[i][j][r];
                    if (bias) v += bias[n_g];
                    if (flags & BG_RELU) v = fmaxf(v, 0.f);
                    if (Cf) Cf[(size_t)m_g * N + n_g] = v;
                    if (Cb) Cb[(size_t)m_g * N + n_g] = f2bf(v);
                }
            }
        }
}

// ---------- bf16 MFMA GEMM, 3-term split, 128 tile, 512 threads, LDS dbuf
// residual input as bf16 hi/lo pair (resh/resl); in-place with Cbh/Cbl is safe
// (same-thread read-before-write, block-private output tiles).
__global__ __launch_bounds__(512) void bgemm3_kernel(
    const unsigned short* __restrict__ Ah, const unsigned short* __restrict__ Al,
    const unsigned short* __restrict__ Bh, const unsigned short* __restrict__ Bl,
    int M, int N, int Kp, int nbx, int nby, int bigx,
    float* __restrict__ Cf, unsigned short* __restrict__ Cbh, unsigned short* __restrict__ Cbl,
    const float* __restrict__ bias,
    const unsigned short* __restrict__ resh, const unsigned short* __restrict__ resl,
    const float* __restrict__ cnorm, int flags)
{
    __shared__ unsigned short SH[2][4][128 * 32];   // 64 KB
    int bxi, byi;
    if (!swizzle_blk(blockIdx.x, nbx, nby, bigx, &bxi, &byi)) return;
    int tid = threadIdx.x;
    int w = tid >> 6, lane = tid & 63;
    int m0 = byi * 128, n0 = bxi * 128;
    int wr = (w >> 1) * 32, wc = (w & 1) * 64;

    f32x4 acc[2][4];
    #pragma unroll
    for (int i = 0; i < 2; i++)
        #pragma unroll
        for (int j = 0; j < 4; j++) acc[i][j] = (f32x4){0.f, 0.f, 0.f, 0.f};

    int arr = w & 3;
    int half = (w >> 2) * 64;
    int scol = (((lane & 3) - ((lane >> 3) & 3)) & 3) * 8;
    const unsigned short* gsrc = (arr == 0) ? Ah : (arr == 1) ? Al : (arr == 2) ? Bh : Bl;
    int glim = (arr < 2) ? (M - 1) : (N - 1);
    int gb   = (arr < 2) ? m0 : n0;
    const unsigned short* gp[4];
    int lofs[4];
    #pragma unroll
    for (int t = 0; t < 4; t++) {
        int r = half + t * 16;
        gp[t] = gsrc + (size_t)min(gb + r + (lane >> 2), glim) * Kp + scol;
        lofs[t] = r * 32;
    }

    int fr = lane & 15, q = lane >> 4;
    int pcs = ((q + (fr >> 1)) & 3) * 8;
    int niter = Kp >> 5;

    #pragma unroll
    for (int t = 0; t < 4; t++) GLDS16(gp[t], &SH[0][arr][lofs[t]]);

    for (int it = 0; it < niter; it++) {
        __syncthreads();                       // drains stage for buffer it&1
        int bsel = it & 1;
        if (it + 1 < niter) {
            int k1 = (it + 1) << 5;
            #pragma unroll
            for (int t = 0; t < 4; t++) GLDS16(gp[t] + k1, &SH[bsel ^ 1][arr][lofs[t]]);
        }
        const unsigned short* Ash = SH[bsel][0];
        const unsigned short* Asl = SH[bsel][1];
        const unsigned short* Bsh = SH[bsel][2];
        const unsigned short* Bsl = SH[bsel][3];
        short8 a[2], b[4];
        #pragma unroll
        for (int i = 0; i < 2; i++)
            a[i] = *(const short8*)&Ash[(wr + i * 16 + fr) * 32 + pcs];
        #pragma unroll
        for (int j = 0; j < 4; j++)
            b[j] = *(const short8*)&Bsh[(wc + j * 16 + fr) * 32 + pcs];
        #pragma unroll
        for (int i = 0; i < 2; i++)
            #pragma unroll
            for (int j = 0; j < 4; j++)
                acc[i][j] = __builtin_amdgcn_mfma_f32_16x16x32_bf16(a[i], b[j], acc[i][j], 0, 0, 0);
        short8 al2[2];
        #pragma unroll
        for (int i = 0; i < 2; i++)
            al2[i] = *(const short8*)&Asl[(wr + i * 16 + fr) * 32 + pcs];
        #pragma unroll
        for (int i = 0; i < 2; i++)
            #pragma unroll
            for (int j = 0; j < 4; j++)
                acc[i][j] = __builtin_amdgcn_mfma_f32_16x16x32_bf16(al2[i], b[j], acc[i][j], 0, 0, 0);
        short8 bl2[4];
        #pragma unroll
        for (int j = 0; j < 4; j++)
            bl2[j] = *(const short8*)&Bsl[(wc + j * 16 + fr) * 32 + pcs];
        #pragma unroll
        for (int i = 0; i < 2; i++)
            #pragma unroll
            for (int j = 0; j < 4; j++)
                acc[i][j] = __builtin_amdgcn_mfma_f32_16x16x32_bf16(a[i], bl2[j], acc[i][j], 0, 0, 0);
    }

    int col = lane & 15, rq = (lane >> 4) * 4;
    #pragma unroll
    for (int i = 0; i < 2; i++)
        #pragma unroll
        for (int j = 0; j < 4; j++) {
            int n_g = n0 + wc + j * 16 + col;
            #pragma unroll
            for (int r = 0; r < 4; r++) {
                int m_g = m0 + wr + i * 16 + rq + r;
                if (m_g < M && n_g < N) {
                    size_t idx = (size_t)m_g * N + n_g;
                    float v = acc[i][j][r];
                    if (bias) v += bias[n_g];
                    if (resh) v += bf2f(resh[idx]) + bf2f(resl[idx]);
                    if (flags & BG_RELU) v = fmaxf(v, 0.f);
                    if (flags & BG_SCORE) v = 2.f * v - cnorm[n_g];
                    if (Cf) Cf[idx] = v;
                    if (Cbh) {
                        unsigned short h = f2bf(v);
                        Cbh[idx] = h;
                        if (Cbl) Cbl[idx] = f2bf(v - bf2f(h));
                    }
                }
            }
        }
}

// ------------------------- small-M GEMM: 64x64 tile, 1- or 3-term (Al null => 1-term)
__global__ __launch_bounds__(256) void bgemm3s_kernel(
    const unsigned short* __restrict__ Ah, const unsigned short* __restrict__ Al,
    const unsigned short* __restrict__ Bh, const unsigned short* __restrict__ Bl,
    int M, int N, int Kp,
    float* __restrict__ Cf, unsigned short* __restrict__ Cbh, unsigned short* __restrict__ Cbl,
    const float* __restrict__ bias, const float* __restrict__ resf, int flags)
{
    __shared__ unsigned short Ash[64 * 32];
    __shared__ unsigned short Asl[64 * 32];
    __shared__ unsigned short Bsh[64 * 32];
    __shared__ unsigned short Bsl[64 * 32];
    int tid = threadIdx.x;
    int w = tid >> 6, lane = tid & 63;
    int m0 = blockIdx.y * 64, n0 = blockIdx.x * 64;
    int wr = (w >> 1) * 32, wc = (w & 1) * 32;
    int three = (Al != nullptr);

    f32x4 acc[2][2];
    #pragma unroll
    for (int i = 0; i < 2; i++)
        #pragma unroll
        for (int j = 0; j < 2; j++) acc[i][j] = (f32x4){0.f, 0.f, 0.f, 0.f};

    int srow = w * 16 + (lane >> 2);
    int scol = (((lane & 3) - ((lane >> 3) & 3)) & 3) * 8;
    size_t ra = (size_t)min(m0 + srow, M - 1) * Kp + scol;
    size_t rb = (size_t)min(n0 + srow, N - 1) * Kp + scol;
    unsigned short* lah = &Ash[(w * 16) * 32];
    unsigned short* lal = &Asl[(w * 16) * 32];
    unsigned short* lbh = &Bsh[(w * 16) * 32];
    unsigned short* lbl = &Bsl[(w * 16) * 32];

    int fr = lane & 15, q = lane >> 4;
    int pcs = ((q + (fr >> 1)) & 3) * 8;

    for (int k0 = 0; k0 < Kp; k0 += 32) {
        __syncthreads();
        GLDS16(Ah + ra + k0, lah);
        GLDS16(Bh + rb + k0, lbh);
        if (three) {
            GLDS16(Al + ra + k0, lal);
            GLDS16(Bl + rb + k0, lbl);
        }
        __syncthreads();
        short8 a[2], b[2];
        #pragma unroll
        for (int i = 0; i < 2; i++)
            a[i] = *(const short8*)&Ash[(wr + i * 16 + fr) * 32 + pcs];
        #pragma unroll
        for (int j = 0; j < 2; j++)
            b[j] = *(const short8*)&Bsh[(wc + j * 16 + fr) * 32 + pcs];
        #pragma unroll
        for (int i = 0; i < 2; i++)
            #pragma unroll
            for (int j = 0; j < 2; j++)
                acc[i][j] = __builtin_amdgcn_mfma_f32_16x16x32_bf16(a[i], b[j], acc[i][j], 0, 0, 0);
        if (three) {
            short8 al2[2], bl2[2];
            #pragma unroll
            for (int i = 0; i < 2; i++)
                al2[i] = *(const short8*)&Asl[(wr + i * 16 + fr) * 32 + pcs];
            #pragma unroll
            for (int j = 0; j < 2; j++)
                bl2[j] = *(const short8*)&Bsl[(wc + j * 16 + fr) * 32 + pcs];
            #pragma unroll
            for (int i = 0; i < 2; i++)
                #pragma unroll
                for (int j = 0; j < 2; j++) {
                    acc[i][j] = __builtin_amdgcn_mfma_f32_16x16x32_bf16(al2[i], b[j], acc[i][j], 0, 0, 0);
                    acc[i][j] = __builtin_amdgcn_mfma_f32_16x16x32_bf16(a[i], bl2[j], acc[i][j], 0, 0, 0);
                }
        }
    }

    int col = lane & 15, rq = (lane >> 4) * 4;
    #pragma unroll
    for (int i = 0; i < 2; i++)
        #pragma unroll
        for (int j = 0; j < 2; j++) {
            int n_g = n0 + wc + j * 16 + col;
            #pragma unroll
            for (int r = 0; r < 4; r++) {
                int m_g = m0 + wr + i * 16 + rq + r;
                if (m_g < M && n_g < N) {
                    float v = acc[i][j][r];
                    if (bias) v += bias[n_g];
                    if (resf) v += resf[(size_t)m_g * N + n_g];
                    if (flags & BG_RELU) v = fmaxf(v, 0.f);
                    if (Cf) Cf[(size_t)m_g * N + n_g] = v;
                    if (Cbh) {
                        unsigned short h = f2bf(v);
                        Cbh[(size_t)m_g * N + n_g] = h;
                        if (Cbl) Cbl[(size_t)m_g * N + n_g] = f2bf(v - bf2f(h));
                    }
                }
            }
        }
}

// ---------------------------------------------------------------- LayerNorm bf16 hi/lo out (fp32 in)
__global__ __launch_bounds__(256) void ln_split_kernel(const float* __restrict__ X,
    unsigned short* __restrict__ Yh, unsigned short* __restrict__ Yl,
    const float* __restrict__ g, const float* __restrict__ bt, int M)
{
    int wave = threadIdx.x >> 6, lane = threadIdx.x & 63;
    int row = blockIdx.x * 4 + wave;
    if (row >= M) return;
    const float* x = X + (size_t)row * DM;
    float4 v0 = ((const float4*)x)[lane * 2];
    float4 v1 = ((const float4*)x)[lane * 2 + 1];
    float s = v0.x + v0.y + v0.z + v0.w + v1.x + v1.y + v1.z + v1.w;
    #pragma unroll
    for (int off = 32; off; off >>= 1) s += __shfl_xor(s, off, 64);
    float m = s * (1.f / DM);
    float q = (v0.x - m) * (v0.x - m) + (v0.y - m) * (v0.y - m)
            + (v0.z - m) * (v0.z - m) + (v0.w - m) * (v0.w - m)
            + (v1.x - m) * (v1.x - m) + (v1.y - m) * (v1.y - m)
            + (v1.z - m) * (v1.z - m) + (v1.w - m) * (v1.w - m);
    #pragma unroll
    for (int off = 32; off; off >>= 1) q += __shfl_xor(q, off, 64);
    float rstd = 1.f / sqrtf(q * (1.f / DM) + 1e-5f);
    float vals[8] = {v0.x, v0.y, v0.z, v0.w, v1.x, v1.y, v1.z, v1.w};
    unsigned short* yh = Yh + (size_t)row * DM + lane * 8;
    unsigned short* yl = Yl + (size_t)row * DM + lane * 8;
    const float* gp = g + lane * 8;
    const float* bp = bt + lane * 8;
    #pragma unroll
    for (int i = 0; i < 8; i++) {
        float y = (vals[i] - m) * rstd * gp[i] + bp[i];
        unsigned short h = f2bf(y);
        yh[i] = h;
        yl[i] = f2bf(y - bf2f(h));
    }
}

// ------------------------------- LayerNorm, bf16 hi/lo in AND out (in-place safe)
__global__ __launch_bounds__(256) void ln_split2_kernel(
    const unsigned short* __restrict__ Xh, const unsigned short* __restrict__ Xl,
    unsigned short* __restrict__ Yh, unsigned short* __restrict__ Yl,
    const float* __restrict__ g, const float* __restrict__ bt, int M)
{
    int wave = threadIdx.x >> 6, lane = threadIdx.x & 63;
    int row = blockIdx.x * 4 + wave;
    if (row >= M) return;
    const ushort4* xh = (const ushort4*)(Xh + (size_t)row * DM) + lane * 2;
    const ushort4* xl = (const ushort4*)(Xl + (size_t)row * DM) + lane * 2;
    ushort4 h0 = xh[0], h1 = xh[1];
    ushort4 l0 = xl[0], l1 = xl[1];
    float vals[8] = {
        bf2f(h0.x) + bf2f(l0.x), bf2f(h0.y) + bf2f(l0.y),
        bf2f(h0.z) + bf2f(l0.z), bf2f(h0.w) + bf2f(l0.w),
        bf2f(h1.x) + bf2f(l1.x), bf2f(h1.y) + bf2f(l1.y),
        bf2f(h1.z) + bf2f(l1.z), bf2f(h1.w) + bf2f(l1.w)
    };
    float s = 0.f;
    #pragma unroll
    for (int i = 0; i < 8; i++) s += vals[i];
    #pragma unroll
    for (int off = 32; off; off >>= 1) s += __shfl_xor(s, off, 64);
    float m = s * (1.f / DM);
    float q = 0.f;
    #pragma unroll
    for (int i = 0; i < 8; i++) q += (vals[i] - m) * (vals[i] - m);
    #pragma unroll
    for (int off = 32; off; off >>= 1) q += __shfl_xor(q, off, 64);
    float rstd = 1.f / sqrtf(q * (1.f / DM) + 1e-5f);
    unsigned short* yh = Yh + (size_t)row * DM + lane * 8;
    unsigned short* yl = Yl + (size_t)row * DM + lane * 8;
    const float* gp = g + lane * 8;
    const float* bp = bt + lane * 8;
    #pragma unroll
    for (int i = 0; i < 8; i++) {
        float y = (vals[i] - m) * rstd * gp[i] + bp[i];
        unsigned short h = f2bf(y);
        yh[i] = h;
        yl[i] = f2bf(y - bf2f(h));
    }
}

// ---------------------------------------------------------------- key norms from hi/lo pair
__global__ __launch_bounds__(256) void cnorm2_kernel(
    const unsigned short* __restrict__ Kh, const unsigned short* __restrict__ Kl,
    float* __restrict__ cn, int N)
{
    int wave = threadIdx.x >> 6, lane = threadIdx.x & 63;
    int row = blockIdx.x * 4 + wave;
    if (row >= N) return;
    const ushort4* xh = (const ushort4*)(Kh + (size_t)row * DM) + lane * 2;
    const ushort4* xl = (const ushort4*)(Kl + (size_t)row * DM) + lane * 2;
    ushort4 h0 = xh[0], h1 = xh[1];
    ushort4 l0 = xl[0], l1 = xl[1];
    float s = 0.f;
    float v;
    v = bf2f(h0.x) + bf2f(l0.x); s += v * v;
    v = bf2f(h0.y) + bf2f(l0.y); s += v * v;
    v = bf2f(h0.z) + bf2f(l0.z); s += v * v;
    v = bf2f(h0.w) + bf2f(l0.w); s += v * v;
    v = bf2f(h1.x) + bf2f(l1.x); s += v * v;
    v = bf2f(h1.y) + bf2f(l1.y); s += v * v;
    v = bf2f(h1.z) + bf2f(l1.z); s += v * v;
    v = bf2f(h1.w) + bf2f(l1.w); s += v * v;
    #pragma unroll
    for (int off = 32; off; off >>= 1) s += __shfl_xor(s, off, 64);
    if (lane == 0) cn[row] = s;
}

// ---------------------------------------------------------------- ctx init
__global__ void ctx_init_kernel(int* __restrict__ idx, float* __restrict__ sc)
{
    int i = blockIdx.x * 256 + threadIdx.x;
    if (i < NB * CTX) { idx[i] = 0; sc[i] = -1e30f; }
}

// ------------------------------------- running top-96 merge: exact radix select
#define CANDCAP 2048
__global__ __launch_bounds__(256) void topk_merge_kernel(
    const float* __restrict__ S, int m, int base,
    const int* __restrict__ pidx, const float* __restrict__ pscore,
    int* __restrict__ nidx, float* __restrict__ nscore)
{
    __shared__ __align__(16) unsigned int ks[TOTMAX];
    __shared__ unsigned int hist[4 * 256];
    __shared__ unsigned int sfx[256];
    __shared__ unsigned int s_prefix;
    __shared__ int s_above;
    __shared__ int prev_i[CTX];
    __shared__ int nsel, neq;
    __shared__ float sel_s[CTX];
    __shared__ int   sel_g[CTX];
    __shared__ int   cnd_g[CANDCAP];

    int b = blockIdx.x, tid = threadIdx.x;
    int lane = tid & 63, wv = tid >> 6;
    const float* Sb = S + (size_t)b * m;
    int tot = m + CTX;

    int m4 = m >> 2;
    const float4* S4 = (const float4*)Sb;
    for (int i = tid; i < m4; i += 256) {
        float4 v = S4[i];
        uint4 kk;
        kk.x = f2key(v.x); kk.y = f2key(v.y); kk.z = f2key(v.z); kk.w = f2key(v.w);
        ((uint4*)ks)[i] = kk;
    }
    for (int i = (m4 << 2) + tid; i < m; i += 256) ks[i] = f2key(Sb[i]);
    if (tid < CTX) {
        ks[m + tid] = f2key(pscore[b * CTX + tid]);
        prev_i[tid] = pidx[b * CTX + tid];
    }
    if (tid == 0) { s_prefix = 0u; s_above = 0; nsel = 0; neq = 0; }
    __syncthreads();

    unsigned int* myhist = &hist[wv * 256];

    for (int pass = 0; pass < 4; pass++) {
        int shift = 24 - pass * 8;
        for (int i = tid; i < 1024; i += 256) hist[i] = 0;
        __syncthreads();
        unsigned int pref = s_prefix;
        unsigned int msk = (pass == 0) ? 0u : (0xFFFFFFFFu << (32 - 8 * pass));
        for (int i0 = 0; i0 < tot; i0 += 256) {
            int i = i0 + tid;
            int pred = 0, digit = 0;
            if (i < tot) {
                unsigned int k = ks[i];
                pred = ((k & msk) == pref);
                digit = (int)((k >> shift) & 255u);
            }
            unsigned long long act = __ballot(pred);
            if (!act) continue;
            int lead = (int)__ffsll(act) - 1;
            int d0 = __shfl(digit, lead, 64);
            unsigned long long same = __ballot(pred && (digit == d0));
            if (same == act) {
                if (lane == lead) atomicAdd(&myhist[d0], (unsigned int)__popcll(act));
            } else {
                if (pred) atomicAdd(&myhist[digit], 1u);
            }
        }
        __syncthreads();
        unsigned int hb = hist[tid] + hist[256 + tid] + hist[512 + tid] + hist[768 + tid];
        __syncthreads();
        hist[tid] = hb;
        sfx[tid] = hb;
        __syncthreads();
        #pragma unroll
        for (int offd = 1; offd < 256; offd <<= 1) {
            unsigned int v = (tid + offd < 256) ? sfx[tid + offd] : 0u;
            __syncthreads();
            sfx[tid] += v;
            __syncthreads();
        }
        {
            int incl = s_above + (int)sfx[tid];
            int excl = incl - (int)hb;
            if (excl < CTX && incl >= CTX) {
                s_prefix = pref | ((unsigned int)tid << shift);
                s_above = excl;
            }
        }
        __syncthreads();
    }
    unsigned int thrK = s_prefix;
    int msel = CTX - s_above;
    float eqv = key2f(thrK);

    for (int i = tid; i < tot; i += 256) {
        unsigned int k = ks[i];
        if (k < thrK) continue;
        int g = (i < m) ? (base + i) : prev_i[i - m];
        if (k > thrK) {
            int p = atomicAdd(&nsel, 1);
            sel_s[p] = key2f(k); sel_g[p] = g;
        } else {
            int p = atomicAdd(&neq, 1);
            if (p < CANDCAP) cnd_g[p] = g;
        }
    }
    __syncthreads();
    int ne = neq;
    if (ne <= CANDCAP) {
        for (int i = tid; i < ne; i += 256) {
            int gi = cnd_g[i];
            int rank = 0;
            for (int j = 0; j < ne; j++) rank += (cnd_g[j] < gi);
            if (rank < msel) {
                int p = atomicAdd(&nsel, 1);
                sel_s[p] = eqv; sel_g[p] = gi;
            }
        }
    } else {
        for (int i = tid; i < tot; i += 256) {
            if (ks[i] != thrK) continue;
            int g = (i < m) ? (base + i) : prev_i[i - m];
            int rank = 0;
            for (int j = 0; j < tot; j++) {
                if (ks[j] == thrK) {
                    int gj = (j < m) ? (base + j) : prev_i[j - m];
                    rank += (gj < g);
                }
            }
            if (rank < msel) {
                int p = atomicAdd(&nsel, 1);
                sel_s[p] = eqv; sel_g[p] = g;
            }
        }
    }
    __syncthreads();
    if (tid < CTX) {
        nidx[b * CTX + tid] = sel_g[tid];
        nscore[b * CTX + tid] = sel_s[tid];
    }
}

// ------------------------------- softmax + label/value context aggregation
__global__ __launch_bounds__(256) void agg_kernel(
    const int* __restrict__ ctx_idx, const float* __restrict__ ctx_score,
    const float* __restrict__ cand_y, const float* __restrict__ T1b,
    const unsigned short* __restrict__ T1c, const float* __restrict__ T_b1,
    const float* __restrict__ x_batch,
    const float* __restrict__ label_w, const float* __restrict__ label_b,
    unsigned short* __restrict__ s_h, unsigned short* __restrict__ s_l,
    float* __restrict__ u_out)
{
    __shared__ float p_s[CTX];
    __shared__ int   p_i[CTX];
    __shared__ float s_ybar;
    int b = blockIdx.x, tid = threadIdx.x;
    if (tid < CTX) { p_s[tid] = ctx_score[b * CTX + tid]; p_i[tid] = ctx_idx[b * CTX + tid]; }
    __syncthreads();
    if (tid == 0) {
        float mx = -1e30f;
        for (int c = 0; c < CTX; c++) mx = fmaxf(mx, p_s[c]);
        float sum = 0.f;
        for (int c = 0; c < CTX; c++) { float e = __expf(p_s[c] - mx); p_s[c] = e; sum += e; }
        float inv = 1.f / sum, yb = 0.f;
        for (int c = 0; c < CTX; c++) { p_s[c] *= inv; yb += p_s[c] * cand_y[p_i[c]]; }
        s_ybar = yb;
    }
    __syncthreads();
    int j = tid * 4;
    float4 kv = *(const float4*)(T1b + (size_t)b * DBK + j);
    float4 tb = *(const float4*)(T_b1 + j);
    float base0 = kv.x + tb.x, base1 = kv.y + tb.y, base2 = kv.z + tb.z, base3 = kv.w + tb.w;
    float a0 = 0.f, a1 = 0.f, a2 = 0.f, a3 = 0.f;
    for (int c = 0; c < CTX; c++) {
        float p = p_s[c];
        ushort4 cu = *(const ushort4*)(T1c + (size_t)p_i[c] * DBK + j);
        a0 = fmaf(p, fmaxf(base0 - bf2f(cu.x), 0.f), a0);
        a1 = fmaf(p, fmaxf(base1 - bf2f(cu.y), 0.f), a1);
        a2 = fmaf(p, fmaxf(base2 - bf2f(cu.z), 0.f), a2);
        a3 = fmaf(p, fmaxf(base3 - bf2f(cu.w), 0.f), a3);
    }
    {
        ushort4 oh, ol;
        oh.x = f2bf(a0); ol.x = f2bf(a0 - bf2f(oh.x));
        oh.y = f2bf(a1); ol.y = f2bf(a1 - bf2f(oh.y));
        oh.z = f2bf(a2); ol.z = f2bf(a2 - bf2f(oh.z));
        oh.w = f2bf(a3); ol.w = f2bf(a3 - bf2f(oh.w));
        *(ushort4*)(s_h + (size_t)b * DBK + j) = oh;
        *(ushort4*)(s_l + (size_t)b * DBK + j) = ol;
    }
    if (tid < 128) {
        int d = tid * 4;
        float4 xv = *(const float4*)(x_batch + (size_t)b * DM + d);
        float4 lw = *(const float4*)(label_w + d);
        float4 lb = *(const float4*)(label_b + d);
        float yb = s_ybar;
        *(float4*)(u_out + (size_t)b * DM + d) =
            make_float4(xv.x + yb * lw.x + lb.x, xv.y + yb * lw.y + lb.y,
                        xv.z + yb * lw.z + lb.z, xv.w + yb * lw.w + lb.w);
    }
}

// ---------------------------------------------------------------- head
__global__ __launch_bounds__(256) void head_kernel(
    const float* __restrict__ X, const float* __restrict__ g,
    const float* __restrict__ bt, const float* __restrict__ w,
    const float* __restrict__ hb, float* __restrict__ out, int M)
{
    int wave = threadIdx.x >> 6, lane = threadIdx.x & 63;
    int row = blockIdx.x * 4 + wave;
    if (row >= M) return;
    const float* x = X + (size_t)row * DM;
    float4 v0 = ((const float4*)x)[lane * 2];
    float4 v1 = ((const float4*)x)[lane * 2 + 1];
    float s = v0.x + v0.y + v0.z + v0.w + v1.x + v1.y + v1.z + v1.w;
    #pragma unroll
    for (int off = 32; off; off >>= 1) s += __shfl_xor(s, off, 64);
    float m = s * (1.f / DM);
    float q = (v0.x - m) * (v0.x - m) + (v0.y - m) * (v0.y - m)
            + (v0.z - m) * (v0.z - m) + (v0.w - m) * (v0.w - m)
            + (v1.x - m) * (v1.x - m) + (v1.y - m) * (v1.y - m)
            + (v1.z - m) * (v1.z - m) + (v1.w - m) * (v1.w - m);
    #pragma unroll
    for (int off = 32; off; off >>= 1) q += __shfl_xor(q, off, 64);
    float rstd = 1.f / sqrtf(q * (1.f / DM) + 1e-5f);
    float4 g0 = ((const float4*)g)[lane * 2], g1 = ((const float4*)g)[lane * 2 + 1];
    float4 b0 = ((const float4*)bt)[lane * 2], b1 = ((const float4*)bt)[lane * 2 + 1];
    float4 w0 = ((const float4*)w)[lane * 2], w1 = ((const float4*)w)[lane * 2 + 1];
    float t = 0.f;
    t += fmaxf((v0.x - m) * rstd * g0.x + b0.x, 0.f) * w0.x;
    t += fmaxf((v0.y - m) * rstd * g0.y + b0.y, 0.f) * w0.y;
    t += fmaxf((v0.z - m) * rstd * g0.z + b0.z, 0.f) * w0.z;
    t += fmaxf((v0.w - m) * rstd * g0.w + b0.w, 0.f) * w0.w;
    t += fmaxf((v1.x - m) * rstd * g1.x + b1.x, 0.f) * w1.x;
    t += fmaxf((v1.y - m) * rstd * g1.y + b1.y, 0.f) * w1.y;
    t += fmaxf((v1.z - m) * rstd * g1.z + b1.z, 0.f) * w1.z;
    t += fmaxf((v1.w - m) * rstd * g1.w + b1.w, 0.f) * w1.w;
    #pragma unroll
    for (int off = 32; off; off >>= 1) t += __shfl_xor(t, off, 64);
    if (lane == 0) out[row] = t + hb[0];
}

// =================================================================== host
extern "C" void kernel_launch(void* const* d_in, const int* in_sizes, int n_in,
                              void* d_out, int out_size, void* d_ws, size_t ws_size,
                              hipStream_t stream) {
    (void)in_sizes; (void)n_in; (void)out_size;
    const float* x_num   = (const float*)d_in[0];
    const float* x_cat   = (const float*)d_in[1];
    const float* cxn     = (const float*)d_in[2];
    const float* cxc     = (const float*)d_in[3];
    const float* cand_y  = (const float*)d_in[4];
    const float* freq    = (const float*)d_in[6];
    const float* plr_w   = (const float*)d_in[7];
    const float* plr_b   = (const float*)d_in[8];
    const float* lin_w   = (const float*)d_in[9];
    const float* lin_b   = (const float*)d_in[10];
    const float* enc_w1  = (const float*)d_in[11];
    const float* enc_b1  = (const float*)d_in[12];
    const float* enc_w2  = (const float*)d_in[13];
    const float* enc_b2  = (const float*)d_in[14];
    const float* mix_g   = (const float*)d_in[15];
    const float* mix_b   = (const float*)d_in[16];
    const float* K_w     = (const float*)d_in[17];
    const float* K_b     = (const float*)d_in[18];
    const float* label_w = (const float*)d_in[19];
    const float* label_b = (const float*)d_in[20];
    const float* T_w1    = (const float*)d_in[21];
    const float* T_b1    = (const float*)d_in[22];
    const float* T_w2    = (const float*)d_in[23];
    const float* pred_g  = (const float*)d_in[24];
    const float* pred_b  = (const float*)d_in[25];
    const float* pred_w1 = (const float*)d_in[26];
    const float* pred_b1 = (const float*)d_in[27];
    const float* pred_w2 = (const float*)d_in[28];
    const float* pred_b2 = (const float*)d_in[29];
    const float* head_g  = (const float*)d_in[30];
    const float* head_b  = (const float*)d_in[31];
    const float* head_w  = (const float*)d_in[32];
    const float* head_bias = (const float*)d_in[33];
    float* out = (float*)d_out;

    char* ws = (char*)d_ws;
    size_t off = 0;
    auto alloc = [&](size_t n) { char* p = ws + off; off = (off + n + 255) & ~(size_t)255; return p; };

    typedef unsigned short u16;
    u16* lin_wt_h = (u16*)alloc((size_t)DM * KP_IN * 2);
    u16* lin_wt_l = (u16*)alloc((size_t)DM * KP_IN * 2);
    u16* e1t_h    = (u16*)alloc((size_t)DBK * DM * 2);
    u16* e1t_l    = (u16*)alloc((size_t)DBK * DM * 2);
    u16* e2t_h    = (u16*)alloc((size_t)DM * DBK * 2);
    u16* e2t_l    = (u16*)alloc((size_t)DM * DBK * 2);
    u16* K_wt_h   = (u16*)alloc((size_t)DM * DM * 2);
    u16* K_wt_l   = (u16*)alloc((size_t)DM * DM * 2);
    u16* T_w1t    = (u16*)alloc((size_t)DBK * DM * 2);
    u16* T_w2t_h  = (u16*)alloc((size_t)DM * DBK * 2);
    u16* T_w2t_l  = (u16*)alloc((size_t)DM * DBK * 2);
    u16* p1t_h    = (u16*)alloc((size_t)DBK * DM * 2);
    u16* p1t_l    = (u16*)alloc((size_t)DBK * DM * 2);
    u16* p2t_h    = (u16*)alloc((size_t)DM * DBK * 2);
    u16* p2t_l    = (u16*)alloc((size_t)DM * DBK * 2);
    u16*   T1c  = (u16*)alloc((size_t)NCAND * DBK * 2);
    float* T1b  = (float*)alloc((size_t)NB * DBK * 4);
    float* xB   = (float*)alloc((size_t)NB * DM * 4);
    u16*   kBh  = (u16*)alloc((size_t)NB * DM * 2);
    u16*   kBl  = (u16*)alloc((size_t)NB * DM * 2);
    u16* binh = (u16*)alloc((size_t)NB * KP_IN * 2);
    u16* binl = (u16*)alloc((size_t)NB * KP_IN * 2);
    u16* xBhh = (u16*)alloc((size_t)NB * DM * 2);
    u16* xBhl = (u16*)alloc((size_t)NB * DM * 2);
    u16* hBh  = (u16*)alloc((size_t)NB * DBK * 2);
    u16* hBl  = (u16*)alloc((size_t)NB * DBK * 2);
    u16* lnBh = (u16*)alloc((size_t)NB * DM * 2);
    u16* lnBl = (u16*)alloc((size_t)NB * DM * 2);
    int*   ctxAi = (int*)alloc((size_t)NB * CTX * 4);
    float* ctxAs = (float*)alloc((size_t)NB * CTX * 4);
    int*   ctxBi = (int*)alloc((size_t)NB * CTX * 4);
    float* ctxBs = (float*)alloc((size_t)NB * CTX * 4);
    u16*   sbufh = (u16*)alloc((size_t)NB * DBK * 2);
    u16*   sbufl = (u16*)alloc((size_t)NB * DBK * 2);
    float* ubuf  = (float*)alloc((size_t)NB * DM * 4);
    float* x2    = (float*)alloc((size_t)NB * DM * 4);
    u16*   h2h   = (u16*)alloc((size_t)NB * DM * 2);
    u16*   h2l   = (u16*)alloc((size_t)NB * DM * 2);
    u16*   hph   = (u16*)alloc((size_t)NB * DBK * 2);
    u16*   hpl   = (u16*)alloc((size_t)NB * DBK * 2);
    float* x3    = (float*)alloc((size_t)NB * DM * 4);

    // --- chunk arenas: 9.5 KB/row (no fp32 masters; hi/lo pairs only) ---
    size_t remain = (ws_size > off + 8192) ? (ws_size - off - 8192) : 0;
    const size_t perrow = 3328 + 2048 + 4096 + 64;
    long ncl = (long)(remain / perrow);
    int NC = (int)(ncl > NCMAX ? NCMAX : ncl);
    NC &= ~127;
    if (NC < 256) NC = 256;
    char* arenaA = alloc((size_t)NC * 3328);   // inCh+inCl -> scoresC + cnC
    char* arenaC = alloc((size_t)NC * 2048);   // x pair (lin out, enc2 in-place, LN in-place)
    char* arenaD = alloc((size_t)NC * 4096);   // h pair -> k pair
    u16* inCh = (u16*)arenaA;
    u16* inCl = inCh + (size_t)NC * KP_IN;
    float* scoresC = (float*)arenaA;                         // after lin: inC dead
    float* cnC = (float*)(arenaA + (size_t)NC * 2048);       // after scoresC (NB*4=2048/row)
    u16* xCh  = (u16*)arenaC;
    u16* xCl  = xCh + (size_t)NC * DM;
    u16* hCh  = (u16*)arenaD;
    u16* hCl  = hCh + (size_t)NC * DBK;
    u16* kCh  = (u16*)arenaD;                                // after enc2: h dead
    u16* kCl  = kCh + (size_t)NC * DM;

    auto bgemm = [&](const u16* A, const u16* Bt, int M, int N, int Kp,
                     float* Cf, u16* Cb, const float* bias, int flags) {
        int nbx = (N + 127) / 128, nby = (M + 127) / 128;
        int npad = (nby + 7) & ~7;
        bgemm_kernel<<<npad * nbx, 512, 0, stream>>>(A, Bt, M, N, Kp, nbx, nby, 0,
                                                     Cf, Cb, bias, flags);
    };
    auto bgemm3 = [&](const u16* Ah, const u16* Al, const u16* Bh, const u16* Bl,
                      int M, int N, int Kp, int bigx, float* Cf, u16* Cbh, u16* Cbl,
                      const float* bias, const u16* resh, const u16* resl,
                      const float* cnorm, int flags) {
        int nbx = (N + 127) / 128, nby = (M + 127) / 128;
        int nbig = bigx ? nbx : nby, nsm = bigx ? nby : nbx;
        int npad = (nbig + 7) & ~7;
        bgemm3_kernel<<<npad * nsm, 512, 0, stream>>>(Ah, Al, Bh, Bl, M, N, Kp,
                                                      nbx, nby, bigx,
                                                      Cf, Cbh, Cbl, bias, resh, resl,
                                                      cnorm, flags);
    };
    auto bgemm3s = [&](const u16* Ah, const u16* Al, const u16* Bh, const u16* Bl,
                       int M, int N, int Kp, float* Cf, u16* Cbh, u16* Cbl,
                       const float* bias, const float* resf, int flags) {
        dim3 grid((N + 63) / 64, (M + 63) / 64);
        bgemm3s_kernel<<<grid, 256, 0, stream>>>(Ah, Al, Bh, Bl, M, N, Kp,
                                                 Cf, Cbh, Cbl, bias, resf, flags);
    };
    auto wprep = [&](const float* W, int K, int N, int Kp, u16* Wh, u16* Wl) {
        int n = N * Kp;
        wprep_kernel<<<(n + 255) / 256, 256, 0, stream>>>(W, K, N, Kp, Wh, Wl);
    };

    // ---------- weight prep ----------
    wprep(lin_w, DIN, DM, KP_IN, lin_wt_h, lin_wt_l);
    wprep(enc_w1, DM, DBK, DM, e1t_h, e1t_l);
    wprep(enc_w2, DBK, DM, DBK, e2t_h, e2t_l);
    wprep(K_w, DM, DM, DM, K_wt_h, K_wt_l);
    wprep(T_w1, DM, DBK, DM, T_w1t, nullptr);
    wprep(T_w2, DBK, DM, DBK, T_w2t_h, T_w2t_l);
    wprep(pred_w1, DM, DBK, DM, p1t_h, p1t_l);
    wprep(pred_w2, DBK, DM, DBK, p2t_h, p2t_l);

    // ---------- batch encode (64-tile split GEMMs, fp32 masters kept — tiny) ----------
    plr_bf16_kernel<<<(NB + 3) / 4, 256, 0, stream>>>(x_num, x_cat, NB, freq, plr_w, plr_b, binh, binl);
    bgemm3s(binh, binl, lin_wt_h, lin_wt_l, NB, DM, KP_IN, xB, xBhh, xBhl, lin_b, nullptr, 0);
    bgemm3s(xBhh, xBhl, e1t_h, e1t_l, NB, DBK, DM, nullptr, hBh, hBl, enc_b1, nullptr, BG_RELU);
    bgemm3s(hBh, hBl, e2t_h, e2t_l, NB, DM, DBK, xB, nullptr, nullptr, enc_b2, xB, 0);
    ln_split_kernel<<<(NB + 3) / 4, 256, 0, stream>>>(xB, lnBh, lnBl, mix_g, mix_b, NB);
    bgemm3s(lnBh, lnBl, K_wt_h, K_wt_l, NB, DM, DM, nullptr, kBh, kBl, K_b, nullptr, 0);
    bgemm3s(kBh, nullptr, T_w1t, nullptr, NB, DBK, DM, T1b, nullptr, nullptr, nullptr, nullptr, 0);
    ctx_init_kernel<<<(NB * CTX + 255) / 256, 256, 0, stream>>>(ctxAi, ctxAs);

    // ---------- candidate chunks (128-tile, 512-thread, swizzled, dbuf GEMMs) ----------
    const int* pI = ctxAi; const float* pS = ctxAs;
    int* nI = ctxBi; float* nS = ctxBs;
    int nch = (NCAND + NC - 1) / NC;
    for (int c = 0; c < nch; c++) {
        int s = c * NC;
        int m = NCAND - s; if (m > NC) m = NC;
        plr_bf16_kernel<<<(m + 3) / 4, 256, 0, stream>>>(cxn + (size_t)s * NFEAT,
                                                         cxc + (size_t)s * NCAT,
                                                         m, freq, plr_w, plr_b, inCh, inCl);
        bgemm3(inCh, inCl, lin_wt_h, lin_wt_l, m, DM, KP_IN, 0,
               nullptr, xCh, xCl, lin_b, nullptr, nullptr, nullptr, 0);
        bgemm3(xCh, xCl, e1t_h, e1t_l, m, DBK, DM, 0,
               nullptr, hCh, hCl, enc_b1, nullptr, nullptr, nullptr, BG_RELU);
        // enc2 with in-place pair residual: x <- x + mlp(x)
        bgemm3(hCh, hCl, e2t_h, e2t_l, m, DM, DBK, 0,
               nullptr, xCh, xCl, enc_b2, xCh, xCl, nullptr, 0);
        // LN in place on the pair
        ln_split2_kernel<<<(m + 3) / 4, 256, 0, stream>>>(xCh, xCl, xCh, xCl, mix_g, mix_b, m);
        bgemm3(xCh, xCl, K_wt_h, K_wt_l, m, DM, DM, 0,
               nullptr, kCh, kCl, K_b, nullptr, nullptr, nullptr, 0);
        cnorm2_kernel<<<(m + 3) / 4, 256, 0, stream>>>(kCh, kCl, cnC, m);
        bgemm(kCh, T_w1t, m, DBK, DM, nullptr, T1c + (size_t)s * DBK, nullptr, 0);
        bgemm3(kBh, kBl, kCh, kCl, NB, m, DM, 1, scoresC, nullptr, nullptr,
               nullptr, nullptr, nullptr, cnC, BG_SCORE);
        topk_merge_kernel<<<NB, 256, 0, stream>>>(scoresC, m, s, pI, pS, nI, nS);
        { const int* t = pI; pI = nI; nI = (int*)t; }
        { const float* t = pS; pS = nS; nS = (float*)t; }
    }

    // ---------- aggregation + predictor + head (64-tile split GEMMs) ----------
    agg_kernel<<<NB, 256, 0, stream>>>(pI, pS, cand_y, T1b, T1c, T_b1,
                                       xB, label_w, label_b, sbufh, sbufl, ubuf);
    bgemm3s(sbufh, sbufl, T_w2t_h, T_w2t_l, NB, DM, DBK, x2, nullptr, nullptr,
            nullptr, ubuf, 0);
    ln_split_kernel<<<(NB + 3) / 4, 256, 0, stream>>>(x2, h2h, h2l, pred_g, pred_b, NB);
    bgemm3s(h2h, h2l, p1t_h, p1t_l, NB, DBK, DM, nullptr, hph, hpl, pred_b1, nullptr, BG_RELU);
    bgemm3s(hph, hpl, p2t_h, p2t_l, NB, DM, DBK, x3, nullptr, nullptr, pred_b2, x2, 0);
    head_kernel<<<(NB + 3) / 4, 256, 0, stream>>>(x3, head_g, head_b, head_w, head_bias, out, NB);
}